// Round 1
// baseline (1210.762 us; speedup 1.0000x reference)
//
#include <hip/hip_runtime.h>
#include <cstddef>

// ---------------------------------------------------------------------------
// PolyaAKT interaction embedder, MI355X/gfx950.  Inputs fp32, output fp32.
// Control path (logits/GRU) high-precision for argmax fidelity; value path
// (experts/LN/proj) in bf16 MFMA.  Per-q dedup throughout.
// R6: GRU per-step critical path cut (bit-exact vs R5):
//  - Wr/Wz resident in VGPRs (live W shrunk to 128 regs so the allocator
//    actually keeps them; R5's 192-reg W array was being rematerialized —
//    VGPR_Count=144 < 192 proved it).  Wn in wave-private LDS [k][lane].
//  - v_pk_fma_f32 packed chains (ar.x/.y == old arx/ary chains, same order).
//  - r-select folded into fp64 XB at staging time (kills per-step shfl).
// top1: f32x4 m-row loads.  qsk: LDS tiles staged as doubles.
// ---------------------------------------------------------------------------

#define NQ 10000
#define TT 32768   // B*S
#define GW 8       // GRU chunk steps

typedef __attribute__((ext_vector_type(8))) short bf16x8;
typedef __attribute__((ext_vector_type(4))) float f32x4;

__device__ double g_qs  [NQ * 256];      // q_summary (relu'd), fp64
__device__ float  g_xgf [NQ * 192];      // gru_in_q @ W_ih^T (fp32)
__device__ double g_xgr [2 * 192];       // r-part of xg (+b_ih), fp64
__device__ float  g_xg0f[192];           // start_token @ W_ih^T + b_ih (fp32)
__device__ double g_lq  [NQ * 4];        // qs @ wgate[0:256]
__device__ float  g_m   [TT * 64];       // GRU hidden per token (fp32)
__device__ int    g_top1[TT];
__device__ unsigned short g_w1t  [4 * 256 * 256];  // bf16 [e][n][k]
__device__ unsigned short g_w2t  [4 * 256 * 256];
__device__ unsigned short g_projt[512 * 256];      // bf16 [n(cor|inc)][k]
__device__ unsigned short g_qf   [NQ * 4 * 256];   // LN'd expert out, bf16

__device__ __forceinline__ float bf2f(unsigned short x) {
  return __uint_as_float(((unsigned)x) << 16);
}
__device__ __forceinline__ unsigned short f2bf(float f) {
  unsigned u = __float_as_uint(f);
  u += 0x7FFFu + ((u >> 16) & 1u);   // RNE
  return (unsigned short)(u >> 16);
}
__device__ __forceinline__ f32x4 mfma16(bf16x8 a, bf16x8 b, f32x4 c) {
  return __builtin_amdgcn_mfma_f32_16x16x32_bf16(a, b, c, 0, 0, 0);
}
// packed fp32 fma: c = a*b + c on both lanes of the pair (bit-identical to
// two scalar v_fma_f32, just one instruction).
__device__ __forceinline__ void pkfma(float2& c, float2 a, float2 b) {
  asm("v_pk_fma_f32 %0, %1, %2, %0" : "+v"(c) : "v"(a), "v"(b));
}

// fast fp64 exp (slow path only): range-reduced degree-10 poly, rel err ~2e-13.
__device__ __forceinline__ double fexp(double x) {
  const double L2E  = 1.4426950408889634074;
  const double LN2H = 6.93147180369123816490e-01;
  const double LN2L = 1.90821492927058770002e-10;
  double n = rint(x * L2E);
  int ni = (int)n;
  double r = fma(-n, LN2H, x);
  r = fma(-n, LN2L, r);
  double p = 2.7557319223985888e-07;
  p = fma(p, r, 2.7557319223985893e-06);
  p = fma(p, r, 2.4801587301587302e-05);
  p = fma(p, r, 1.9841269841269841e-04);
  p = fma(p, r, 1.3888888888888889e-03);
  p = fma(p, r, 8.3333333333333332e-03);
  p = fma(p, r, 4.1666666666666664e-02);
  p = fma(p, r, 1.6666666666666666e-01);
  p = fma(p, r, 0.5);
  p = fma(p, r, 1.0);
  p = fma(p, r, 1.0);
  return ldexp(p, ni);
}

// tanh via odd Taylor, |p| <= 0.25: abs err ~5e-11.
__device__ __forceinline__ double tpoly(double p) {
  const double p2 = p * p;
  double t = -1382.0 / 155925.0;          // p^11
  t = fma(t, p2, 62.0 / 2835.0);          // p^9
  t = fma(t, p2, -17.0 / 315.0);          // p^7
  t = fma(t, p2, 2.0 / 15.0);             // p^5
  t = fma(t, p2, -1.0 / 3.0);             // p^3
  t = fma(t, p2, 1.0);
  return p * t;
}

// ---------------------------------------------------------------------------
// prep: bf16 transposed weight tables + fp64 folds (xg_r, xg0).
// ---------------------------------------------------------------------------
__global__ void __launch_bounds__(256) prep_kernel(
    const float* __restrict__ expert_w1, const float* __restrict__ expert_w2,
    const float* __restrict__ proj_cor_w, const float* __restrict__ proj_inc_w,
    const float* __restrict__ resp_table, const float* __restrict__ reducer_w,
    const float* __restrict__ reducer_b,  const float* __restrict__ start_token,
    const float* __restrict__ gru_w_ih,   const float* __restrict__ gru_b_ih)
{
  __shared__ double red2f[128];   // [rr][j]
  const int tid = threadIdx.x;
  if (blockIdx.x == 0) {
    if (tid < 128) {
      const int rr = tid >> 6, j = tid & 63;
      double acc = (double)reducer_b[j];
      for (int k = 0; k < 256; ++k)
        acc += (double)resp_table[rr * 256 + k] *
               (double)reducer_w[(256 + k) * 64 + j];
      red2f[tid] = acc;
    }
    __syncthreads();
    if (tid < 192) {
      const double bih = (double)gru_b_ih[tid];
      double a0 = bih, a1 = bih, a2 = bih;
      for (int j = 0; j < 64; ++j) {
        const double w = (double)gru_w_ih[tid * 64 + j];
        a0 += red2f[j] * w;
        a1 += red2f[64 + j] * w;
        a2 += (double)start_token[j] * w;
      }
      g_xgr[tid] = a0; g_xgr[192 + tid] = a1; g_xg0f[tid] = (float)a2;
    }
  }
  const int idx0 = blockIdx.x * 256 + tid;
  const int stride = gridDim.x * 256;
  for (int i = idx0; i < 4 * 256 * 256; i += stride) {
    const int e = i >> 16, rem = i & 65535, n = rem >> 8, k = rem & 255;
    g_w1t[i] = f2bf(expert_w1[e * 65536 + k * 256 + n]);
    g_w2t[i] = f2bf(expert_w2[e * 65536 + k * 256 + n]);
  }
  for (int i = idx0; i < 512 * 256; i += stride) {
    const int n = i >> 8, k = i & 255;
    g_projt[i] = f2bf((n < 256) ? proj_cor_w[k * 256 + n]
                                : proj_inc_w[k * 256 + (n - 256)]);
  }
}

// ---------------------------------------------------------------------------
// qsk: fp64 GEMM  qs[q][n] = relu( emb_row_q(1024) . adapter_w[:,n] + b[n] )
// LDS tiles staged pre-converted to double: inner loop has no cvts and
// vector LDS reads; fma order unchanged (bit-exact vs R5).
// ---------------------------------------------------------------------------
__global__ void __launch_bounds__(256) qsk_kernel(
    const float* __restrict__ emb, const float* __restrict__ adapter_w,
    const float* __restrict__ adapter_b)
{
  __shared__ __align__(16) double Asd[32][66];   // [kk][row]
  __shared__ __align__(16) double Bsd[32][66];   // [kk][col]
  const int tid = threadIdx.x;
  const int q0 = blockIdx.x * 64;
  const int n0 = blockIdx.y * 64;
  const int ty = tid >> 4, tx = tid & 15;

  double acc[4][4];
#pragma unroll
  for (int i = 0; i < 4; ++i)
#pragma unroll
    for (int j = 0; j < 4; ++j) acc[i][j] = 0.0;

  const int arow = tid >> 2, aks = (tid & 3) * 8;
  const int qa = min(q0 + arow, NQ - 1);
  const int bkk = tid >> 3, bns = (tid & 7) * 8;

  for (int kc = 0; kc < 1024; kc += 32) {
    f32x4 av0 = *(const f32x4*)(emb + (size_t)qa * 1024 + kc + aks);
    f32x4 av1 = *(const f32x4*)(emb + (size_t)qa * 1024 + kc + aks + 4);
    f32x4 bv0 = *(const f32x4*)(adapter_w + (size_t)(kc + bkk) * 256 + n0 + bns);
    f32x4 bv1 = *(const f32x4*)(adapter_w + (size_t)(kc + bkk) * 256 + n0 + bns + 4);
    __syncthreads();
#pragma unroll
    for (int i = 0; i < 4; ++i) {
      Asd[aks + i][arow]     = (double)av0[i];
      Asd[aks + 4 + i][arow] = (double)av1[i];
      Bsd[bkk][bns + i]      = (double)bv0[i];
      Bsd[bkk][bns + 4 + i]  = (double)bv1[i];
    }
    __syncthreads();
#pragma unroll 4
    for (int kk = 0; kk < 32; ++kk) {
      double a[4], b[4];
#pragma unroll
      for (int i = 0; i < 4; ++i) a[i] = Asd[kk][ty * 4 + i];
#pragma unroll
      for (int j = 0; j < 4; ++j) b[j] = Bsd[kk][tx * 4 + j];
#pragma unroll
      for (int i = 0; i < 4; ++i)
#pragma unroll
        for (int j = 0; j < 4; ++j) acc[i][j] = fma(a[i], b[j], acc[i][j]);
    }
  }
#pragma unroll
  for (int i = 0; i < 4; ++i) {
    const int qrow = q0 + ty * 4 + i;
    if (qrow < NQ) {
#pragma unroll
      for (int j = 0; j < 4; ++j) {
        const int n = n0 + tx * 4 + j;
        double v = acc[i][j] + (double)adapter_b[n];
        g_qs[(size_t)qrow * 256 + n] = v > 0.0 ? v : 0.0;
      }
    }
  }
}

// ---------------------------------------------------------------------------
// smallk: per q -> gru_in_q(64), xg_q(192) fp32, lq(4).  One block per q.
// ---------------------------------------------------------------------------
__global__ void __launch_bounds__(256) smallk_kernel(
    const float* __restrict__ reducer_w, const float* __restrict__ gru_w_ih,
    const float* __restrict__ wgate_w)
{
  __shared__ double qsr[256];
  __shared__ double ps[4][64];
  __shared__ double gi[64];
  const int tid = threadIdx.x;
  const int qq = blockIdx.x;
  qsr[tid] = g_qs[(size_t)qq * 256 + tid];
  __syncthreads();
  {
    const int j = tid & 63, h = tid >> 6;
    const int k0 = h * 64;
    double a0 = 0.0, a1 = 0.0, a2 = 0.0, a3 = 0.0;
    for (int k = 0; k < 64; k += 4) {
      a0 = fma(qsr[k0 + k + 0], (double)reducer_w[(k0 + k + 0) * 64 + j], a0);
      a1 = fma(qsr[k0 + k + 1], (double)reducer_w[(k0 + k + 1) * 64 + j], a1);
      a2 = fma(qsr[k0 + k + 2], (double)reducer_w[(k0 + k + 2) * 64 + j], a2);
      a3 = fma(qsr[k0 + k + 3], (double)reducer_w[(k0 + k + 3) * 64 + j], a3);
    }
    ps[h][j] = (a0 + a1) + (a2 + a3);
  }
  __syncthreads();
  if (tid < 64) gi[tid] = (ps[0][tid] + ps[1][tid]) + (ps[2][tid] + ps[3][tid]);
  if (tid >= 64 && tid < 68) {
    const int e = tid - 64;
    double a0 = 0.0, a1 = 0.0, a2 = 0.0, a3 = 0.0;
    for (int k = 0; k < 256; k += 4) {
      a0 = fma(qsr[k + 0], (double)wgate_w[(k + 0) * 4 + e], a0);
      a1 = fma(qsr[k + 1], (double)wgate_w[(k + 1) * 4 + e], a1);
      a2 = fma(qsr[k + 2], (double)wgate_w[(k + 2) * 4 + e], a2);
      a3 = fma(qsr[k + 3], (double)wgate_w[(k + 3) * 4 + e], a3);
    }
    g_lq[(size_t)qq * 4 + e] = (a0 + a1) + (a2 + a3);
  }
  __syncthreads();
  if (tid < 192) {
    double a0 = 0.0, a1 = 0.0, a2 = 0.0, a3 = 0.0;
    for (int k = 0; k < 64; k += 4) {
      a0 = fma(gi[k + 0], (double)gru_w_ih[tid * 64 + k + 0], a0);
      a1 = fma(gi[k + 1], (double)gru_w_ih[tid * 64 + k + 1], a1);
      a2 = fma(gi[k + 2], (double)gru_w_ih[tid * 64 + k + 2], a2);
      a3 = fma(gi[k + 3], (double)gru_w_ih[tid * 64 + k + 3], a3);
    }
    g_xgf[(size_t)qq * 192 + tid] = (float)((a0 + a1) + (a2 + a3));
  }
}

// ---------------------------------------------------------------------------
// gru: one wave per sequence, NO barriers.  64 blocks x 64 threads.
// Lane j owns h[j] (fp64 carry in reg), full r/z/n dots per lane via
// wave-private LDS h mirror.  Wr/Wz rows in VGPRs (128 regs), Wn row in
// wave-private LDS [k][lane] (stride-1 b64, own-column reads, no sync).
// Packed v_pk_fma_f32 chains (bit-exact to the old scalar x/y pair chains).
// x staged fp32 per 8-step chunk (1-chunk pipeline, 2-chunk q/r lookahead),
// published as fp64 with the r-dependent xg fold (bit-exact: same single
// fp64 add, moved off the critical path).
// ---------------------------------------------------------------------------
__global__ void __launch_bounds__(64, 1) gru_kernel(
    const int* __restrict__ q, const int* __restrict__ r,
    const float* __restrict__ whh, const float* __restrict__ bhh)
{
  __shared__ __align__(16) double XB[2][GW][192];
  __shared__ __align__(16) float HF[64];
  __shared__ __align__(16) float WnL[32 * 128];   // [i][j] float2
  const int j = threadIdx.x;         // lane == thread
  const int b = blockIdx.x;

  // Wr/Wz rows for this lane, fp32 in VGPRs (as float2 pairs); Wn -> LDS.
  float2 Wr[32], Wz[32];
#pragma unroll
  for (int i = 0; i < 32; ++i) {
    Wr[i] = *(const float2*)(whh + (size_t)(0 * 64 + j) * 64 + 2 * i);
    Wz[i] = *(const float2*)(whh + (size_t)(1 * 64 + j) * 64 + 2 * i);
    const float2 wv = *(const float2*)(whh + (size_t)(2 * 64 + j) * 64 + 2 * i);
    *(float2*)&WnL[(i * 64 + j) * 2] = wv;       // own column, no sync needed
  }
  const double br = (double)bhh[j];
  const double bz = (double)bhh[64 + j];
  const double bn = (double)bhh[128 + j];
  const double xr0 = g_xgr[j],       xz0 = g_xgr[64 + j],       xn0 = g_xgr[128 + j];
  const double xr1 = g_xgr[192 + j], xz1 = g_xgr[256 + j],      xn1 = g_xgr[320 + j];

  // initial chunk 0 staging (fp64, r-fold applied)
  {
    int qv0 = 0, rv0 = 0;
    if (j > 0 && j < GW) {
      qv0 = q[b * 512 + j - 1];
      rv0 = r[b * 512 + j - 1];
    }
#pragma unroll
    for (int s = 0; s < GW; ++s) {
      double v0, v1, v2;
      if (s == 0) {       // start token: xg0 already holds b_ih; no r-term
        v0 = (double)g_xg0f[j];
        v1 = (double)g_xg0f[64 + j];
        v2 = (double)g_xg0f[128 + j];
      } else {
        const int qo = __shfl(qv0, s);
        const int rs = __shfl(rv0, s);
        const size_t base = (size_t)qo * 192 + j;
        v0 = (double)g_xgf[base]       + ((rs == 0) ? xr0 : xr1);
        v1 = (double)g_xgf[base + 64]  + ((rs == 0) ? xz0 : xz1);
        v2 = (double)g_xgf[base + 128] + ((rs == 0) ? xn0 : xn1);
      }
      XB[0][s][j] = v0; XB[0][s][64 + j] = v1; XB[0][s][128 + j] = v2;
    }
  }
  int qv_nxt = 0, rv_nxt = 0;
  if (j < GW) {
    const int tk = GW + j - 1;
    qv_nxt = q[b * 512 + tk];
    rv_nxt = r[b * 512 + tk];
  }
  HF[j] = 0.f;
  double hd = 0.0;

  int p = 0;
  for (int cc = 0; cc < 512 / GW; ++cc) {
    // stage loads for chunk cc+1 (fp32 regs; published after the 8 steps)
    float xs0[GW], xs1[GW], xs2[GW];
    if (cc < 512 / GW - 1) {
#pragma unroll
      for (int s = 0; s < GW; ++s) {
        const int qo = __shfl(qv_nxt, s);
        const size_t base = (size_t)qo * 192 + j;
        xs0[s] = g_xgf[base];
        xs1[s] = g_xgf[base + 64];
        xs2[s] = g_xgf[base + 128];
      }
    }
    // q/r lookahead for chunk cc+2
    int qv_n2 = 0, rv_n2 = 0;
    if (cc < 512 / GW - 2 && j < GW) {
      const int tk = (cc + 2) * GW + j - 1;
      qv_n2 = q[b * 512 + tk];
      rv_n2 = r[b * 512 + tk];
    }

    const int sbase = cc * GW;
#pragma unroll
    for (int sc = 0; sc < GW; ++sc) {
      const double xr = XB[p][sc][j];
      const double xz = XB[p][sc][64 + j];
      const double xn = XB[p][sc][128 + j];
      float2 ar = {0.f, 0.f}, az = {0.f, 0.f}, an = {0.f, 0.f};
      {
        const float4* hp = (const float4*)HF;
#pragma unroll
        for (int g = 0; g < 4; ++g) {
          const float4 t0 = hp[4 * g + 0];
          const float4 t1 = hp[4 * g + 1];
          const float4 t2 = hp[4 * g + 2];
          const float4 t3 = hp[4 * g + 3];
          float2 h8[8];
          h8[0] = make_float2(t0.x, t0.y); h8[1] = make_float2(t0.z, t0.w);
          h8[2] = make_float2(t1.x, t1.y); h8[3] = make_float2(t1.z, t1.w);
          h8[4] = make_float2(t2.x, t2.y); h8[5] = make_float2(t2.z, t2.w);
          h8[6] = make_float2(t3.x, t3.y); h8[7] = make_float2(t3.z, t3.w);
#pragma unroll
          for (int u = 0; u < 8; ++u) {
            const int i = 8 * g + u;
            const float2 wn = *(const float2*)&WnL[(i * 64 + j) * 2];
            pkfma(ar, Wr[i], h8[u]);
            pkfma(az, Wz[i], h8[u]);
            pkfma(an, wn,   h8[u]);
          }
        }
      }
      const double hr = br + (double)(ar.x + ar.y);
      const double hz = bz + (double)(az.x + az.y);
      const double hn = bn + (double)(an.x + an.y);
      const double pr = xr + hr, pz = xz + hz;
      double rg = fma(0.5, tpoly(0.5 * pr), 0.5);
      double zg = fma(0.5, tpoly(0.5 * pz), 0.5);
      double pre = fma(rg, hn, xn);
      double ng = tpoly(pre);
      const bool bad = (fabs(pr) > 0.5) | (fabs(pz) > 0.5) | (fabs(pre) > 0.25);
      if (bad) {   // rare slow path
        rg = 1.0 / (1.0 + fexp(-pr));
        zg = 1.0 / (1.0 + fexp(-pz));
        pre = fma(rg, hn, xn);
        ng = 1.0 - 2.0 / (fexp(pre + pre) + 1.0);
      }
      const double hnew = fma(zg, hd - ng, ng);   // (1-z)n + z h
      hd = hnew;
      const float hnf = (float)hnew;
      HF[j] = hnf;                                 // same-wave DS order
      g_m[((size_t)b * 512 + sbase + sc) * 64 + j] = hnf;
    }

    // publish staged x for chunk cc+1 (fp64 fold, identical single add)
    if (cc < 512 / GW - 1) {
#pragma unroll
      for (int s = 0; s < GW; ++s) {
        const int rs = __shfl(rv_nxt, s);
        XB[p ^ 1][s][j]       = (double)xs0[s] + ((rs == 0) ? xr0 : xr1);
        XB[p ^ 1][s][64 + j]  = (double)xs1[s] + ((rs == 0) ? xz0 : xz1);
        XB[p ^ 1][s][128 + j] = (double)xs2[s] + ((rs == 0) ? xn0 : xn1);
      }
    }
    qv_nxt = qv_n2; rv_nxt = rv_n2;
    p ^= 1;
  }
}

// ---------------------------------------------------------------------------
// top1: logits = lq[q_t] + m_t @ wgate[256:320] + wgate_b ; first-max argmax.
// m-row loads vectorized f32x4 (same fma order -> bit-exact).
// ---------------------------------------------------------------------------
__global__ void __launch_bounds__(256) top1_kernel(
    const int* __restrict__ q,
    const float* __restrict__ wgate_w, const float* __restrict__ wgate_b)
{
  __shared__ double w2[256];   // [j][e]
  const int tid = threadIdx.x;
  w2[tid] = (double)wgate_w[1024 + tid];
  __syncthreads();
  const int t = blockIdx.x * 256 + tid;
  const int qv = q[t];
  double l0 = g_lq[(size_t)qv * 4 + 0] + (double)wgate_b[0];
  double l1 = g_lq[(size_t)qv * 4 + 1] + (double)wgate_b[1];
  double l2 = g_lq[(size_t)qv * 4 + 2] + (double)wgate_b[2];
  double l3 = g_lq[(size_t)qv * 4 + 3] + (double)wgate_b[3];
  const f32x4* mr4 = (const f32x4*)(g_m + (size_t)t * 64);
#pragma unroll 4
  for (int jj = 0; jj < 16; ++jj) {
    const f32x4 mv4 = mr4[jj];
#pragma unroll
    for (int c = 0; c < 4; ++c) {
      const double mv = (double)mv4[c];
      const int k = (jj * 4 + c) * 4;
      l0 = fma(mv, w2[k + 0], l0);
      l1 = fma(mv, w2[k + 1], l1);
      l2 = fma(mv, w2[k + 2], l2);
      l3 = fma(mv, w2[k + 3], l3);
    }
  }
  int bi = 0; double bvv = l0;
  if (l1 > bvv) { bvv = l1; bi = 1; }
  if (l2 > bvv) { bvv = l2; bi = 2; }
  if (l3 > bvv) { bvv = l3; bi = 3; }
  g_top1[t] = bi;
}

// ---------------------------------------------------------------------------
// kernelE: per 32 q-values: stage emb rows as bf16; for each expert e:
// h1=relu(qr_e@W1+b1) -> out=h1@W2+b2 -> LN -> qf[q][e] bf16.
// ---------------------------------------------------------------------------
__global__ void __launch_bounds__(128) kernelE(
    const float* __restrict__ emb,
    const float* __restrict__ b1, const float* __restrict__ b2,
    const float* __restrict__ lng, const float* __restrict__ lnb)
{
  __shared__ __align__(16) unsigned short QR[32 * 1032];
  __shared__ __align__(16) unsigned short H1[32 * 264];
  __shared__ __align__(16) unsigned short EO[32 * 264];
  const int tid = threadIdx.x;
  const int t0 = blockIdx.x * 32;
  const int w = tid >> 6;
  const int lane = tid & 63;
  const int l15 = lane & 15;
  const int quad = lane >> 4;

  for (int c = 0; c < 64; ++c) {
    const int idx = c * 128 + tid;
    const int row = idx >> 8, col4 = idx & 255;
    const int qv = min(t0 + row, NQ - 1);
    f32x4 v = *(const f32x4*)(emb + (size_t)qv * 1024 + col4 * 4);
    unsigned a = ((unsigned)f2bf(v[1]) << 16) | f2bf(v[0]);
    unsigned bb = ((unsigned)f2bf(v[3]) << 16) | f2bf(v[2]);
    *(uint2*)&QR[row * 1032 + col4 * 4] = make_uint2(a, bb);
  }
  __syncthreads();

  const f32x4 z4 = {0.f, 0.f, 0.f, 0.f};
  const int n0 = w * 128;

  for (int e = 0; e < 4; ++e) {
    f32x4 acc[2][8];
#pragma unroll
    for (int a = 0; a < 2; ++a)
#pragma unroll
      for (int bq = 0; bq < 8; ++bq) acc[a][bq] = z4;
#pragma unroll
    for (int ks = 0; ks < 8; ++ks) {
      const int koff = e * 256 + ks * 32 + quad * 8;
      bf16x8 a0 = *(const bf16x8*)&QR[l15 * 1032 + koff];
      bf16x8 a1 = *(const bf16x8*)&QR[(16 + l15) * 1032 + koff];
      const int kb = ks * 32 + quad * 8;
#pragma unroll
      for (int nt = 0; nt < 8; ++nt) {
        bf16x8 bbv = *(const bf16x8*)(g_w1t + (size_t)e * 65536 +
                                      (size_t)(n0 + nt * 16 + l15) * 256 + kb);
        acc[0][nt] = mfma16(a0, bbv, acc[0][nt]);
        acc[1][nt] = mfma16(a1, bbv, acc[1][nt]);
      }
    }
#pragma unroll
    for (int nt = 0; nt < 8; ++nt) {
      const int n = n0 + nt * 16 + l15;
      const float b1v = b1[e * 256 + n];
#pragma unroll
      for (int mt = 0; mt < 2; ++mt)
#pragma unroll
        for (int rg = 0; rg < 4; ++rg) {
          const int m = mt * 16 + quad * 4 + rg;
          H1[m * 264 + n] = f2bf(fmaxf(acc[mt][nt][rg] + b1v, 0.f));
        }
    }
    __syncthreads();
    f32x4 acc2[2][8];
#pragma unroll
    for (int a = 0; a < 2; ++a)
#pragma unroll
      for (int bq = 0; bq < 8; ++bq) acc2[a][bq] = z4;
#pragma unroll
    for (int ks = 0; ks < 8; ++ks) {
      const int koff = ks * 32 + quad * 8;
      bf16x8 a0 = *(const bf16x8*)&H1[l15 * 264 + koff];
      bf16x8 a1 = *(const bf16x8*)&H1[(16 + l15) * 264 + koff];
#pragma unroll
      for (int nt = 0; nt < 8; ++nt) {
        bf16x8 bbv = *(const bf16x8*)(g_w2t + (size_t)e * 65536 +
                                      (size_t)(n0 + nt * 16 + l15) * 256 + koff);
        acc2[0][nt] = mfma16(a0, bbv, acc2[0][nt]);
        acc2[1][nt] = mfma16(a1, bbv, acc2[1][nt]);
      }
    }
#pragma unroll
    for (int nt = 0; nt < 8; ++nt) {
      const int n = n0 + nt * 16 + l15;
      const float b2v = b2[e * 256 + n];
#pragma unroll
      for (int mt = 0; mt < 2; ++mt)
#pragma unroll
        for (int rg = 0; rg < 4; ++rg) {
          const int m = mt * 16 + quad * 4 + rg;
          EO[m * 264 + n] = f2bf(acc2[mt][nt][rg] + b2v);
        }
    }
    __syncthreads();
    {
      const int m = tid >> 2;
      const int sub = tid & 3;
      float sx = 0.f, sxx = 0.f;
#pragma unroll
      for (int i = 0; i < 8; ++i) {
        bf16x8 v = *(const bf16x8*)&EO[m * 264 + sub * 64 + i * 8];
#pragma unroll
        for (int c = 0; c < 8; ++c) {
          const float f = bf2f((unsigned short)v[c]);
          sx += f; sxx += f * f;
        }
      }
      sx += __shfl_xor(sx, 1); sxx += __shfl_xor(sxx, 1);
      sx += __shfl_xor(sx, 2); sxx += __shfl_xor(sxx, 2);
      const float mu = sx * (1.f / 256.f);
      const float var = sxx * (1.f / 256.f) - mu * mu;
      const float inv = 1.f / sqrtf(var + 1e-5f);
      if (t0 + m < NQ) {
        const size_t base = ((size_t)(t0 + m) * 4 + e) * 256;
#pragma unroll
        for (int i = 0; i < 8; ++i) {
          const int dbase = sub * 64 + i * 8;
          bf16x8 v = *(const bf16x8*)&EO[m * 264 + dbase];
          bf16x8 ov;
#pragma unroll
          for (int c = 0; c < 8; ++c) {
            const int d = dbase + c;
            const float f = bf2f((unsigned short)v[c]);
            ov[c] = (short)f2bf(lng[d] * (f - mu) * inv + lnb[d]);
          }
          *(bf16x8*)(g_qf + base + dbase) = ov;
        }
      }
    }
    __syncthreads();
  }
}

// ---------------------------------------------------------------------------
// kernelF: per 32 tokens: gather qf[q_t][top1_t] -> q_fused out (fp32) and
// LDS; proj (cor|inc) bf16 MFMA; qa_fused by r.
// ---------------------------------------------------------------------------
__global__ void __launch_bounds__(128) kernelF(
    const int* __restrict__ q, const int* __restrict__ r,
    const float* __restrict__ pcb, const float* __restrict__ pib,
    float* __restrict__ out)
{
  __shared__ __align__(16) unsigned short QF[32 * 264];
  __shared__ int rv_l[32];
  const int tid = threadIdx.x;
  const int t0 = blockIdx.x * 32;
  const int w = tid >> 6;
  const int lane = tid & 63;
  const int l15 = lane & 15;
  const int quad = lane >> 4;
  if (tid < 32) rv_l[tid] = r[t0 + tid];
  __syncthreads();

  {
    const int m = tid >> 2;
    const size_t row = ((size_t)q[t0 + m] * 4 + g_top1[t0 + m]) * 256;
#pragma unroll
    for (int i = 0; i < 8; ++i) {
      const int dbase = (tid & 3) * 64 + i * 8;
      bf16x8 v = *(const bf16x8*)(g_qf + row + dbase);
      *(bf16x8*)&QF[m * 264 + dbase] = v;
      f32x4 f0, f1;
#pragma unroll
      for (int c = 0; c < 4; ++c) f0[c] = bf2f((unsigned short)v[c]);
#pragma unroll
      for (int c = 0; c < 4; ++c) f1[c] = bf2f((unsigned short)v[4 + c]);
      *(f32x4*)(out + (size_t)(t0 + m) * 256 + dbase) = f0;
      *(f32x4*)(out + (size_t)(t0 + m) * 256 + dbase + 4) = f1;
    }
  }
  __syncthreads();

  const f32x4 z4 = {0.f, 0.f, 0.f, 0.f};
  const int n0 = w * 128;
  for (int ph = 0; ph < 2; ++ph) {
    f32x4 acc[2][8];
#pragma unroll
    for (int a = 0; a < 2; ++a)
#pragma unroll
      for (int bq = 0; bq < 8; ++bq) acc[a][bq] = z4;
#pragma unroll
    for (int ks = 0; ks < 8; ++ks) {
      const int koff = ks * 32 + quad * 8;
      bf16x8 a0 = *(const bf16x8*)&QF[l15 * 264 + koff];
      bf16x8 a1 = *(const bf16x8*)&QF[(16 + l15) * 264 + koff];
#pragma unroll
      for (int nt = 0; nt < 8; ++nt) {
        bf16x8 bbv = *(const bf16x8*)(g_projt +
            (size_t)(ph * 256 + n0 + nt * 16 + l15) * 256 + koff);
        acc[0][nt] = mfma16(a0, bbv, acc[0][nt]);
        acc[1][nt] = mfma16(a1, bbv, acc[1][nt]);
      }
    }
    const float* pbb = ph ? pib : pcb;
    const int want = ph ? 0 : 1;
#pragma unroll
    for (int nt = 0; nt < 8; ++nt) {
      const int n = n0 + nt * 16 + l15;
      const float pbv = pbb[n];
#pragma unroll
      for (int mt = 0; mt < 2; ++mt)
#pragma unroll
        for (int rg = 0; rg < 4; ++rg) {
          const int m = mt * 16 + quad * 4 + rg;
          if (rv_l[m] == want)
            out[(size_t)TT * 256 + (size_t)(t0 + m) * 256 + n] =
                acc[mt][nt][rg] + pbv;
        }
    }
  }
}

// ---------------------------------------------------------------------------
extern "C" void kernel_launch(void* const* d_in, const int* in_sizes, int n_in,
                              void* d_out, int out_size, void* d_ws, size_t ws_size,
                              hipStream_t stream)
{
  const int*   q   = (const int*)d_in[0];
  const int*   r   = (const int*)d_in[1];
  const float* emb = (const float*)d_in[2];
  const float* ew1 = (const float*)d_in[3];
  const float* eb1 = (const float*)d_in[4];
  const float* ew2 = (const float*)d_in[5];
  const float* eb2 = (const float*)d_in[6];
  const float* aw  = (const float*)d_in[7];
  const float* ab  = (const float*)d_in[8];
  const float* rw  = (const float*)d_in[9];
  const float* rb  = (const float*)d_in[10];
  const float* st  = (const float*)d_in[11];
  const float* wih = (const float*)d_in[12];
  const float* whh = (const float*)d_in[13];
  const float* bih = (const float*)d_in[14];
  const float* bhh = (const float*)d_in[15];
  const float* wgw = (const float*)d_in[16];
  const float* wgb = (const float*)d_in[17];
  const float* lng = (const float*)d_in[18];
  const float* lnb = (const float*)d_in[19];
  const float* resp= (const float*)d_in[20];
  const float* pcw = (const float*)d_in[21];
  const float* pcb = (const float*)d_in[22];
  const float* piw = (const float*)d_in[23];
  const float* pib = (const float*)d_in[24];
  float* out = (float*)d_out;
  (void)bih; (void)in_sizes; (void)n_in; (void)d_ws; (void)ws_size; (void)out_size;

  prep_kernel<<<64, 256, 0, stream>>>(ew1, ew2, pcw, piw, resp, rw, rb, st, wih, bih);
  qsk_kernel<<<dim3(157, 4), 256, 0, stream>>>(emb, aw, ab);
  smallk_kernel<<<NQ, 256, 0, stream>>>(rw, wih, wgw);
  gru_kernel<<<64, 64, 0, stream>>>(q, r, whh, bhh);
  top1_kernel<<<128, 256, 0, stream>>>(q, wgw, wgb);
  kernelE<<<313, 128, 0, stream>>>(emb, eb1, eb2, lng, lnb);
  kernelF<<<1024, 128, 0, stream>>>(q, r, pcb, pib, out);
}

// Round 2
// 1176.690 us; speedup vs baseline: 1.0290x; 1.0290x over previous
//
#include <hip/hip_runtime.h>
#include <cstddef>

// ---------------------------------------------------------------------------
// PolyaAKT interaction embedder, MI355X/gfx950.  Inputs fp32, output fp32.
// Control path (logits/GRU) high-precision for argmax fidelity; value path
// (experts/LN/proj) in bf16 MFMA.  Per-q dedup throughout.
// R7: GRU weight residency forced (bit-exact vs R5/R6):
//  - Wr/Wz/Wn all in VGPRs, PINNED via empty asm ("+v") after load so the
//    allocator cannot rematerialize the global loads into the step loop
//    (R5 VGPR=144 / R6 VGPR=132 both proved remat was happening).
//  - v_pk_fma_f32 packed chains (bit-exact to scalar pair chains).
//  - r-select folded into fp64 XB at staging time (no per-step shfl).
//  - WnL LDS mirror removed (R6's regression: 32 ds_read_b64 on the
//    critical path per step).
// qsk reverted to R5 float-staged tiles (R6 double-staging regressed).
// top1 keeps f32x4 m-row loads.
// ---------------------------------------------------------------------------

#define NQ 10000
#define TT 32768   // B*S
#define GW 8       // GRU chunk steps

typedef __attribute__((ext_vector_type(8))) short bf16x8;
typedef __attribute__((ext_vector_type(4))) float f32x4;

__device__ double g_qs  [NQ * 256];      // q_summary (relu'd), fp64
__device__ float  g_xgf [NQ * 192];      // gru_in_q @ W_ih^T (fp32)
__device__ double g_xgr [2 * 192];       // r-part of xg (+b_ih), fp64
__device__ float  g_xg0f[192];           // start_token @ W_ih^T + b_ih (fp32)
__device__ double g_lq  [NQ * 4];        // qs @ wgate[0:256]
__device__ float  g_m   [TT * 64];       // GRU hidden per token (fp32)
__device__ int    g_top1[TT];
__device__ unsigned short g_w1t  [4 * 256 * 256];  // bf16 [e][n][k]
__device__ unsigned short g_w2t  [4 * 256 * 256];
__device__ unsigned short g_projt[512 * 256];      // bf16 [n(cor|inc)][k]
__device__ unsigned short g_qf   [NQ * 4 * 256];   // LN'd expert out, bf16

__device__ __forceinline__ float bf2f(unsigned short x) {
  return __uint_as_float(((unsigned)x) << 16);
}
__device__ __forceinline__ unsigned short f2bf(float f) {
  unsigned u = __float_as_uint(f);
  u += 0x7FFFu + ((u >> 16) & 1u);   // RNE
  return (unsigned short)(u >> 16);
}
__device__ __forceinline__ f32x4 mfma16(bf16x8 a, bf16x8 b, f32x4 c) {
  return __builtin_amdgcn_mfma_f32_16x16x32_bf16(a, b, c, 0, 0, 0);
}
// packed fp32 fma: c = a*b + c on both lanes of the pair (bit-identical to
// two scalar v_fma_f32, just one instruction).
__device__ __forceinline__ void pkfma(float2& c, float2 a, float2 b) {
  asm("v_pk_fma_f32 %0, %1, %2, %0" : "+v"(c) : "v"(a), "v"(b));
}

// fast fp64 exp (slow path only): range-reduced degree-10 poly, rel err ~2e-13.
__device__ __forceinline__ double fexp(double x) {
  const double L2E  = 1.4426950408889634074;
  const double LN2H = 6.93147180369123816490e-01;
  const double LN2L = 1.90821492927058770002e-10;
  double n = rint(x * L2E);
  int ni = (int)n;
  double r = fma(-n, LN2H, x);
  r = fma(-n, LN2L, r);
  double p = 2.7557319223985888e-07;
  p = fma(p, r, 2.7557319223985893e-06);
  p = fma(p, r, 2.4801587301587302e-05);
  p = fma(p, r, 1.9841269841269841e-04);
  p = fma(p, r, 1.3888888888888889e-03);
  p = fma(p, r, 8.3333333333333332e-03);
  p = fma(p, r, 4.1666666666666664e-02);
  p = fma(p, r, 1.6666666666666666e-01);
  p = fma(p, r, 0.5);
  p = fma(p, r, 1.0);
  p = fma(p, r, 1.0);
  return ldexp(p, ni);
}

// tanh via odd Taylor, |p| <= 0.25: abs err ~5e-11.
__device__ __forceinline__ double tpoly(double p) {
  const double p2 = p * p;
  double t = -1382.0 / 155925.0;          // p^11
  t = fma(t, p2, 62.0 / 2835.0);          // p^9
  t = fma(t, p2, -17.0 / 315.0);          // p^7
  t = fma(t, p2, 2.0 / 15.0);             // p^5
  t = fma(t, p2, -1.0 / 3.0);             // p^3
  t = fma(t, p2, 1.0);
  return p * t;
}

// ---------------------------------------------------------------------------
// prep: bf16 transposed weight tables + fp64 folds (xg_r, xg0).
// ---------------------------------------------------------------------------
__global__ void __launch_bounds__(256) prep_kernel(
    const float* __restrict__ expert_w1, const float* __restrict__ expert_w2,
    const float* __restrict__ proj_cor_w, const float* __restrict__ proj_inc_w,
    const float* __restrict__ resp_table, const float* __restrict__ reducer_w,
    const float* __restrict__ reducer_b,  const float* __restrict__ start_token,
    const float* __restrict__ gru_w_ih,   const float* __restrict__ gru_b_ih)
{
  __shared__ double red2f[128];   // [rr][j]
  const int tid = threadIdx.x;
  if (blockIdx.x == 0) {
    if (tid < 128) {
      const int rr = tid >> 6, j = tid & 63;
      double acc = (double)reducer_b[j];
      for (int k = 0; k < 256; ++k)
        acc += (double)resp_table[rr * 256 + k] *
               (double)reducer_w[(256 + k) * 64 + j];
      red2f[tid] = acc;
    }
    __syncthreads();
    if (tid < 192) {
      const double bih = (double)gru_b_ih[tid];
      double a0 = bih, a1 = bih, a2 = bih;
      for (int j = 0; j < 64; ++j) {
        const double w = (double)gru_w_ih[tid * 64 + j];
        a0 += red2f[j] * w;
        a1 += red2f[64 + j] * w;
        a2 += (double)start_token[j] * w;
      }
      g_xgr[tid] = a0; g_xgr[192 + tid] = a1; g_xg0f[tid] = (float)a2;
    }
  }
  const int idx0 = blockIdx.x * 256 + tid;
  const int stride = gridDim.x * 256;
  for (int i = idx0; i < 4 * 256 * 256; i += stride) {
    const int e = i >> 16, rem = i & 65535, n = rem >> 8, k = rem & 255;
    g_w1t[i] = f2bf(expert_w1[e * 65536 + k * 256 + n]);
    g_w2t[i] = f2bf(expert_w2[e * 65536 + k * 256 + n]);
  }
  for (int i = idx0; i < 512 * 256; i += stride) {
    const int n = i >> 8, k = i & 255;
    g_projt[i] = f2bf((n < 256) ? proj_cor_w[k * 256 + n]
                                : proj_inc_w[k * 256 + (n - 256)]);
  }
}

// ---------------------------------------------------------------------------
// qsk: fp64 GEMM  qs[q][n] = relu( emb_row_q(1024) . adapter_w[:,n] + b[n] )
// (R5 float-staged tiles; R6 double-staging regressed.)
// ---------------------------------------------------------------------------
__global__ void __launch_bounds__(256) qsk_kernel(
    const float* __restrict__ emb, const float* __restrict__ adapter_w,
    const float* __restrict__ adapter_b)
{
  __shared__ __align__(16) float As[64][33];
  __shared__ __align__(16) float Bs[32][65];
  const int tid = threadIdx.x;
  const int q0 = blockIdx.x * 64;
  const int n0 = blockIdx.y * 64;
  const int ty = tid >> 4, tx = tid & 15;

  double acc[4][4];
#pragma unroll
  for (int i = 0; i < 4; ++i)
#pragma unroll
    for (int j = 0; j < 4; ++j) acc[i][j] = 0.0;

  const int arow = tid >> 2, aks = (tid & 3) * 8;
  const int qa = min(q0 + arow, NQ - 1);
  const int bkk = tid >> 3, bns = (tid & 7) * 8;

  for (int kc = 0; kc < 1024; kc += 32) {
    f32x4 av0 = *(const f32x4*)(emb + (size_t)qa * 1024 + kc + aks);
    f32x4 av1 = *(const f32x4*)(emb + (size_t)qa * 1024 + kc + aks + 4);
    f32x4 bv0 = *(const f32x4*)(adapter_w + (size_t)(kc + bkk) * 256 + n0 + bns);
    f32x4 bv1 = *(const f32x4*)(adapter_w + (size_t)(kc + bkk) * 256 + n0 + bns + 4);
    __syncthreads();
#pragma unroll
    for (int i = 0; i < 4; ++i) { As[arow][aks + i] = av0[i]; As[arow][aks + 4 + i] = av1[i]; }
#pragma unroll
    for (int i = 0; i < 4; ++i) { Bs[bkk][bns + i] = bv0[i]; Bs[bkk][bns + 4 + i] = bv1[i]; }
    __syncthreads();
#pragma unroll 4
    for (int kk = 0; kk < 32; ++kk) {
      double a[4], b[4];
#pragma unroll
      for (int i = 0; i < 4; ++i) a[i] = (double)As[ty * 4 + i][kk];
#pragma unroll
      for (int j = 0; j < 4; ++j) b[j] = (double)Bs[kk][tx * 4 + j];
#pragma unroll
      for (int i = 0; i < 4; ++i)
#pragma unroll
        for (int j = 0; j < 4; ++j) acc[i][j] = fma(a[i], b[j], acc[i][j]);
    }
  }
#pragma unroll
  for (int i = 0; i < 4; ++i) {
    const int qrow = q0 + ty * 4 + i;
    if (qrow < NQ) {
#pragma unroll
      for (int j = 0; j < 4; ++j) {
        const int n = n0 + tx * 4 + j;
        double v = acc[i][j] + (double)adapter_b[n];
        g_qs[(size_t)qrow * 256 + n] = v > 0.0 ? v : 0.0;
      }
    }
  }
}

// ---------------------------------------------------------------------------
// smallk: per q -> gru_in_q(64), xg_q(192) fp32, lq(4).  One block per q.
// ---------------------------------------------------------------------------
__global__ void __launch_bounds__(256) smallk_kernel(
    const float* __restrict__ reducer_w, const float* __restrict__ gru_w_ih,
    const float* __restrict__ wgate_w)
{
  __shared__ double qsr[256];
  __shared__ double ps[4][64];
  __shared__ double gi[64];
  const int tid = threadIdx.x;
  const int qq = blockIdx.x;
  qsr[tid] = g_qs[(size_t)qq * 256 + tid];
  __syncthreads();
  {
    const int j = tid & 63, h = tid >> 6;
    const int k0 = h * 64;
    double a0 = 0.0, a1 = 0.0, a2 = 0.0, a3 = 0.0;
    for (int k = 0; k < 64; k += 4) {
      a0 = fma(qsr[k0 + k + 0], (double)reducer_w[(k0 + k + 0) * 64 + j], a0);
      a1 = fma(qsr[k0 + k + 1], (double)reducer_w[(k0 + k + 1) * 64 + j], a1);
      a2 = fma(qsr[k0 + k + 2], (double)reducer_w[(k0 + k + 2) * 64 + j], a2);
      a3 = fma(qsr[k0 + k + 3], (double)reducer_w[(k0 + k + 3) * 64 + j], a3);
    }
    ps[h][j] = (a0 + a1) + (a2 + a3);
  }
  __syncthreads();
  if (tid < 64) gi[tid] = (ps[0][tid] + ps[1][tid]) + (ps[2][tid] + ps[3][tid]);
  if (tid >= 64 && tid < 68) {
    const int e = tid - 64;
    double a0 = 0.0, a1 = 0.0, a2 = 0.0, a3 = 0.0;
    for (int k = 0; k < 256; k += 4) {
      a0 = fma(qsr[k + 0], (double)wgate_w[(k + 0) * 4 + e], a0);
      a1 = fma(qsr[k + 1], (double)wgate_w[(k + 1) * 4 + e], a1);
      a2 = fma(qsr[k + 2], (double)wgate_w[(k + 2) * 4 + e], a2);
      a3 = fma(qsr[k + 3], (double)wgate_w[(k + 3) * 4 + e], a3);
    }
    g_lq[(size_t)qq * 4 + e] = (a0 + a1) + (a2 + a3);
  }
  __syncthreads();
  if (tid < 192) {
    double a0 = 0.0, a1 = 0.0, a2 = 0.0, a3 = 0.0;
    for (int k = 0; k < 64; k += 4) {
      a0 = fma(gi[k + 0], (double)gru_w_ih[tid * 64 + k + 0], a0);
      a1 = fma(gi[k + 1], (double)gru_w_ih[tid * 64 + k + 1], a1);
      a2 = fma(gi[k + 2], (double)gru_w_ih[tid * 64 + k + 2], a2);
      a3 = fma(gi[k + 3], (double)gru_w_ih[tid * 64 + k + 3], a3);
    }
    g_xgf[(size_t)qq * 192 + tid] = (float)((a0 + a1) + (a2 + a3));
  }
}

// ---------------------------------------------------------------------------
// gru: one wave per sequence, NO barriers.  64 blocks x 64 threads.
// Lane j owns h[j] (fp64 carry in reg), full r/z/n dots per lane via
// wave-private LDS h mirror.  Wr/Wz/Wn rows in VGPRs, PINNED opaque so the
// allocator cannot sink the loads into the loop (192 regs + ~80 live ≈ 270,
// fits the 512-VGPR budget at 1 wave/SIMD).
// Packed v_pk_fma_f32 chains (bit-exact to scalar x/y pair chains).
// x staged fp32 per 8-step chunk (1-chunk pipeline, 2-chunk q/r lookahead),
// published as fp64 with the r-dependent xg fold (bit-exact: same single
// fp64 add, moved off the critical path).
// ---------------------------------------------------------------------------
__global__ void __launch_bounds__(64, 1) gru_kernel(
    const int* __restrict__ q, const int* __restrict__ r,
    const float* __restrict__ whh, const float* __restrict__ bhh)
{
  __shared__ __align__(16) double XB[2][GW][192];
  __shared__ __align__(16) float HF[64];
  const int j = threadIdx.x;         // lane == thread
  const int b = blockIdx.x;

  // W rows for this lane, fp32 in VGPRs (as float2 pairs), pinned resident.
  float2 Wr[32], Wz[32], Wn[32];
#pragma unroll
  for (int i = 0; i < 32; ++i) {
    Wr[i] = *(const float2*)(whh + (size_t)(0 * 64 + j) * 64 + 2 * i);
    Wz[i] = *(const float2*)(whh + (size_t)(1 * 64 + j) * 64 + 2 * i);
    Wn[i] = *(const float2*)(whh + (size_t)(2 * 64 + j) * 64 + 2 * i);
  }
#pragma unroll
  for (int i = 0; i < 32; ++i) {
    asm volatile("" : "+v"(Wr[i]));
    asm volatile("" : "+v"(Wz[i]));
    asm volatile("" : "+v"(Wn[i]));
  }
  const double br = (double)bhh[j];
  const double bz = (double)bhh[64 + j];
  const double bn = (double)bhh[128 + j];
  const double xr0 = g_xgr[j],       xz0 = g_xgr[64 + j],       xn0 = g_xgr[128 + j];
  const double xr1 = g_xgr[192 + j], xz1 = g_xgr[256 + j],      xn1 = g_xgr[320 + j];

  // initial chunk 0 staging (fp64, r-fold applied)
  {
    int qv0 = 0, rv0 = 0;
    if (j > 0 && j < GW) {
      qv0 = q[b * 512 + j - 1];
      rv0 = r[b * 512 + j - 1];
    }
#pragma unroll
    for (int s = 0; s < GW; ++s) {
      double v0, v1, v2;
      if (s == 0) {       // start token: xg0 already holds b_ih; no r-term
        v0 = (double)g_xg0f[j];
        v1 = (double)g_xg0f[64 + j];
        v2 = (double)g_xg0f[128 + j];
      } else {
        const int qo = __shfl(qv0, s);
        const int rs = __shfl(rv0, s);
        const size_t base = (size_t)qo * 192 + j;
        v0 = (double)g_xgf[base]       + ((rs == 0) ? xr0 : xr1);
        v1 = (double)g_xgf[base + 64]  + ((rs == 0) ? xz0 : xz1);
        v2 = (double)g_xgf[base + 128] + ((rs == 0) ? xn0 : xn1);
      }
      XB[0][s][j] = v0; XB[0][s][64 + j] = v1; XB[0][s][128 + j] = v2;
    }
  }
  int qv_nxt = 0, rv_nxt = 0;
  if (j < GW) {
    const int tk = GW + j - 1;
    qv_nxt = q[b * 512 + tk];
    rv_nxt = r[b * 512 + tk];
  }
  HF[j] = 0.f;
  double hd = 0.0;

  int p = 0;
  for (int cc = 0; cc < 512 / GW; ++cc) {
    // stage loads for chunk cc+1 (fp32 regs; published after the 8 steps)
    float xs0[GW], xs1[GW], xs2[GW];
    if (cc < 512 / GW - 1) {
#pragma unroll
      for (int s = 0; s < GW; ++s) {
        const int qo = __shfl(qv_nxt, s);
        const size_t base = (size_t)qo * 192 + j;
        xs0[s] = g_xgf[base];
        xs1[s] = g_xgf[base + 64];
        xs2[s] = g_xgf[base + 128];
      }
    }
    // q/r lookahead for chunk cc+2
    int qv_n2 = 0, rv_n2 = 0;
    if (cc < 512 / GW - 2 && j < GW) {
      const int tk = (cc + 2) * GW + j - 1;
      qv_n2 = q[b * 512 + tk];
      rv_n2 = r[b * 512 + tk];
    }

    const int sbase = cc * GW;
#pragma unroll
    for (int sc = 0; sc < GW; ++sc) {
      const double xr = XB[p][sc][j];
      const double xz = XB[p][sc][64 + j];
      const double xn = XB[p][sc][128 + j];
      float2 ar = {0.f, 0.f}, az = {0.f, 0.f}, an = {0.f, 0.f};
      {
        const float4* hp = (const float4*)HF;
#pragma unroll
        for (int g = 0; g < 4; ++g) {
          const float4 t0 = hp[4 * g + 0];
          const float4 t1 = hp[4 * g + 1];
          const float4 t2 = hp[4 * g + 2];
          const float4 t3 = hp[4 * g + 3];
          float2 h8[8];
          h8[0] = make_float2(t0.x, t0.y); h8[1] = make_float2(t0.z, t0.w);
          h8[2] = make_float2(t1.x, t1.y); h8[3] = make_float2(t1.z, t1.w);
          h8[4] = make_float2(t2.x, t2.y); h8[5] = make_float2(t2.z, t2.w);
          h8[6] = make_float2(t3.x, t3.y); h8[7] = make_float2(t3.z, t3.w);
#pragma unroll
          for (int u = 0; u < 8; ++u) {
            const int i = 8 * g + u;
            pkfma(ar, Wr[i], h8[u]);
            pkfma(az, Wz[i], h8[u]);
            pkfma(an, Wn[i], h8[u]);
          }
        }
      }
      const double hr = br + (double)(ar.x + ar.y);
      const double hz = bz + (double)(az.x + az.y);
      const double hn = bn + (double)(an.x + an.y);
      const double pr = xr + hr, pz = xz + hz;
      double rg = fma(0.5, tpoly(0.5 * pr), 0.5);
      double zg = fma(0.5, tpoly(0.5 * pz), 0.5);
      double pre = fma(rg, hn, xn);
      double ng = tpoly(pre);
      const bool bad = (fabs(pr) > 0.5) | (fabs(pz) > 0.5) | (fabs(pre) > 0.25);
      if (bad) {   // rare slow path
        rg = 1.0 / (1.0 + fexp(-pr));
        zg = 1.0 / (1.0 + fexp(-pz));
        pre = fma(rg, hn, xn);
        ng = 1.0 - 2.0 / (fexp(pre + pre) + 1.0);
      }
      const double hnew = fma(zg, hd - ng, ng);   // (1-z)n + z h
      hd = hnew;
      const float hnf = (float)hnew;
      HF[j] = hnf;                                 // same-wave DS order
      g_m[((size_t)b * 512 + sbase + sc) * 64 + j] = hnf;
    }

    // publish staged x for chunk cc+1 (fp64 fold, identical single add)
    if (cc < 512 / GW - 1) {
#pragma unroll
      for (int s = 0; s < GW; ++s) {
        const int rs = __shfl(rv_nxt, s);
        XB[p ^ 1][s][j]       = (double)xs0[s] + ((rs == 0) ? xr0 : xr1);
        XB[p ^ 1][s][64 + j]  = (double)xs1[s] + ((rs == 0) ? xz0 : xz1);
        XB[p ^ 1][s][128 + j] = (double)xs2[s] + ((rs == 0) ? xn0 : xn1);
      }
    }
    qv_nxt = qv_n2; rv_nxt = rv_n2;
    p ^= 1;
  }
}

// ---------------------------------------------------------------------------
// top1: logits = lq[q_t] + m_t @ wgate[256:320] + wgate_b ; first-max argmax.
// m-row loads vectorized f32x4 (same fma order -> bit-exact).
// ---------------------------------------------------------------------------
__global__ void __launch_bounds__(256) top1_kernel(
    const int* __restrict__ q,
    const float* __restrict__ wgate_w, const float* __restrict__ wgate_b)
{
  __shared__ double w2[256];   // [j][e]
  const int tid = threadIdx.x;
  w2[tid] = (double)wgate_w[1024 + tid];
  __syncthreads();
  const int t = blockIdx.x * 256 + tid;
  const int qv = q[t];
  double l0 = g_lq[(size_t)qv * 4 + 0] + (double)wgate_b[0];
  double l1 = g_lq[(size_t)qv * 4 + 1] + (double)wgate_b[1];
  double l2 = g_lq[(size_t)qv * 4 + 2] + (double)wgate_b[2];
  double l3 = g_lq[(size_t)qv * 4 + 3] + (double)wgate_b[3];
  const f32x4* mr4 = (const f32x4*)(g_m + (size_t)t * 64);
#pragma unroll 4
  for (int jj = 0; jj < 16; ++jj) {
    const f32x4 mv4 = mr4[jj];
#pragma unroll
    for (int c = 0; c < 4; ++c) {
      const double mv = (double)mv4[c];
      const int k = (jj * 4 + c) * 4;
      l0 = fma(mv, w2[k + 0], l0);
      l1 = fma(mv, w2[k + 1], l1);
      l2 = fma(mv, w2[k + 2], l2);
      l3 = fma(mv, w2[k + 3], l3);
    }
  }
  int bi = 0; double bvv = l0;
  if (l1 > bvv) { bvv = l1; bi = 1; }
  if (l2 > bvv) { bvv = l2; bi = 2; }
  if (l3 > bvv) { bvv = l3; bi = 3; }
  g_top1[t] = bi;
}

// ---------------------------------------------------------------------------
// kernelE: per 32 q-values: stage emb rows as bf16; for each expert e:
// h1=relu(qr_e@W1+b1) -> out=h1@W2+b2 -> LN -> qf[q][e] bf16.
// ---------------------------------------------------------------------------
__global__ void __launch_bounds__(128) kernelE(
    const float* __restrict__ emb,
    const float* __restrict__ b1, const float* __restrict__ b2,
    const float* __restrict__ lng, const float* __restrict__ lnb)
{
  __shared__ __align__(16) unsigned short QR[32 * 1032];
  __shared__ __align__(16) unsigned short H1[32 * 264];
  __shared__ __align__(16) unsigned short EO[32 * 264];
  const int tid = threadIdx.x;
  const int t0 = blockIdx.x * 32;
  const int w = tid >> 6;
  const int lane = tid & 63;
  const int l15 = lane & 15;
  const int quad = lane >> 4;

  for (int c = 0; c < 64; ++c) {
    const int idx = c * 128 + tid;
    const int row = idx >> 8, col4 = idx & 255;
    const int qv = min(t0 + row, NQ - 1);
    f32x4 v = *(const f32x4*)(emb + (size_t)qv * 1024 + col4 * 4);
    unsigned a = ((unsigned)f2bf(v[1]) << 16) | f2bf(v[0]);
    unsigned bb = ((unsigned)f2bf(v[3]) << 16) | f2bf(v[2]);
    *(uint2*)&QR[row * 1032 + col4 * 4] = make_uint2(a, bb);
  }
  __syncthreads();

  const f32x4 z4 = {0.f, 0.f, 0.f, 0.f};
  const int n0 = w * 128;

  for (int e = 0; e < 4; ++e) {
    f32x4 acc[2][8];
#pragma unroll
    for (int a = 0; a < 2; ++a)
#pragma unroll
      for (int bq = 0; bq < 8; ++bq) acc[a][bq] = z4;
#pragma unroll
    for (int ks = 0; ks < 8; ++ks) {
      const int koff = e * 256 + ks * 32 + quad * 8;
      bf16x8 a0 = *(const bf16x8*)&QR[l15 * 1032 + koff];
      bf16x8 a1 = *(const bf16x8*)&QR[(16 + l15) * 1032 + koff];
      const int kb = ks * 32 + quad * 8;
#pragma unroll
      for (int nt = 0; nt < 8; ++nt) {
        bf16x8 bbv = *(const bf16x8*)(g_w1t + (size_t)e * 65536 +
                                      (size_t)(n0 + nt * 16 + l15) * 256 + kb);
        acc[0][nt] = mfma16(a0, bbv, acc[0][nt]);
        acc[1][nt] = mfma16(a1, bbv, acc[1][nt]);
      }
    }
#pragma unroll
    for (int nt = 0; nt < 8; ++nt) {
      const int n = n0 + nt * 16 + l15;
      const float b1v = b1[e * 256 + n];
#pragma unroll
      for (int mt = 0; mt < 2; ++mt)
#pragma unroll
        for (int rg = 0; rg < 4; ++rg) {
          const int m = mt * 16 + quad * 4 + rg;
          H1[m * 264 + n] = f2bf(fmaxf(acc[mt][nt][rg] + b1v, 0.f));
        }
    }
    __syncthreads();
    f32x4 acc2[2][8];
#pragma unroll
    for (int a = 0; a < 2; ++a)
#pragma unroll
      for (int bq = 0; bq < 8; ++bq) acc2[a][bq] = z4;
#pragma unroll
    for (int ks = 0; ks < 8; ++ks) {
      const int koff = ks * 32 + quad * 8;
      bf16x8 a0 = *(const bf16x8*)&H1[l15 * 264 + koff];
      bf16x8 a1 = *(const bf16x8*)&H1[(16 + l15) * 264 + koff];
#pragma unroll
      for (int nt = 0; nt < 8; ++nt) {
        bf16x8 bbv = *(const bf16x8*)(g_w2t + (size_t)e * 65536 +
                                      (size_t)(n0 + nt * 16 + l15) * 256 + koff);
        acc2[0][nt] = mfma16(a0, bbv, acc2[0][nt]);
        acc2[1][nt] = mfma16(a1, bbv, acc2[1][nt]);
      }
    }
#pragma unroll
    for (int nt = 0; nt < 8; ++nt) {
      const int n = n0 + nt * 16 + l15;
      const float b2v = b2[e * 256 + n];
#pragma unroll
      for (int mt = 0; mt < 2; ++mt)
#pragma unroll
        for (int rg = 0; rg < 4; ++rg) {
          const int m = mt * 16 + quad * 4 + rg;
          EO[m * 264 + n] = f2bf(acc2[mt][nt][rg] + b2v);
        }
    }
    __syncthreads();
    {
      const int m = tid >> 2;
      const int sub = tid & 3;
      float sx = 0.f, sxx = 0.f;
#pragma unroll
      for (int i = 0; i < 8; ++i) {
        bf16x8 v = *(const bf16x8*)&EO[m * 264 + sub * 64 + i * 8];
#pragma unroll
        for (int c = 0; c < 8; ++c) {
          const float f = bf2f((unsigned short)v[c]);
          sx += f; sxx += f * f;
        }
      }
      sx += __shfl_xor(sx, 1); sxx += __shfl_xor(sxx, 1);
      sx += __shfl_xor(sx, 2); sxx += __shfl_xor(sxx, 2);
      const float mu = sx * (1.f / 256.f);
      const float var = sxx * (1.f / 256.f) - mu * mu;
      const float inv = 1.f / sqrtf(var + 1e-5f);
      if (t0 + m < NQ) {
        const size_t base = ((size_t)(t0 + m) * 4 + e) * 256;
#pragma unroll
        for (int i = 0; i < 8; ++i) {
          const int dbase = sub * 64 + i * 8;
          bf16x8 v = *(const bf16x8*)&EO[m * 264 + dbase];
          bf16x8 ov;
#pragma unroll
          for (int c = 0; c < 8; ++c) {
            const int d = dbase + c;
            const float f = bf2f((unsigned short)v[c]);
            ov[c] = (short)f2bf(lng[d] * (f - mu) * inv + lnb[d]);
          }
          *(bf16x8*)(g_qf + base + dbase) = ov;
        }
      }
    }
    __syncthreads();
  }
}

// ---------------------------------------------------------------------------
// kernelF: per 32 tokens: gather qf[q_t][top1_t] -> q_fused out (fp32) and
// LDS; proj (cor|inc) bf16 MFMA; qa_fused by r.
// ---------------------------------------------------------------------------
__global__ void __launch_bounds__(128) kernelF(
    const int* __restrict__ q, const int* __restrict__ r,
    const float* __restrict__ pcb, const float* __restrict__ pib,
    float* __restrict__ out)
{
  __shared__ __align__(16) unsigned short QF[32 * 264];
  __shared__ int rv_l[32];
  const int tid = threadIdx.x;
  const int t0 = blockIdx.x * 32;
  const int w = tid >> 6;
  const int lane = tid & 63;
  const int l15 = lane & 15;
  const int quad = lane >> 4;
  if (tid < 32) rv_l[tid] = r[t0 + tid];
  __syncthreads();

  {
    const int m = tid >> 2;
    const size_t row = ((size_t)q[t0 + m] * 4 + g_top1[t0 + m]) * 256;
#pragma unroll
    for (int i = 0; i < 8; ++i) {
      const int dbase = (tid & 3) * 64 + i * 8;
      bf16x8 v = *(const bf16x8*)(g_qf + row + dbase);
      *(bf16x8*)&QF[m * 264 + dbase] = v;
      f32x4 f0, f1;
#pragma unroll
      for (int c = 0; c < 4; ++c) f0[c] = bf2f((unsigned short)v[c]);
#pragma unroll
      for (int c = 0; c < 4; ++c) f1[c] = bf2f((unsigned short)v[4 + c]);
      *(f32x4*)(out + (size_t)(t0 + m) * 256 + dbase) = f0;
      *(f32x4*)(out + (size_t)(t0 + m) * 256 + dbase + 4) = f1;
    }
  }
  __syncthreads();

  const f32x4 z4 = {0.f, 0.f, 0.f, 0.f};
  const int n0 = w * 128;
  for (int ph = 0; ph < 2; ++ph) {
    f32x4 acc[2][8];
#pragma unroll
    for (int a = 0; a < 2; ++a)
#pragma unroll
      for (int bq = 0; bq < 8; ++bq) acc[a][bq] = z4;
#pragma unroll
    for (int ks = 0; ks < 8; ++ks) {
      const int koff = ks * 32 + quad * 8;
      bf16x8 a0 = *(const bf16x8*)&QF[l15 * 264 + koff];
      bf16x8 a1 = *(const bf16x8*)&QF[(16 + l15) * 264 + koff];
#pragma unroll
      for (int nt = 0; nt < 8; ++nt) {
        bf16x8 bbv = *(const bf16x8*)(g_projt +
            (size_t)(ph * 256 + n0 + nt * 16 + l15) * 256 + koff);
        acc[0][nt] = mfma16(a0, bbv, acc[0][nt]);
        acc[1][nt] = mfma16(a1, bbv, acc[1][nt]);
      }
    }
    const float* pbb = ph ? pib : pcb;
    const int want = ph ? 0 : 1;
#pragma unroll
    for (int nt = 0; nt < 8; ++nt) {
      const int n = n0 + nt * 16 + l15;
      const float pbv = pbb[n];
#pragma unroll
      for (int mt = 0; mt < 2; ++mt)
#pragma unroll
        for (int rg = 0; rg < 4; ++rg) {
          const int m = mt * 16 + quad * 4 + rg;
          if (rv_l[m] == want)
            out[(size_t)TT * 256 + (size_t)(t0 + m) * 256 + n] =
                acc[mt][nt][rg] + pbv;
        }
    }
  }
}

// ---------------------------------------------------------------------------
extern "C" void kernel_launch(void* const* d_in, const int* in_sizes, int n_in,
                              void* d_out, int out_size, void* d_ws, size_t ws_size,
                              hipStream_t stream)
{
  const int*   q   = (const int*)d_in[0];
  const int*   r   = (const int*)d_in[1];
  const float* emb = (const float*)d_in[2];
  const float* ew1 = (const float*)d_in[3];
  const float* eb1 = (const float*)d_in[4];
  const float* ew2 = (const float*)d_in[5];
  const float* eb2 = (const float*)d_in[6];
  const float* aw  = (const float*)d_in[7];
  const float* ab  = (const float*)d_in[8];
  const float* rw  = (const float*)d_in[9];
  const float* rb  = (const float*)d_in[10];
  const float* st  = (const float*)d_in[11];
  const float* wih = (const float*)d_in[12];
  const float* whh = (const float*)d_in[13];
  const float* bih = (const float*)d_in[14];
  const float* bhh = (const float*)d_in[15];
  const float* wgw = (const float*)d_in[16];
  const float* wgb = (const float*)d_in[17];
  const float* lng = (const float*)d_in[18];
  const float* lnb = (const float*)d_in[19];
  const float* resp= (const float*)d_in[20];
  const float* pcw = (const float*)d_in[21];
  const float* pcb = (const float*)d_in[22];
  const float* piw = (const float*)d_in[23];
  const float* pib = (const float*)d_in[24];
  float* out = (float*)d_out;
  (void)bih; (void)in_sizes; (void)n_in; (void)d_ws; (void)ws_size; (void)out_size;

  prep_kernel<<<64, 256, 0, stream>>>(ew1, ew2, pcw, piw, resp, rw, rb, st, wih, bih);
  qsk_kernel<<<dim3(157, 4), 256, 0, stream>>>(emb, aw, ab);
  smallk_kernel<<<NQ, 256, 0, stream>>>(rw, wih, wgw);
  gru_kernel<<<64, 64, 0, stream>>>(q, r, whh, bhh);
  top1_kernel<<<128, 256, 0, stream>>>(q, wgw, wgb);
  kernelE<<<313, 128, 0, stream>>>(emb, eb1, eb2, lng, lnb);
  kernelF<<<1024, 128, 0, stream>>>(q, r, pcb, pib, out);
}

// Round 3
// 1092.359 us; speedup vs baseline: 1.1084x; 1.0772x over previous
//
#include <hip/hip_runtime.h>
#include <cstddef>

// ---------------------------------------------------------------------------
// PolyaAKT interaction embedder, MI355X/gfx950.  Inputs fp32, output fp32.
// Control path (logits/GRU) high-precision for argmax fidelity; value path
// (experts/LN/proj) in bf16 MFMA.  Per-q dedup throughout.
// R8: GRU slimmed below the 256-arch-VGPR cap so W_hh is truly resident:
//  - R5/R6/R7 all hit the same wall: live set (W 192 + staging 24 + r-fold
//    consts 12 + fp64 temps) > 256 addressable VGPRs -> allocator remats W
//    from memory every step (VGPR_Count 132-148 proved it).
//  - Fix: precompute r-folded x table g_xq2[q][r][192] fp32 in smallk
//    (one extra fp32 rounding ~1e-8, far below the reference's own fp32
//    noise ~1e-6 -> argmax decisions unaffected).  GRU loses ALL chunk
//    staging (XB LDS, xs regs, fold consts, shfl pipeline): per step it
//    prefetches 3 floats + q/r one step ahead (~10 regs).  Live set ~230.
//  - LDS = 64-float HF mirror only.  W pinned after load (anti-remat).
// ---------------------------------------------------------------------------

#define NQ 10000
#define TT 32768   // B*S

typedef __attribute__((ext_vector_type(8))) short bf16x8;
typedef __attribute__((ext_vector_type(4))) float f32x4;

__device__ double g_qs  [NQ * 256];      // q_summary (relu'd), fp64
__device__ double g_xgr [2 * 192];       // r-part of xg (+b_ih), fp64
__device__ float  g_xg0f[192];           // start_token @ W_ih^T + b_ih (fp32)
__device__ float  g_xq2 [NQ * 384];      // r-folded xg: [q][r][192] fp32
__device__ double g_lq  [NQ * 4];        // qs @ wgate[0:256]
__device__ float  g_m   [TT * 64];       // GRU hidden per token (fp32)
__device__ int    g_top1[TT];
__device__ unsigned short g_w1t  [4 * 256 * 256];  // bf16 [e][n][k]
__device__ unsigned short g_w2t  [4 * 256 * 256];
__device__ unsigned short g_projt[512 * 256];      // bf16 [n(cor|inc)][k]
__device__ unsigned short g_qf   [NQ * 4 * 256];   // LN'd expert out, bf16

__device__ __forceinline__ float bf2f(unsigned short x) {
  return __uint_as_float(((unsigned)x) << 16);
}
__device__ __forceinline__ unsigned short f2bf(float f) {
  unsigned u = __float_as_uint(f);
  u += 0x7FFFu + ((u >> 16) & 1u);   // RNE
  return (unsigned short)(u >> 16);
}
__device__ __forceinline__ f32x4 mfma16(bf16x8 a, bf16x8 b, f32x4 c) {
  return __builtin_amdgcn_mfma_f32_16x16x32_bf16(a, b, c, 0, 0, 0);
}
// packed fp32 fma: c = a*b + c on both lanes of the pair (bit-identical to
// two scalar v_fma_f32, just one instruction).
__device__ __forceinline__ void pkfma(float2& c, float2 a, float2 b) {
  asm("v_pk_fma_f32 %0, %1, %2, %0" : "+v"(c) : "v"(a), "v"(b));
}

// fast fp64 exp (slow path only): range-reduced degree-10 poly, rel err ~2e-13.
__device__ __forceinline__ double fexp(double x) {
  const double L2E  = 1.4426950408889634074;
  const double LN2H = 6.93147180369123816490e-01;
  const double LN2L = 1.90821492927058770002e-10;
  double n = rint(x * L2E);
  int ni = (int)n;
  double r = fma(-n, LN2H, x);
  r = fma(-n, LN2L, r);
  double p = 2.7557319223985888e-07;
  p = fma(p, r, 2.7557319223985893e-06);
  p = fma(p, r, 2.4801587301587302e-05);
  p = fma(p, r, 1.9841269841269841e-04);
  p = fma(p, r, 1.3888888888888889e-03);
  p = fma(p, r, 8.3333333333333332e-03);
  p = fma(p, r, 4.1666666666666664e-02);
  p = fma(p, r, 1.6666666666666666e-01);
  p = fma(p, r, 0.5);
  p = fma(p, r, 1.0);
  p = fma(p, r, 1.0);
  return ldexp(p, ni);
}

// tanh via odd Taylor, |p| <= 0.25: abs err ~5e-11.
__device__ __forceinline__ double tpoly(double p) {
  const double p2 = p * p;
  double t = -1382.0 / 155925.0;          // p^11
  t = fma(t, p2, 62.0 / 2835.0);          // p^9
  t = fma(t, p2, -17.0 / 315.0);          // p^7
  t = fma(t, p2, 2.0 / 15.0);             // p^5
  t = fma(t, p2, -1.0 / 3.0);             // p^3
  t = fma(t, p2, 1.0);
  return p * t;
}

// ---------------------------------------------------------------------------
// prep: bf16 transposed weight tables + fp64 folds (xg_r, xg0).
// ---------------------------------------------------------------------------
__global__ void __launch_bounds__(256) prep_kernel(
    const float* __restrict__ expert_w1, const float* __restrict__ expert_w2,
    const float* __restrict__ proj_cor_w, const float* __restrict__ proj_inc_w,
    const float* __restrict__ resp_table, const float* __restrict__ reducer_w,
    const float* __restrict__ reducer_b,  const float* __restrict__ start_token,
    const float* __restrict__ gru_w_ih,   const float* __restrict__ gru_b_ih)
{
  __shared__ double red2f[128];   // [rr][j]
  const int tid = threadIdx.x;
  if (blockIdx.x == 0) {
    if (tid < 128) {
      const int rr = tid >> 6, j = tid & 63;
      double acc = (double)reducer_b[j];
      for (int k = 0; k < 256; ++k)
        acc += (double)resp_table[rr * 256 + k] *
               (double)reducer_w[(256 + k) * 64 + j];
      red2f[tid] = acc;
    }
    __syncthreads();
    if (tid < 192) {
      const double bih = (double)gru_b_ih[tid];
      double a0 = bih, a1 = bih, a2 = bih;
      for (int j = 0; j < 64; ++j) {
        const double w = (double)gru_w_ih[tid * 64 + j];
        a0 += red2f[j] * w;
        a1 += red2f[64 + j] * w;
        a2 += (double)start_token[j] * w;
      }
      g_xgr[tid] = a0; g_xgr[192 + tid] = a1; g_xg0f[tid] = (float)a2;
    }
  }
  const int idx0 = blockIdx.x * 256 + tid;
  const int stride = gridDim.x * 256;
  for (int i = idx0; i < 4 * 256 * 256; i += stride) {
    const int e = i >> 16, rem = i & 65535, n = rem >> 8, k = rem & 255;
    g_w1t[i] = f2bf(expert_w1[e * 65536 + k * 256 + n]);
    g_w2t[i] = f2bf(expert_w2[e * 65536 + k * 256 + n]);
  }
  for (int i = idx0; i < 512 * 256; i += stride) {
    const int n = i >> 8, k = i & 255;
    g_projt[i] = f2bf((n < 256) ? proj_cor_w[k * 256 + n]
                                : proj_inc_w[k * 256 + (n - 256)]);
  }
}

// ---------------------------------------------------------------------------
// qsk: fp64 GEMM  qs[q][n] = relu( emb_row_q(1024) . adapter_w[:,n] + b[n] )
// ---------------------------------------------------------------------------
__global__ void __launch_bounds__(256) qsk_kernel(
    const float* __restrict__ emb, const float* __restrict__ adapter_w,
    const float* __restrict__ adapter_b)
{
  __shared__ __align__(16) float As[64][33];
  __shared__ __align__(16) float Bs[32][65];
  const int tid = threadIdx.x;
  const int q0 = blockIdx.x * 64;
  const int n0 = blockIdx.y * 64;
  const int ty = tid >> 4, tx = tid & 15;

  double acc[4][4];
#pragma unroll
  for (int i = 0; i < 4; ++i)
#pragma unroll
    for (int j = 0; j < 4; ++j) acc[i][j] = 0.0;

  const int arow = tid >> 2, aks = (tid & 3) * 8;
  const int qa = min(q0 + arow, NQ - 1);
  const int bkk = tid >> 3, bns = (tid & 7) * 8;

  for (int kc = 0; kc < 1024; kc += 32) {
    f32x4 av0 = *(const f32x4*)(emb + (size_t)qa * 1024 + kc + aks);
    f32x4 av1 = *(const f32x4*)(emb + (size_t)qa * 1024 + kc + aks + 4);
    f32x4 bv0 = *(const f32x4*)(adapter_w + (size_t)(kc + bkk) * 256 + n0 + bns);
    f32x4 bv1 = *(const f32x4*)(adapter_w + (size_t)(kc + bkk) * 256 + n0 + bns + 4);
    __syncthreads();
#pragma unroll
    for (int i = 0; i < 4; ++i) { As[arow][aks + i] = av0[i]; As[arow][aks + 4 + i] = av1[i]; }
#pragma unroll
    for (int i = 0; i < 4; ++i) { Bs[bkk][bns + i] = bv0[i]; Bs[bkk][bns + 4 + i] = bv1[i]; }
    __syncthreads();
#pragma unroll 4
    for (int kk = 0; kk < 32; ++kk) {
      double a[4], b[4];
#pragma unroll
      for (int i = 0; i < 4; ++i) a[i] = (double)As[ty * 4 + i][kk];
#pragma unroll
      for (int j = 0; j < 4; ++j) b[j] = (double)Bs[kk][tx * 4 + j];
#pragma unroll
      for (int i = 0; i < 4; ++i)
#pragma unroll
        for (int j = 0; j < 4; ++j) acc[i][j] = fma(a[i], b[j], acc[i][j]);
    }
  }
#pragma unroll
  for (int i = 0; i < 4; ++i) {
    const int qrow = q0 + ty * 4 + i;
    if (qrow < NQ) {
#pragma unroll
      for (int j = 0; j < 4; ++j) {
        const int n = n0 + tx * 4 + j;
        double v = acc[i][j] + (double)adapter_b[n];
        g_qs[(size_t)qrow * 256 + n] = v > 0.0 ? v : 0.0;
      }
    }
  }
}

// ---------------------------------------------------------------------------
// smallk: per q -> gru_in_q(64), r-folded xg table (fp32), lq(4).
// One block per q.
// ---------------------------------------------------------------------------
__global__ void __launch_bounds__(256) smallk_kernel(
    const float* __restrict__ reducer_w, const float* __restrict__ gru_w_ih,
    const float* __restrict__ wgate_w)
{
  __shared__ double qsr[256];
  __shared__ double ps[4][64];
  __shared__ double gi[64];
  const int tid = threadIdx.x;
  const int qq = blockIdx.x;
  qsr[tid] = g_qs[(size_t)qq * 256 + tid];
  __syncthreads();
  {
    const int j = tid & 63, h = tid >> 6;
    const int k0 = h * 64;
    double a0 = 0.0, a1 = 0.0, a2 = 0.0, a3 = 0.0;
    for (int k = 0; k < 64; k += 4) {
      a0 = fma(qsr[k0 + k + 0], (double)reducer_w[(k0 + k + 0) * 64 + j], a0);
      a1 = fma(qsr[k0 + k + 1], (double)reducer_w[(k0 + k + 1) * 64 + j], a1);
      a2 = fma(qsr[k0 + k + 2], (double)reducer_w[(k0 + k + 2) * 64 + j], a2);
      a3 = fma(qsr[k0 + k + 3], (double)reducer_w[(k0 + k + 3) * 64 + j], a3);
    }
    ps[h][j] = (a0 + a1) + (a2 + a3);
  }
  __syncthreads();
  if (tid < 64) gi[tid] = (ps[0][tid] + ps[1][tid]) + (ps[2][tid] + ps[3][tid]);
  if (tid >= 64 && tid < 68) {
    const int e = tid - 64;
    double a0 = 0.0, a1 = 0.0, a2 = 0.0, a3 = 0.0;
    for (int k = 0; k < 256; k += 4) {
      a0 = fma(qsr[k + 0], (double)wgate_w[(k + 0) * 4 + e], a0);
      a1 = fma(qsr[k + 1], (double)wgate_w[(k + 1) * 4 + e], a1);
      a2 = fma(qsr[k + 2], (double)wgate_w[(k + 2) * 4 + e], a2);
      a3 = fma(qsr[k + 3], (double)wgate_w[(k + 3) * 4 + e], a3);
    }
    g_lq[(size_t)qq * 4 + e] = (a0 + a1) + (a2 + a3);
  }
  __syncthreads();
  if (tid < 192) {
    double a0 = 0.0, a1 = 0.0, a2 = 0.0, a3 = 0.0;
    for (int k = 0; k < 64; k += 4) {
      a0 = fma(gi[k + 0], (double)gru_w_ih[tid * 64 + k + 0], a0);
      a1 = fma(gi[k + 1], (double)gru_w_ih[tid * 64 + k + 1], a1);
      a2 = fma(gi[k + 2], (double)gru_w_ih[tid * 64 + k + 2], a2);
      a3 = fma(gi[k + 3], (double)gru_w_ih[tid * 64 + k + 3], a3);
    }
    const double s = (a0 + a1) + (a2 + a3);
    // r-folded x values (fp32): one extra rounding ~1e-8, below the
    // reference's own fp32 noise -> argmax decisions unaffected.
    g_xq2[(size_t)qq * 384 + tid]       = (float)(s + g_xgr[tid]);
    g_xq2[(size_t)qq * 384 + 192 + tid] = (float)(s + g_xgr[192 + tid]);
  }
}

// ---------------------------------------------------------------------------
// gru: one wave per sequence, NO barriers.  64 blocks x 64 threads.
// Lane j owns h[j] (fp64 carry in reg), full r/z/n dots per lane via
// wave-private LDS h mirror (broadcast b128 reads).  Wr/Wz/Wn rows in VGPRs
// (192 regs); total live set ~230 < 256 arch cap -> resident, no remat.
// Per step: prefetch next step's 3 r-folded x floats + q/r one step ahead
// (latency hidden under ~500-cycle step).  No chunk staging, no XB LDS.
// ---------------------------------------------------------------------------
__global__ void __launch_bounds__(64, 1) gru_kernel(
    const int* __restrict__ q, const int* __restrict__ r,
    const float* __restrict__ whh, const float* __restrict__ bhh)
{
  __shared__ __align__(16) float HF[64];
  const int j = threadIdx.x;         // lane == thread
  const int b = blockIdx.x;

  // W rows for this lane, fp32 in VGPRs (as float2 pairs), pinned resident.
  float2 Wr[32], Wz[32], Wn[32];
#pragma unroll
  for (int i = 0; i < 32; ++i) {
    Wr[i] = *(const float2*)(whh + (size_t)(0 * 64 + j) * 64 + 2 * i);
    Wz[i] = *(const float2*)(whh + (size_t)(1 * 64 + j) * 64 + 2 * i);
    Wn[i] = *(const float2*)(whh + (size_t)(2 * 64 + j) * 64 + 2 * i);
  }
#pragma unroll
  for (int i = 0; i < 32; ++i) {
    asm volatile("" : "+v"(Wr[i]));
    asm volatile("" : "+v"(Wz[i]));
    asm volatile("" : "+v"(Wn[i]));
  }
  const double br = (double)bhh[j];
  const double bz = (double)bhh[64 + j];
  const double bn = (double)bhh[128 + j];

  // step 0 consumes the start token (b_ih already folded in g_xg0f)
  float cx0 = g_xg0f[j], cx1 = g_xg0f[64 + j], cx2 = g_xg0f[128 + j];
  // q/r for token 0 (feeds x of step 1)
  int qA = q[b * 512], rA = r[b * 512];

  HF[j] = 0.f;
  double hd = 0.0;

  for (int t = 0; t < 512; ++t) {
    // prefetch x for step t+1 (token t) and q/r for token t+1
    float nx0 = 0.f, nx1 = 0.f, nx2 = 0.f;
    int qB = qA, rB = rA;
    if (t < 511) {
      const size_t base = (size_t)(qA * 2 + rA) * 192 + j;
      nx0 = g_xq2[base];
      nx1 = g_xq2[base + 64];
      nx2 = g_xq2[base + 128];
      const int tk = min(t + 1, 510);
      qB = q[b * 512 + tk];
      rB = r[b * 512 + tk];
    }

    // matvec: 96 packed fp32 FMAs against resident W, h via LDS broadcast
    float2 ar = {0.f, 0.f}, az = {0.f, 0.f}, an = {0.f, 0.f};
    {
      const float4* hp = (const float4*)HF;
#pragma unroll
      for (int g = 0; g < 16; ++g) {
        const float4 t4 = hp[g];
        const float2 hA = make_float2(t4.x, t4.y);
        const float2 hB = make_float2(t4.z, t4.w);
        pkfma(ar, Wr[2 * g], hA); pkfma(ar, Wr[2 * g + 1], hB);
        pkfma(az, Wz[2 * g], hA); pkfma(az, Wz[2 * g + 1], hB);
        pkfma(an, Wn[2 * g], hA); pkfma(an, Wn[2 * g + 1], hB);
      }
    }
    const double hr = br + (double)(ar.x + ar.y);
    const double hz = bz + (double)(az.x + az.y);
    const double hn = bn + (double)(an.x + an.y);
    const double pr = (double)cx0 + hr, pz = (double)cx1 + hz;
    const double xn = (double)cx2;
    double rg = fma(0.5, tpoly(0.5 * pr), 0.5);
    double zg = fma(0.5, tpoly(0.5 * pz), 0.5);
    double pre = fma(rg, hn, xn);
    double ng = tpoly(pre);
    const bool bad = (fabs(pr) > 0.5) | (fabs(pz) > 0.5) | (fabs(pre) > 0.25);
    if (bad) {   // rare slow path
      rg = 1.0 / (1.0 + fexp(-pr));
      zg = 1.0 / (1.0 + fexp(-pz));
      pre = fma(rg, hn, xn);
      ng = 1.0 - 2.0 / (fexp(pre + pre) + 1.0);
    }
    const double hnew = fma(zg, hd - ng, ng);   // (1-z)n + z h
    hd = hnew;
    const float hnf = (float)hnew;
    HF[j] = hnf;                                 // same-wave DS order
    g_m[((size_t)b * 512 + t) * 64 + j] = hnf;

    cx0 = nx0; cx1 = nx1; cx2 = nx2;
    qA = qB; rA = rB;
  }
}

// ---------------------------------------------------------------------------
// top1: logits = lq[q_t] + m_t @ wgate[256:320] + wgate_b ; first-max argmax.
// ---------------------------------------------------------------------------
__global__ void __launch_bounds__(256) top1_kernel(
    const int* __restrict__ q,
    const float* __restrict__ wgate_w, const float* __restrict__ wgate_b)
{
  __shared__ double w2[256];   // [j][e]
  const int tid = threadIdx.x;
  w2[tid] = (double)wgate_w[1024 + tid];
  __syncthreads();
  const int t = blockIdx.x * 256 + tid;
  const int qv = q[t];
  double l0 = g_lq[(size_t)qv * 4 + 0] + (double)wgate_b[0];
  double l1 = g_lq[(size_t)qv * 4 + 1] + (double)wgate_b[1];
  double l2 = g_lq[(size_t)qv * 4 + 2] + (double)wgate_b[2];
  double l3 = g_lq[(size_t)qv * 4 + 3] + (double)wgate_b[3];
  const f32x4* mr4 = (const f32x4*)(g_m + (size_t)t * 64);
#pragma unroll 4
  for (int jj = 0; jj < 16; ++jj) {
    const f32x4 mv4 = mr4[jj];
#pragma unroll
    for (int c = 0; c < 4; ++c) {
      const double mv = (double)mv4[c];
      const int k = (jj * 4 + c) * 4;
      l0 = fma(mv, w2[k + 0], l0);
      l1 = fma(mv, w2[k + 1], l1);
      l2 = fma(mv, w2[k + 2], l2);
      l3 = fma(mv, w2[k + 3], l3);
    }
  }
  int bi = 0; double bvv = l0;
  if (l1 > bvv) { bvv = l1; bi = 1; }
  if (l2 > bvv) { bvv = l2; bi = 2; }
  if (l3 > bvv) { bvv = l3; bi = 3; }
  g_top1[t] = bi;
}

// ---------------------------------------------------------------------------
// kernelE: per 32 q-values: stage emb rows as bf16; for each expert e:
// h1=relu(qr_e@W1+b1) -> out=h1@W2+b2 -> LN -> qf[q][e] bf16.
// ---------------------------------------------------------------------------
__global__ void __launch_bounds__(128) kernelE(
    const float* __restrict__ emb,
    const float* __restrict__ b1, const float* __restrict__ b2,
    const float* __restrict__ lng, const float* __restrict__ lnb)
{
  __shared__ __align__(16) unsigned short QR[32 * 1032];
  __shared__ __align__(16) unsigned short H1[32 * 264];
  __shared__ __align__(16) unsigned short EO[32 * 264];
  const int tid = threadIdx.x;
  const int t0 = blockIdx.x * 32;
  const int w = tid >> 6;
  const int lane = tid & 63;
  const int l15 = lane & 15;
  const int quad = lane >> 4;

  for (int c = 0; c < 64; ++c) {
    const int idx = c * 128 + tid;
    const int row = idx >> 8, col4 = idx & 255;
    const int qv = min(t0 + row, NQ - 1);
    f32x4 v = *(const f32x4*)(emb + (size_t)qv * 1024 + col4 * 4);
    unsigned a = ((unsigned)f2bf(v[1]) << 16) | f2bf(v[0]);
    unsigned bb = ((unsigned)f2bf(v[3]) << 16) | f2bf(v[2]);
    *(uint2*)&QR[row * 1032 + col4 * 4] = make_uint2(a, bb);
  }
  __syncthreads();

  const f32x4 z4 = {0.f, 0.f, 0.f, 0.f};
  const int n0 = w * 128;

  for (int e = 0; e < 4; ++e) {
    f32x4 acc[2][8];
#pragma unroll
    for (int a = 0; a < 2; ++a)
#pragma unroll
      for (int bq = 0; bq < 8; ++bq) acc[a][bq] = z4;
#pragma unroll
    for (int ks = 0; ks < 8; ++ks) {
      const int koff = e * 256 + ks * 32 + quad * 8;
      bf16x8 a0 = *(const bf16x8*)&QR[l15 * 1032 + koff];
      bf16x8 a1 = *(const bf16x8*)&QR[(16 + l15) * 1032 + koff];
      const int kb = ks * 32 + quad * 8;
#pragma unroll
      for (int nt = 0; nt < 8; ++nt) {
        bf16x8 bbv = *(const bf16x8*)(g_w1t + (size_t)e * 65536 +
                                      (size_t)(n0 + nt * 16 + l15) * 256 + kb);
        acc[0][nt] = mfma16(a0, bbv, acc[0][nt]);
        acc[1][nt] = mfma16(a1, bbv, acc[1][nt]);
      }
    }
#pragma unroll
    for (int nt = 0; nt < 8; ++nt) {
      const int n = n0 + nt * 16 + l15;
      const float b1v = b1[e * 256 + n];
#pragma unroll
      for (int mt = 0; mt < 2; ++mt)
#pragma unroll
        for (int rg = 0; rg < 4; ++rg) {
          const int m = mt * 16 + quad * 4 + rg;
          H1[m * 264 + n] = f2bf(fmaxf(acc[mt][nt][rg] + b1v, 0.f));
        }
    }
    __syncthreads();
    f32x4 acc2[2][8];
#pragma unroll
    for (int a = 0; a < 2; ++a)
#pragma unroll
      for (int bq = 0; bq < 8; ++bq) acc2[a][bq] = z4;
#pragma unroll
    for (int ks = 0; ks < 8; ++ks) {
      const int koff = ks * 32 + quad * 8;
      bf16x8 a0 = *(const bf16x8*)&H1[l15 * 264 + koff];
      bf16x8 a1 = *(const bf16x8*)&H1[(16 + l15) * 264 + koff];
#pragma unroll
      for (int nt = 0; nt < 8; ++nt) {
        bf16x8 bbv = *(const bf16x8*)(g_w2t + (size_t)e * 65536 +
                                      (size_t)(n0 + nt * 16 + l15) * 256 + koff);
        acc2[0][nt] = mfma16(a0, bbv, acc2[0][nt]);
        acc2[1][nt] = mfma16(a1, bbv, acc2[1][nt]);
      }
    }
#pragma unroll
    for (int nt = 0; nt < 8; ++nt) {
      const int n = n0 + nt * 16 + l15;
      const float b2v = b2[e * 256 + n];
#pragma unroll
      for (int mt = 0; mt < 2; ++mt)
#pragma unroll
        for (int rg = 0; rg < 4; ++rg) {
          const int m = mt * 16 + quad * 4 + rg;
          EO[m * 264 + n] = f2bf(acc2[mt][nt][rg] + b2v);
        }
    }
    __syncthreads();
    {
      const int m = tid >> 2;
      const int sub = tid & 3;
      float sx = 0.f, sxx = 0.f;
#pragma unroll
      for (int i = 0; i < 8; ++i) {
        bf16x8 v = *(const bf16x8*)&EO[m * 264 + sub * 64 + i * 8];
#pragma unroll
        for (int c = 0; c < 8; ++c) {
          const float f = bf2f((unsigned short)v[c]);
          sx += f; sxx += f * f;
        }
      }
      sx += __shfl_xor(sx, 1); sxx += __shfl_xor(sxx, 1);
      sx += __shfl_xor(sx, 2); sxx += __shfl_xor(sxx, 2);
      const float mu = sx * (1.f / 256.f);
      const float var = sxx * (1.f / 256.f) - mu * mu;
      const float inv = 1.f / sqrtf(var + 1e-5f);
      if (t0 + m < NQ) {
        const size_t base = ((size_t)(t0 + m) * 4 + e) * 256;
#pragma unroll
        for (int i = 0; i < 8; ++i) {
          const int dbase = sub * 64 + i * 8;
          bf16x8 v = *(const bf16x8*)&EO[m * 264 + dbase];
          bf16x8 ov;
#pragma unroll
          for (int c = 0; c < 8; ++c) {
            const int d = dbase + c;
            const float f = bf2f((unsigned short)v[c]);
            ov[c] = (short)f2bf(lng[d] * (f - mu) * inv + lnb[d]);
          }
          *(bf16x8*)(g_qf + base + dbase) = ov;
        }
      }
    }
    __syncthreads();
  }
}

// ---------------------------------------------------------------------------
// kernelF: per 32 tokens: gather qf[q_t][top1_t] -> q_fused out (fp32) and
// LDS; proj (cor|inc) bf16 MFMA; qa_fused by r.
// ---------------------------------------------------------------------------
__global__ void __launch_bounds__(128) kernelF(
    const int* __restrict__ q, const int* __restrict__ r,
    const float* __restrict__ pcb, const float* __restrict__ pib,
    float* __restrict__ out)
{
  __shared__ __align__(16) unsigned short QF[32 * 264];
  __shared__ int rv_l[32];
  const int tid = threadIdx.x;
  const int t0 = blockIdx.x * 32;
  const int w = tid >> 6;
  const int lane = tid & 63;
  const int l15 = lane & 15;
  const int quad = lane >> 4;
  if (tid < 32) rv_l[tid] = r[t0 + tid];
  __syncthreads();

  {
    const int m = tid >> 2;
    const size_t row = ((size_t)q[t0 + m] * 4 + g_top1[t0 + m]) * 256;
#pragma unroll
    for (int i = 0; i < 8; ++i) {
      const int dbase = (tid & 3) * 64 + i * 8;
      bf16x8 v = *(const bf16x8*)(g_qf + row + dbase);
      *(bf16x8*)&QF[m * 264 + dbase] = v;
      f32x4 f0, f1;
#pragma unroll
      for (int c = 0; c < 4; ++c) f0[c] = bf2f((unsigned short)v[c]);
#pragma unroll
      for (int c = 0; c < 4; ++c) f1[c] = bf2f((unsigned short)v[4 + c]);
      *(f32x4*)(out + (size_t)(t0 + m) * 256 + dbase) = f0;
      *(f32x4*)(out + (size_t)(t0 + m) * 256 + dbase + 4) = f1;
    }
  }
  __syncthreads();

  const f32x4 z4 = {0.f, 0.f, 0.f, 0.f};
  const int n0 = w * 128;
  for (int ph = 0; ph < 2; ++ph) {
    f32x4 acc[2][8];
#pragma unroll
    for (int a = 0; a < 2; ++a)
#pragma unroll
      for (int bq = 0; bq < 8; ++bq) acc[a][bq] = z4;
#pragma unroll
    for (int ks = 0; ks < 8; ++ks) {
      const int koff = ks * 32 + quad * 8;
      bf16x8 a0 = *(const bf16x8*)&QF[l15 * 264 + koff];
      bf16x8 a1 = *(const bf16x8*)&QF[(16 + l15) * 264 + koff];
#pragma unroll
      for (int nt = 0; nt < 8; ++nt) {
        bf16x8 bbv = *(const bf16x8*)(g_projt +
            (size_t)(ph * 256 + n0 + nt * 16 + l15) * 256 + koff);
        acc[0][nt] = mfma16(a0, bbv, acc[0][nt]);
        acc[1][nt] = mfma16(a1, bbv, acc[1][nt]);
      }
    }
    const float* pbb = ph ? pib : pcb;
    const int want = ph ? 0 : 1;
#pragma unroll
    for (int nt = 0; nt < 8; ++nt) {
      const int n = n0 + nt * 16 + l15;
      const float pbv = pbb[n];
#pragma unroll
      for (int mt = 0; mt < 2; ++mt)
#pragma unroll
        for (int rg = 0; rg < 4; ++rg) {
          const int m = mt * 16 + quad * 4 + rg;
          if (rv_l[m] == want)
            out[(size_t)TT * 256 + (size_t)(t0 + m) * 256 + n] =
                acc[mt][nt][rg] + pbv;
        }
    }
  }
}

// ---------------------------------------------------------------------------
extern "C" void kernel_launch(void* const* d_in, const int* in_sizes, int n_in,
                              void* d_out, int out_size, void* d_ws, size_t ws_size,
                              hipStream_t stream)
{
  const int*   q   = (const int*)d_in[0];
  const int*   r   = (const int*)d_in[1];
  const float* emb = (const float*)d_in[2];
  const float* ew1 = (const float*)d_in[3];
  const float* eb1 = (const float*)d_in[4];
  const float* ew2 = (const float*)d_in[5];
  const float* eb2 = (const float*)d_in[6];
  const float* aw  = (const float*)d_in[7];
  const float* ab  = (const float*)d_in[8];
  const float* rw  = (const float*)d_in[9];
  const float* rb  = (const float*)d_in[10];
  const float* st  = (const float*)d_in[11];
  const float* wih = (const float*)d_in[12];
  const float* whh = (const float*)d_in[13];
  const float* bih = (const float*)d_in[14];
  const float* bhh = (const float*)d_in[15];
  const float* wgw = (const float*)d_in[16];
  const float* wgb = (const float*)d_in[17];
  const float* lng = (const float*)d_in[18];
  const float* lnb = (const float*)d_in[19];
  const float* resp= (const float*)d_in[20];
  const float* pcw = (const float*)d_in[21];
  const float* pcb = (const float*)d_in[22];
  const float* piw = (const float*)d_in[23];
  const float* pib = (const float*)d_in[24];
  float* out = (float*)d_out;
  (void)bih; (void)in_sizes; (void)n_in; (void)d_ws; (void)ws_size; (void)out_size;

  prep_kernel<<<64, 256, 0, stream>>>(ew1, ew2, pcw, piw, resp, rw, rb, st, wih, bih);
  qsk_kernel<<<dim3(157, 4), 256, 0, stream>>>(emb, aw, ab);
  smallk_kernel<<<NQ, 256, 0, stream>>>(rw, wih, wgw);
  gru_kernel<<<64, 64, 0, stream>>>(q, r, whh, bhh);
  top1_kernel<<<128, 256, 0, stream>>>(q, wgw, wgb);
  kernelE<<<313, 128, 0, stream>>>(emb, eb1, eb2, lng, lnb);
  kernelF<<<1024, 128, 0, stream>>>(q, r, pcb, pib, out);
}

// Round 4
// 1079.058 us; speedup vs baseline: 1.1221x; 1.0123x over previous
//
#include <hip/hip_runtime.h>
#include <cstddef>

// ---------------------------------------------------------------------------
// PolyaAKT interaction embedder, MI355X/gfx950.  Inputs fp32, output fp32.
// Control path (logits/GRU) high-precision for argmax fidelity; value path
// (experts/LN/proj) in bf16 MFMA.  Per-q dedup throughout.
// R9: GRU restructured so W_hh residency is guaranteed BY CONSTRUCTION:
//  - R5-R8 evidence: 192-reg W + fp64 tail + h-broadcast can't fit the
//    256-arch-VGPR cap in one wave (VGPR_Count 124-148 across 4 attempts;
//    allocator spills W every time).
//  - Fix: 2 waves/block, lane pairs split each row's dot over k-halves.
//    Per-lane W = 48 float2 = 96 VGPRs; live set ~180 -> resident.
//    Half-sums combine via __shfl_xor(.,1); both pair lanes run the fp64
//    tail redundantly (no divergence).  h exchanged via double-buffered
//    HF[2][64], ONE raw s_barrier per step (lgkmcnt-only drain; no vmcnt
//    stall on the g_m stores).
// ---------------------------------------------------------------------------

#define NQ 10000
#define TT 32768   // B*S

typedef __attribute__((ext_vector_type(8))) short bf16x8;
typedef __attribute__((ext_vector_type(4))) float f32x4;

__device__ double g_qs  [NQ * 256];      // q_summary (relu'd), fp64
__device__ double g_xgr [2 * 192];       // r-part of xg (+b_ih), fp64
__device__ float  g_xg0f[192];           // start_token @ W_ih^T + b_ih (fp32)
__device__ float  g_xq2 [NQ * 384];      // r-folded xg: [q][r][192] fp32
__device__ double g_lq  [NQ * 4];        // qs @ wgate[0:256]
__device__ float  g_m   [TT * 64];       // GRU hidden per token (fp32)
__device__ int    g_top1[TT];
__device__ unsigned short g_w1t  [4 * 256 * 256];  // bf16 [e][n][k]
__device__ unsigned short g_w2t  [4 * 256 * 256];
__device__ unsigned short g_projt[512 * 256];      // bf16 [n(cor|inc)][k]
__device__ unsigned short g_qf   [NQ * 4 * 256];   // LN'd expert out, bf16

__device__ __forceinline__ float bf2f(unsigned short x) {
  return __uint_as_float(((unsigned)x) << 16);
}
__device__ __forceinline__ unsigned short f2bf(float f) {
  unsigned u = __float_as_uint(f);
  u += 0x7FFFu + ((u >> 16) & 1u);   // RNE
  return (unsigned short)(u >> 16);
}
__device__ __forceinline__ f32x4 mfma16(bf16x8 a, bf16x8 b, f32x4 c) {
  return __builtin_amdgcn_mfma_f32_16x16x32_bf16(a, b, c, 0, 0, 0);
}
// packed fp32 fma: c = a*b + c on both lanes of the pair (bit-identical to
// two scalar v_fma_f32, just one instruction).
__device__ __forceinline__ void pkfma(float2& c, float2 a, float2 b) {
  asm("v_pk_fma_f32 %0, %1, %2, %0" : "+v"(c) : "v"(a), "v"(b));
}

// fast fp64 exp (slow path only): range-reduced degree-10 poly, rel err ~2e-13.
__device__ __forceinline__ double fexp(double x) {
  const double L2E  = 1.4426950408889634074;
  const double LN2H = 6.93147180369123816490e-01;
  const double LN2L = 1.90821492927058770002e-10;
  double n = rint(x * L2E);
  int ni = (int)n;
  double r = fma(-n, LN2H, x);
  r = fma(-n, LN2L, r);
  double p = 2.7557319223985888e-07;
  p = fma(p, r, 2.7557319223985893e-06);
  p = fma(p, r, 2.4801587301587302e-05);
  p = fma(p, r, 1.9841269841269841e-04);
  p = fma(p, r, 1.3888888888888889e-03);
  p = fma(p, r, 8.3333333333333332e-03);
  p = fma(p, r, 4.1666666666666664e-02);
  p = fma(p, r, 1.6666666666666666e-01);
  p = fma(p, r, 0.5);
  p = fma(p, r, 1.0);
  p = fma(p, r, 1.0);
  return ldexp(p, ni);
}

// tanh via odd Taylor, |p| <= 0.25: abs err ~5e-11.
__device__ __forceinline__ double tpoly(double p) {
  const double p2 = p * p;
  double t = -1382.0 / 155925.0;          // p^11
  t = fma(t, p2, 62.0 / 2835.0);          // p^9
  t = fma(t, p2, -17.0 / 315.0);          // p^7
  t = fma(t, p2, 2.0 / 15.0);             // p^5
  t = fma(t, p2, -1.0 / 3.0);             // p^3
  t = fma(t, p2, 1.0);
  return p * t;
}

// ---------------------------------------------------------------------------
// prep: bf16 transposed weight tables + fp64 folds (xg_r, xg0).
// ---------------------------------------------------------------------------
__global__ void __launch_bounds__(256) prep_kernel(
    const float* __restrict__ expert_w1, const float* __restrict__ expert_w2,
    const float* __restrict__ proj_cor_w, const float* __restrict__ proj_inc_w,
    const float* __restrict__ resp_table, const float* __restrict__ reducer_w,
    const float* __restrict__ reducer_b,  const float* __restrict__ start_token,
    const float* __restrict__ gru_w_ih,   const float* __restrict__ gru_b_ih)
{
  __shared__ double red2f[128];   // [rr][j]
  const int tid = threadIdx.x;
  if (blockIdx.x == 0) {
    if (tid < 128) {
      const int rr = tid >> 6, j = tid & 63;
      double acc = (double)reducer_b[j];
      for (int k = 0; k < 256; ++k)
        acc += (double)resp_table[rr * 256 + k] *
               (double)reducer_w[(256 + k) * 64 + j];
      red2f[tid] = acc;
    }
    __syncthreads();
    if (tid < 192) {
      const double bih = (double)gru_b_ih[tid];
      double a0 = bih, a1 = bih, a2 = bih;
      for (int j = 0; j < 64; ++j) {
        const double w = (double)gru_w_ih[tid * 64 + j];
        a0 += red2f[j] * w;
        a1 += red2f[64 + j] * w;
        a2 += (double)start_token[j] * w;
      }
      g_xgr[tid] = a0; g_xgr[192 + tid] = a1; g_xg0f[tid] = (float)a2;
    }
  }
  const int idx0 = blockIdx.x * 256 + tid;
  const int stride = gridDim.x * 256;
  for (int i = idx0; i < 4 * 256 * 256; i += stride) {
    const int e = i >> 16, rem = i & 65535, n = rem >> 8, k = rem & 255;
    g_w1t[i] = f2bf(expert_w1[e * 65536 + k * 256 + n]);
    g_w2t[i] = f2bf(expert_w2[e * 65536 + k * 256 + n]);
  }
  for (int i = idx0; i < 512 * 256; i += stride) {
    const int n = i >> 8, k = i & 255;
    g_projt[i] = f2bf((n < 256) ? proj_cor_w[k * 256 + n]
                                : proj_inc_w[k * 256 + (n - 256)]);
  }
}

// ---------------------------------------------------------------------------
// qsk: fp64 GEMM  qs[q][n] = relu( emb_row_q(1024) . adapter_w[:,n] + b[n] )
// ---------------------------------------------------------------------------
__global__ void __launch_bounds__(256) qsk_kernel(
    const float* __restrict__ emb, const float* __restrict__ adapter_w,
    const float* __restrict__ adapter_b)
{
  __shared__ __align__(16) float As[64][33];
  __shared__ __align__(16) float Bs[32][65];
  const int tid = threadIdx.x;
  const int q0 = blockIdx.x * 64;
  const int n0 = blockIdx.y * 64;
  const int ty = tid >> 4, tx = tid & 15;

  double acc[4][4];
#pragma unroll
  for (int i = 0; i < 4; ++i)
#pragma unroll
    for (int j = 0; j < 4; ++j) acc[i][j] = 0.0;

  const int arow = tid >> 2, aks = (tid & 3) * 8;
  const int qa = min(q0 + arow, NQ - 1);
  const int bkk = tid >> 3, bns = (tid & 7) * 8;

  for (int kc = 0; kc < 1024; kc += 32) {
    f32x4 av0 = *(const f32x4*)(emb + (size_t)qa * 1024 + kc + aks);
    f32x4 av1 = *(const f32x4*)(emb + (size_t)qa * 1024 + kc + aks + 4);
    f32x4 bv0 = *(const f32x4*)(adapter_w + (size_t)(kc + bkk) * 256 + n0 + bns);
    f32x4 bv1 = *(const f32x4*)(adapter_w + (size_t)(kc + bkk) * 256 + n0 + bns + 4);
    __syncthreads();
#pragma unroll
    for (int i = 0; i < 4; ++i) { As[arow][aks + i] = av0[i]; As[arow][aks + 4 + i] = av1[i]; }
#pragma unroll
    for (int i = 0; i < 4; ++i) { Bs[bkk][bns + i] = bv0[i]; Bs[bkk][bns + 4 + i] = bv1[i]; }
    __syncthreads();
#pragma unroll 4
    for (int kk = 0; kk < 32; ++kk) {
      double a[4], b[4];
#pragma unroll
      for (int i = 0; i < 4; ++i) a[i] = (double)As[ty * 4 + i][kk];
#pragma unroll
      for (int j = 0; j < 4; ++j) b[j] = (double)Bs[kk][tx * 4 + j];
#pragma unroll
      for (int i = 0; i < 4; ++i)
#pragma unroll
        for (int j = 0; j < 4; ++j) acc[i][j] = fma(a[i], b[j], acc[i][j]);
    }
  }
#pragma unroll
  for (int i = 0; i < 4; ++i) {
    const int qrow = q0 + ty * 4 + i;
    if (qrow < NQ) {
#pragma unroll
      for (int j = 0; j < 4; ++j) {
        const int n = n0 + tx * 4 + j;
        double v = acc[i][j] + (double)adapter_b[n];
        g_qs[(size_t)qrow * 256 + n] = v > 0.0 ? v : 0.0;
      }
    }
  }
}

// ---------------------------------------------------------------------------
// smallk: per q -> gru_in_q(64), r-folded xg table (fp32), lq(4).
// One block per q.
// ---------------------------------------------------------------------------
__global__ void __launch_bounds__(256) smallk_kernel(
    const float* __restrict__ reducer_w, const float* __restrict__ gru_w_ih,
    const float* __restrict__ wgate_w)
{
  __shared__ double qsr[256];
  __shared__ double ps[4][64];
  __shared__ double gi[64];
  const int tid = threadIdx.x;
  const int qq = blockIdx.x;
  qsr[tid] = g_qs[(size_t)qq * 256 + tid];
  __syncthreads();
  {
    const int j = tid & 63, h = tid >> 6;
    const int k0 = h * 64;
    double a0 = 0.0, a1 = 0.0, a2 = 0.0, a3 = 0.0;
    for (int k = 0; k < 64; k += 4) {
      a0 = fma(qsr[k0 + k + 0], (double)reducer_w[(k0 + k + 0) * 64 + j], a0);
      a1 = fma(qsr[k0 + k + 1], (double)reducer_w[(k0 + k + 1) * 64 + j], a1);
      a2 = fma(qsr[k0 + k + 2], (double)reducer_w[(k0 + k + 2) * 64 + j], a2);
      a3 = fma(qsr[k0 + k + 3], (double)reducer_w[(k0 + k + 3) * 64 + j], a3);
    }
    ps[h][j] = (a0 + a1) + (a2 + a3);
  }
  __syncthreads();
  if (tid < 64) gi[tid] = (ps[0][tid] + ps[1][tid]) + (ps[2][tid] + ps[3][tid]);
  if (tid >= 64 && tid < 68) {
    const int e = tid - 64;
    double a0 = 0.0, a1 = 0.0, a2 = 0.0, a3 = 0.0;
    for (int k = 0; k < 256; k += 4) {
      a0 = fma(qsr[k + 0], (double)wgate_w[(k + 0) * 4 + e], a0);
      a1 = fma(qsr[k + 1], (double)wgate_w[(k + 1) * 4 + e], a1);
      a2 = fma(qsr[k + 2], (double)wgate_w[(k + 2) * 4 + e], a2);
      a3 = fma(qsr[k + 3], (double)wgate_w[(k + 3) * 4 + e], a3);
    }
    g_lq[(size_t)qq * 4 + e] = (a0 + a1) + (a2 + a3);
  }
  __syncthreads();
  if (tid < 192) {
    double a0 = 0.0, a1 = 0.0, a2 = 0.0, a3 = 0.0;
    for (int k = 0; k < 64; k += 4) {
      a0 = fma(gi[k + 0], (double)gru_w_ih[tid * 64 + k + 0], a0);
      a1 = fma(gi[k + 1], (double)gru_w_ih[tid * 64 + k + 1], a1);
      a2 = fma(gi[k + 2], (double)gru_w_ih[tid * 64 + k + 2], a2);
      a3 = fma(gi[k + 3], (double)gru_w_ih[tid * 64 + k + 3], a3);
    }
    const double s = (a0 + a1) + (a2 + a3);
    // r-folded x values (fp32): one extra rounding ~1e-8, below the
    // reference's own fp32 noise -> argmax decisions unaffected.
    g_xq2[(size_t)qq * 384 + tid]       = (float)(s + g_xgr[tid]);
    g_xq2[(size_t)qq * 384 + 192 + tid] = (float)(s + g_xgr[192 + tid]);
  }
}

// ---------------------------------------------------------------------------
// gru: 64 blocks x 128 threads (2 waves).  wave w owns rows j = w*32+p;
// lane pair (2p, 2p+1) splits row p's dots over k-halves [0,32)/[32,64).
// Per-lane W = 48 float2 = 96 VGPRs -> resident by construction.
// Half-sums combine via __shfl_xor(.,1) (in-pair, no LDS); both pair lanes
// run the fp64 tail redundantly.  h exchanged via double-buffered HF[2][64],
// ONE raw s_barrier per step (lgkmcnt-only drain; g_m stores not drained).
// Per step: prefetch next r-folded x (3 floats) + q/r one step ahead.
// ---------------------------------------------------------------------------
__global__ void __launch_bounds__(128, 1) gru_kernel(
    const int* __restrict__ q, const int* __restrict__ r,
    const float* __restrict__ whh, const float* __restrict__ bhh)
{
  __shared__ __align__(16) float HF[2][64];
  const int tid = threadIdx.x;
  const int b = blockIdx.x;
  const int wv = tid >> 6;           // wave: rows [wv*32, wv*32+32)
  const int l = tid & 63;
  const int p = l >> 1;              // row within wave
  const int half = l & 1;            // k-half
  const int j = wv * 32 + p;         // row
  const int k0 = half * 32;

  // W half-rows for this lane, fp32 float2 pairs, resident (96 VGPRs).
  float2 Wr[16], Wz[16], Wn[16];
#pragma unroll
  for (int i = 0; i < 16; ++i) {
    Wr[i] = *(const float2*)(whh + (size_t)(0 * 64 + j) * 64 + k0 + 2 * i);
    Wz[i] = *(const float2*)(whh + (size_t)(1 * 64 + j) * 64 + k0 + 2 * i);
    Wn[i] = *(const float2*)(whh + (size_t)(2 * 64 + j) * 64 + k0 + 2 * i);
  }
#pragma unroll
  for (int i = 0; i < 16; ++i) {
    asm volatile("" : "+v"(Wr[i]));
    asm volatile("" : "+v"(Wz[i]));
    asm volatile("" : "+v"(Wn[i]));
  }
  const double br = (double)bhh[j];
  const double bz = (double)bhh[64 + j];
  const double bn = (double)bhh[128 + j];

  // step 0 consumes the start token (b_ih already folded in g_xg0f)
  float cx0 = g_xg0f[j], cx1 = g_xg0f[64 + j], cx2 = g_xg0f[128 + j];
  int qA = q[b * 512], rA = r[b * 512];

  if (tid < 64) HF[0][tid] = 0.f;
  double hd = 0.0;
  asm volatile("s_waitcnt lgkmcnt(0)\n\ts_barrier" ::: "memory");

  for (int t = 0; t < 512; ++t) {
    // prefetch x for step t+1 (token t) and q/r for token t+1
    float nx0 = 0.f, nx1 = 0.f, nx2 = 0.f;
    int qB = qA, rB = rA;
    if (t < 511) {
      const size_t base = (size_t)(qA * 2 + rA) * 192 + j;
      nx0 = g_xq2[base];
      nx1 = g_xq2[base + 64];
      nx2 = g_xq2[base + 128];
      const int tk = min(t + 1, 510);
      qB = q[b * 512 + tk];
      rB = r[b * 512 + tk];
    }

    // half-dot: 48 packed fp32 FMAs against resident W
    float2 ar = {0.f, 0.f}, az = {0.f, 0.f}, an = {0.f, 0.f};
    {
      const float4* hp = (const float4*)&HF[t & 1][k0];
#pragma unroll
      for (int g = 0; g < 8; ++g) {
        const float4 t4 = hp[g];
        const float2 hA = make_float2(t4.x, t4.y);
        const float2 hB = make_float2(t4.z, t4.w);
        pkfma(ar, Wr[2 * g], hA); pkfma(ar, Wr[2 * g + 1], hB);
        pkfma(az, Wz[2 * g], hA); pkfma(az, Wz[2 * g + 1], hB);
        pkfma(an, Wn[2 * g], hA); pkfma(an, Wn[2 * g + 1], hB);
      }
    }
    // combine k-halves in-pair (fp64 add is commutative -> pair-uniform)
    const float srh = ar.x + ar.y;
    const float szh = az.x + az.y;
    const float snh = an.x + an.y;
    const float sro = __shfl_xor(srh, 1);
    const float szo = __shfl_xor(szh, 1);
    const float sno = __shfl_xor(snh, 1);
    const double hr = br + ((double)srh + (double)sro);
    const double hz = bz + ((double)szh + (double)szo);
    const double hn = bn + ((double)snh + (double)sno);
    const double pr = (double)cx0 + hr, pz = (double)cx1 + hz;
    const double xn = (double)cx2;
    double rg = fma(0.5, tpoly(0.5 * pr), 0.5);
    double zg = fma(0.5, tpoly(0.5 * pz), 0.5);
    double pre = fma(rg, hn, xn);
    double ng = tpoly(pre);
    const bool bad = (fabs(pr) > 0.5) | (fabs(pz) > 0.5) | (fabs(pre) > 0.25);
    if (bad) {   // rare slow path
      rg = 1.0 / (1.0 + fexp(-pr));
      zg = 1.0 / (1.0 + fexp(-pz));
      pre = fma(rg, hn, xn);
      ng = 1.0 - 2.0 / (fexp(pre + pre) + 1.0);
    }
    const double hnew = fma(zg, hd - ng, ng);   // (1-z)n + z h
    hd = hnew;
    const float hnf = (float)hnew;
    if (half == 0) {
      HF[(t & 1) ^ 1][j] = hnf;
      g_m[((size_t)b * 512 + t) * 64 + j] = hnf;
    }
    asm volatile("s_waitcnt lgkmcnt(0)\n\ts_barrier" ::: "memory");

    cx0 = nx0; cx1 = nx1; cx2 = nx2;
    qA = qB; rA = rB;
  }
}

// ---------------------------------------------------------------------------
// top1: logits = lq[q_t] + m_t @ wgate[256:320] + wgate_b ; first-max argmax.
// ---------------------------------------------------------------------------
__global__ void __launch_bounds__(256) top1_kernel(
    const int* __restrict__ q,
    const float* __restrict__ wgate_w, const float* __restrict__ wgate_b)
{
  __shared__ double w2[256];   // [j][e]
  const int tid = threadIdx.x;
  w2[tid] = (double)wgate_w[1024 + tid];
  __syncthreads();
  const int t = blockIdx.x * 256 + tid;
  const int qv = q[t];
  double l0 = g_lq[(size_t)qv * 4 + 0] + (double)wgate_b[0];
  double l1 = g_lq[(size_t)qv * 4 + 1] + (double)wgate_b[1];
  double l2 = g_lq[(size_t)qv * 4 + 2] + (double)wgate_b[2];
  double l3 = g_lq[(size_t)qv * 4 + 3] + (double)wgate_b[3];
  const f32x4* mr4 = (const f32x4*)(g_m + (size_t)t * 64);
#pragma unroll 4
  for (int jj = 0; jj < 16; ++jj) {
    const f32x4 mv4 = mr4[jj];
#pragma unroll
    for (int c = 0; c < 4; ++c) {
      const double mv = (double)mv4[c];
      const int k = (jj * 4 + c) * 4;
      l0 = fma(mv, w2[k + 0], l0);
      l1 = fma(mv, w2[k + 1], l1);
      l2 = fma(mv, w2[k + 2], l2);
      l3 = fma(mv, w2[k + 3], l3);
    }
  }
  int bi = 0; double bvv = l0;
  if (l1 > bvv) { bvv = l1; bi = 1; }
  if (l2 > bvv) { bvv = l2; bi = 2; }
  if (l3 > bvv) { bvv = l3; bi = 3; }
  g_top1[t] = bi;
}

// ---------------------------------------------------------------------------
// kernelE: per 32 q-values: stage emb rows as bf16; for each expert e:
// h1=relu(qr_e@W1+b1) -> out=h1@W2+b2 -> LN -> qf[q][e] bf16.
// ---------------------------------------------------------------------------
__global__ void __launch_bounds__(128) kernelE(
    const float* __restrict__ emb,
    const float* __restrict__ b1, const float* __restrict__ b2,
    const float* __restrict__ lng, const float* __restrict__ lnb)
{
  __shared__ __align__(16) unsigned short QR[32 * 1032];
  __shared__ __align__(16) unsigned short H1[32 * 264];
  __shared__ __align__(16) unsigned short EO[32 * 264];
  const int tid = threadIdx.x;
  const int t0 = blockIdx.x * 32;
  const int w = tid >> 6;
  const int lane = tid & 63;
  const int l15 = lane & 15;
  const int quad = lane >> 4;

  for (int c = 0; c < 64; ++c) {
    const int idx = c * 128 + tid;
    const int row = idx >> 8, col4 = idx & 255;
    const int qv = min(t0 + row, NQ - 1);
    f32x4 v = *(const f32x4*)(emb + (size_t)qv * 1024 + col4 * 4);
    unsigned a = ((unsigned)f2bf(v[1]) << 16) | f2bf(v[0]);
    unsigned bb = ((unsigned)f2bf(v[3]) << 16) | f2bf(v[2]);
    *(uint2*)&QR[row * 1032 + col4 * 4] = make_uint2(a, bb);
  }
  __syncthreads();

  const f32x4 z4 = {0.f, 0.f, 0.f, 0.f};
  const int n0 = w * 128;

  for (int e = 0; e < 4; ++e) {
    f32x4 acc[2][8];
#pragma unroll
    for (int a = 0; a < 2; ++a)
#pragma unroll
      for (int bq = 0; bq < 8; ++bq) acc[a][bq] = z4;
#pragma unroll
    for (int ks = 0; ks < 8; ++ks) {
      const int koff = e * 256 + ks * 32 + quad * 8;
      bf16x8 a0 = *(const bf16x8*)&QR[l15 * 1032 + koff];
      bf16x8 a1 = *(const bf16x8*)&QR[(16 + l15) * 1032 + koff];
      const int kb = ks * 32 + quad * 8;
#pragma unroll
      for (int nt = 0; nt < 8; ++nt) {
        bf16x8 bbv = *(const bf16x8*)(g_w1t + (size_t)e * 65536 +
                                      (size_t)(n0 + nt * 16 + l15) * 256 + kb);
        acc[0][nt] = mfma16(a0, bbv, acc[0][nt]);
        acc[1][nt] = mfma16(a1, bbv, acc[1][nt]);
      }
    }
#pragma unroll
    for (int nt = 0; nt < 8; ++nt) {
      const int n = n0 + nt * 16 + l15;
      const float b1v = b1[e * 256 + n];
#pragma unroll
      for (int mt = 0; mt < 2; ++mt)
#pragma unroll
        for (int rg = 0; rg < 4; ++rg) {
          const int m = mt * 16 + quad * 4 + rg;
          H1[m * 264 + n] = f2bf(fmaxf(acc[mt][nt][rg] + b1v, 0.f));
        }
    }
    __syncthreads();
    f32x4 acc2[2][8];
#pragma unroll
    for (int a = 0; a < 2; ++a)
#pragma unroll
      for (int bq = 0; bq < 8; ++bq) acc2[a][bq] = z4;
#pragma unroll
    for (int ks = 0; ks < 8; ++ks) {
      const int koff = ks * 32 + quad * 8;
      bf16x8 a0 = *(const bf16x8*)&H1[l15 * 264 + koff];
      bf16x8 a1 = *(const bf16x8*)&H1[(16 + l15) * 264 + koff];
#pragma unroll
      for (int nt = 0; nt < 8; ++nt) {
        bf16x8 bbv = *(const bf16x8*)(g_w2t + (size_t)e * 65536 +
                                      (size_t)(n0 + nt * 16 + l15) * 256 + koff);
        acc2[0][nt] = mfma16(a0, bbv, acc2[0][nt]);
        acc2[1][nt] = mfma16(a1, bbv, acc2[1][nt]);
      }
    }
#pragma unroll
    for (int nt = 0; nt < 8; ++nt) {
      const int n = n0 + nt * 16 + l15;
      const float b2v = b2[e * 256 + n];
#pragma unroll
      for (int mt = 0; mt < 2; ++mt)
#pragma unroll
        for (int rg = 0; rg < 4; ++rg) {
          const int m = mt * 16 + quad * 4 + rg;
          EO[m * 264 + n] = f2bf(acc2[mt][nt][rg] + b2v);
        }
    }
    __syncthreads();
    {
      const int m = tid >> 2;
      const int sub = tid & 3;
      float sx = 0.f, sxx = 0.f;
#pragma unroll
      for (int i = 0; i < 8; ++i) {
        bf16x8 v = *(const bf16x8*)&EO[m * 264 + sub * 64 + i * 8];
#pragma unroll
        for (int c = 0; c < 8; ++c) {
          const float f = bf2f((unsigned short)v[c]);
          sx += f; sxx += f * f;
        }
      }
      sx += __shfl_xor(sx, 1); sxx += __shfl_xor(sxx, 1);
      sx += __shfl_xor(sx, 2); sxx += __shfl_xor(sxx, 2);
      const float mu = sx * (1.f / 256.f);
      const float var = sxx * (1.f / 256.f) - mu * mu;
      const float inv = 1.f / sqrtf(var + 1e-5f);
      if (t0 + m < NQ) {
        const size_t base = ((size_t)(t0 + m) * 4 + e) * 256;
#pragma unroll
        for (int i = 0; i < 8; ++i) {
          const int dbase = sub * 64 + i * 8;
          bf16x8 v = *(const bf16x8*)&EO[m * 264 + dbase];
          bf16x8 ov;
#pragma unroll
          for (int c = 0; c < 8; ++c) {
            const int d = dbase + c;
            const float f = bf2f((unsigned short)v[c]);
            ov[c] = (short)f2bf(lng[d] * (f - mu) * inv + lnb[d]);
          }
          *(bf16x8*)(g_qf + base + dbase) = ov;
        }
      }
    }
    __syncthreads();
  }
}

// ---------------------------------------------------------------------------
// kernelF: per 32 tokens: gather qf[q_t][top1_t] -> q_fused out (fp32) and
// LDS; proj (cor|inc) bf16 MFMA; qa_fused by r.
// ---------------------------------------------------------------------------
__global__ void __launch_bounds__(128) kernelF(
    const int* __restrict__ q, const int* __restrict__ r,
    const float* __restrict__ pcb, const float* __restrict__ pib,
    float* __restrict__ out)
{
  __shared__ __align__(16) unsigned short QF[32 * 264];
  __shared__ int rv_l[32];
  const int tid = threadIdx.x;
  const int t0 = blockIdx.x * 32;
  const int w = tid >> 6;
  const int lane = tid & 63;
  const int l15 = lane & 15;
  const int quad = lane >> 4;
  if (tid < 32) rv_l[tid] = r[t0 + tid];
  __syncthreads();

  {
    const int m = tid >> 2;
    const size_t row = ((size_t)q[t0 + m] * 4 + g_top1[t0 + m]) * 256;
#pragma unroll
    for (int i = 0; i < 8; ++i) {
      const int dbase = (tid & 3) * 64 + i * 8;
      bf16x8 v = *(const bf16x8*)(g_qf + row + dbase);
      *(bf16x8*)&QF[m * 264 + dbase] = v;
      f32x4 f0, f1;
#pragma unroll
      for (int c = 0; c < 4; ++c) f0[c] = bf2f((unsigned short)v[c]);
#pragma unroll
      for (int c = 0; c < 4; ++c) f1[c] = bf2f((unsigned short)v[4 + c]);
      *(f32x4*)(out + (size_t)(t0 + m) * 256 + dbase) = f0;
      *(f32x4*)(out + (size_t)(t0 + m) * 256 + dbase + 4) = f1;
    }
  }
  __syncthreads();

  const f32x4 z4 = {0.f, 0.f, 0.f, 0.f};
  const int n0 = w * 128;
  for (int ph = 0; ph < 2; ++ph) {
    f32x4 acc[2][8];
#pragma unroll
    for (int a = 0; a < 2; ++a)
#pragma unroll
      for (int bq = 0; bq < 8; ++bq) acc[a][bq] = z4;
#pragma unroll
    for (int ks = 0; ks < 8; ++ks) {
      const int koff = ks * 32 + quad * 8;
      bf16x8 a0 = *(const bf16x8*)&QF[l15 * 264 + koff];
      bf16x8 a1 = *(const bf16x8*)&QF[(16 + l15) * 264 + koff];
#pragma unroll
      for (int nt = 0; nt < 8; ++nt) {
        bf16x8 bbv = *(const bf16x8*)(g_projt +
            (size_t)(ph * 256 + n0 + nt * 16 + l15) * 256 + koff);
        acc[0][nt] = mfma16(a0, bbv, acc[0][nt]);
        acc[1][nt] = mfma16(a1, bbv, acc[1][nt]);
      }
    }
    const float* pbb = ph ? pib : pcb;
    const int want = ph ? 0 : 1;
#pragma unroll
    for (int nt = 0; nt < 8; ++nt) {
      const int n = n0 + nt * 16 + l15;
      const float pbv = pbb[n];
#pragma unroll
      for (int mt = 0; mt < 2; ++mt)
#pragma unroll
        for (int rg = 0; rg < 4; ++rg) {
          const int m = mt * 16 + quad * 4 + rg;
          if (rv_l[m] == want)
            out[(size_t)TT * 256 + (size_t)(t0 + m) * 256 + n] =
                acc[mt][nt][rg] + pbv;
        }
    }
  }
}

// ---------------------------------------------------------------------------
extern "C" void kernel_launch(void* const* d_in, const int* in_sizes, int n_in,
                              void* d_out, int out_size, void* d_ws, size_t ws_size,
                              hipStream_t stream)
{
  const int*   q   = (const int*)d_in[0];
  const int*   r   = (const int*)d_in[1];
  const float* emb = (const float*)d_in[2];
  const float* ew1 = (const float*)d_in[3];
  const float* eb1 = (const float*)d_in[4];
  const float* ew2 = (const float*)d_in[5];
  const float* eb2 = (const float*)d_in[6];
  const float* aw  = (const float*)d_in[7];
  const float* ab  = (const float*)d_in[8];
  const float* rw  = (const float*)d_in[9];
  const float* rb  = (const float*)d_in[10];
  const float* st  = (const float*)d_in[11];
  const float* wih = (const float*)d_in[12];
  const float* whh = (const float*)d_in[13];
  const float* bih = (const float*)d_in[14];
  const float* bhh = (const float*)d_in[15];
  const float* wgw = (const float*)d_in[16];
  const float* wgb = (const float*)d_in[17];
  const float* lng = (const float*)d_in[18];
  const float* lnb = (const float*)d_in[19];
  const float* resp= (const float*)d_in[20];
  const float* pcw = (const float*)d_in[21];
  const float* pcb = (const float*)d_in[22];
  const float* piw = (const float*)d_in[23];
  const float* pib = (const float*)d_in[24];
  float* out = (float*)d_out;
  (void)bih; (void)in_sizes; (void)n_in; (void)d_ws; (void)ws_size; (void)out_size;

  prep_kernel<<<64, 256, 0, stream>>>(ew1, ew2, pcw, piw, resp, rw, rb, st, wih, bih);
  qsk_kernel<<<dim3(157, 4), 256, 0, stream>>>(emb, aw, ab);
  smallk_kernel<<<NQ, 256, 0, stream>>>(rw, wih, wgw);
  gru_kernel<<<64, 128, 0, stream>>>(q, r, whh, bhh);
  top1_kernel<<<128, 256, 0, stream>>>(q, wgw, wgb);
  kernelE<<<313, 128, 0, stream>>>(emb, eb1, eb2, lng, lnb);
  kernelF<<<1024, 128, 0, stream>>>(q, r, pcb, pib, out);
}

// Round 5
// 870.807 us; speedup vs baseline: 1.3904x; 1.2391x over previous
//
#include <hip/hip_runtime.h>
#include <cstddef>

// ---------------------------------------------------------------------------
// PolyaAKT interaction embedder, MI355X/gfx950.  Inputs fp32, output fp32.
// Control path (logits/GRU) high-precision for argmax fidelity; value path
// (experts/LN/proj) in bf16 MFMA.  Per-q dedup throughout.
// R10: kernelE de-starved (R9 counters: LDS 97.5KB -> 1 block/CU, 2 waves,
// Occupancy 3.6%, MfmaUtil 1.4% -- latency-bound with no waves):
//  - experts split across blocks: grid (313,4), e = blockIdx.y.  Each block
//    stages only its expert's 32x256 emb slice (16.9 KB; the 4 expert
//    slices are disjoint -> same total traffic, 1/4 the LDS).
//  - LDS 99.8 -> 50.7 KB -> 3 blocks/CU; grid 313 -> 1252 blocks -> CUs
//    saturated at 6 waves/CU (vs 2.4).
// GRU keeps R9's 2-wave k-split structure (resident W by construction).
// ---------------------------------------------------------------------------

#define NQ 10000
#define TT 32768   // B*S

typedef __attribute__((ext_vector_type(8))) short bf16x8;
typedef __attribute__((ext_vector_type(4))) float f32x4;

__device__ double g_qs  [NQ * 256];      // q_summary (relu'd), fp64
__device__ double g_xgr [2 * 192];       // r-part of xg (+b_ih), fp64
__device__ float  g_xg0f[192];           // start_token @ W_ih^T + b_ih (fp32)
__device__ float  g_xq2 [NQ * 384];      // r-folded xg: [q][r][192] fp32
__device__ double g_lq  [NQ * 4];        // qs @ wgate[0:256]
__device__ float  g_m   [TT * 64];       // GRU hidden per token (fp32)
__device__ int    g_top1[TT];
__device__ unsigned short g_w1t  [4 * 256 * 256];  // bf16 [e][n][k]
__device__ unsigned short g_w2t  [4 * 256 * 256];
__device__ unsigned short g_projt[512 * 256];      // bf16 [n(cor|inc)][k]
__device__ unsigned short g_qf   [NQ * 4 * 256];   // LN'd expert out, bf16

__device__ __forceinline__ float bf2f(unsigned short x) {
  return __uint_as_float(((unsigned)x) << 16);
}
__device__ __forceinline__ unsigned short f2bf(float f) {
  unsigned u = __float_as_uint(f);
  u += 0x7FFFu + ((u >> 16) & 1u);   // RNE
  return (unsigned short)(u >> 16);
}
__device__ __forceinline__ f32x4 mfma16(bf16x8 a, bf16x8 b, f32x4 c) {
  return __builtin_amdgcn_mfma_f32_16x16x32_bf16(a, b, c, 0, 0, 0);
}
// packed fp32 fma: c = a*b + c on both lanes of the pair (bit-identical to
// two scalar v_fma_f32, just one instruction).
__device__ __forceinline__ void pkfma(float2& c, float2 a, float2 b) {
  asm("v_pk_fma_f32 %0, %1, %2, %0" : "+v"(c) : "v"(a), "v"(b));
}

// fast fp64 exp (slow path only): range-reduced degree-10 poly, rel err ~2e-13.
__device__ __forceinline__ double fexp(double x) {
  const double L2E  = 1.4426950408889634074;
  const double LN2H = 6.93147180369123816490e-01;
  const double LN2L = 1.90821492927058770002e-10;
  double n = rint(x * L2E);
  int ni = (int)n;
  double r = fma(-n, LN2H, x);
  r = fma(-n, LN2L, r);
  double p = 2.7557319223985888e-07;
  p = fma(p, r, 2.7557319223985893e-06);
  p = fma(p, r, 2.4801587301587302e-05);
  p = fma(p, r, 1.9841269841269841e-04);
  p = fma(p, r, 1.3888888888888889e-03);
  p = fma(p, r, 8.3333333333333332e-03);
  p = fma(p, r, 4.1666666666666664e-02);
  p = fma(p, r, 1.6666666666666666e-01);
  p = fma(p, r, 0.5);
  p = fma(p, r, 1.0);
  p = fma(p, r, 1.0);
  return ldexp(p, ni);
}

// tanh via odd Taylor, |p| <= 0.25: abs err ~5e-11.
__device__ __forceinline__ double tpoly(double p) {
  const double p2 = p * p;
  double t = -1382.0 / 155925.0;          // p^11
  t = fma(t, p2, 62.0 / 2835.0);          // p^9
  t = fma(t, p2, -17.0 / 315.0);          // p^7
  t = fma(t, p2, 2.0 / 15.0);             // p^5
  t = fma(t, p2, -1.0 / 3.0);             // p^3
  t = fma(t, p2, 1.0);
  return p * t;
}

// ---------------------------------------------------------------------------
// prep: bf16 transposed weight tables + fp64 folds (xg_r, xg0).
// ---------------------------------------------------------------------------
__global__ void __launch_bounds__(256) prep_kernel(
    const float* __restrict__ expert_w1, const float* __restrict__ expert_w2,
    const float* __restrict__ proj_cor_w, const float* __restrict__ proj_inc_w,
    const float* __restrict__ resp_table, const float* __restrict__ reducer_w,
    const float* __restrict__ reducer_b,  const float* __restrict__ start_token,
    const float* __restrict__ gru_w_ih,   const float* __restrict__ gru_b_ih)
{
  __shared__ double red2f[128];   // [rr][j]
  const int tid = threadIdx.x;
  if (blockIdx.x == 0) {
    if (tid < 128) {
      const int rr = tid >> 6, j = tid & 63;
      double acc = (double)reducer_b[j];
      for (int k = 0; k < 256; ++k)
        acc += (double)resp_table[rr * 256 + k] *
               (double)reducer_w[(256 + k) * 64 + j];
      red2f[tid] = acc;
    }
    __syncthreads();
    if (tid < 192) {
      const double bih = (double)gru_b_ih[tid];
      double a0 = bih, a1 = bih, a2 = bih;
      for (int j = 0; j < 64; ++j) {
        const double w = (double)gru_w_ih[tid * 64 + j];
        a0 += red2f[j] * w;
        a1 += red2f[64 + j] * w;
        a2 += (double)start_token[j] * w;
      }
      g_xgr[tid] = a0; g_xgr[192 + tid] = a1; g_xg0f[tid] = (float)a2;
    }
  }
  const int idx0 = blockIdx.x * 256 + tid;
  const int stride = gridDim.x * 256;
  for (int i = idx0; i < 4 * 256 * 256; i += stride) {
    const int e = i >> 16, rem = i & 65535, n = rem >> 8, k = rem & 255;
    g_w1t[i] = f2bf(expert_w1[e * 65536 + k * 256 + n]);
    g_w2t[i] = f2bf(expert_w2[e * 65536 + k * 256 + n]);
  }
  for (int i = idx0; i < 512 * 256; i += stride) {
    const int n = i >> 8, k = i & 255;
    g_projt[i] = f2bf((n < 256) ? proj_cor_w[k * 256 + n]
                                : proj_inc_w[k * 256 + (n - 256)]);
  }
}

// ---------------------------------------------------------------------------
// qsk: fp64 GEMM  qs[q][n] = relu( emb_row_q(1024) . adapter_w[:,n] + b[n] )
// ---------------------------------------------------------------------------
__global__ void __launch_bounds__(256) qsk_kernel(
    const float* __restrict__ emb, const float* __restrict__ adapter_w,
    const float* __restrict__ adapter_b)
{
  __shared__ __align__(16) float As[64][33];
  __shared__ __align__(16) float Bs[32][65];
  const int tid = threadIdx.x;
  const int q0 = blockIdx.x * 64;
  const int n0 = blockIdx.y * 64;
  const int ty = tid >> 4, tx = tid & 15;

  double acc[4][4];
#pragma unroll
  for (int i = 0; i < 4; ++i)
#pragma unroll
    for (int j = 0; j < 4; ++j) acc[i][j] = 0.0;

  const int arow = tid >> 2, aks = (tid & 3) * 8;
  const int qa = min(q0 + arow, NQ - 1);
  const int bkk = tid >> 3, bns = (tid & 7) * 8;

  for (int kc = 0; kc < 1024; kc += 32) {
    f32x4 av0 = *(const f32x4*)(emb + (size_t)qa * 1024 + kc + aks);
    f32x4 av1 = *(const f32x4*)(emb + (size_t)qa * 1024 + kc + aks + 4);
    f32x4 bv0 = *(const f32x4*)(adapter_w + (size_t)(kc + bkk) * 256 + n0 + bns);
    f32x4 bv1 = *(const f32x4*)(adapter_w + (size_t)(kc + bkk) * 256 + n0 + bns + 4);
    __syncthreads();
#pragma unroll
    for (int i = 0; i < 4; ++i) { As[arow][aks + i] = av0[i]; As[arow][aks + 4 + i] = av1[i]; }
#pragma unroll
    for (int i = 0; i < 4; ++i) { Bs[bkk][bns + i] = bv0[i]; Bs[bkk][bns + 4 + i] = bv1[i]; }
    __syncthreads();
#pragma unroll 4
    for (int kk = 0; kk < 32; ++kk) {
      double a[4], b[4];
#pragma unroll
      for (int i = 0; i < 4; ++i) a[i] = (double)As[ty * 4 + i][kk];
#pragma unroll
      for (int j = 0; j < 4; ++j) b[j] = (double)Bs[kk][tx * 4 + j];
#pragma unroll
      for (int i = 0; i < 4; ++i)
#pragma unroll
        for (int j = 0; j < 4; ++j) acc[i][j] = fma(a[i], b[j], acc[i][j]);
    }
  }
#pragma unroll
  for (int i = 0; i < 4; ++i) {
    const int qrow = q0 + ty * 4 + i;
    if (qrow < NQ) {
#pragma unroll
      for (int j = 0; j < 4; ++j) {
        const int n = n0 + tx * 4 + j;
        double v = acc[i][j] + (double)adapter_b[n];
        g_qs[(size_t)qrow * 256 + n] = v > 0.0 ? v : 0.0;
      }
    }
  }
}

// ---------------------------------------------------------------------------
// smallk: per q -> gru_in_q(64), r-folded xg table (fp32), lq(4).
// One block per q.
// ---------------------------------------------------------------------------
__global__ void __launch_bounds__(256) smallk_kernel(
    const float* __restrict__ reducer_w, const float* __restrict__ gru_w_ih,
    const float* __restrict__ wgate_w)
{
  __shared__ double qsr[256];
  __shared__ double ps[4][64];
  __shared__ double gi[64];
  const int tid = threadIdx.x;
  const int qq = blockIdx.x;
  qsr[tid] = g_qs[(size_t)qq * 256 + tid];
  __syncthreads();
  {
    const int j = tid & 63, h = tid >> 6;
    const int k0 = h * 64;
    double a0 = 0.0, a1 = 0.0, a2 = 0.0, a3 = 0.0;
    for (int k = 0; k < 64; k += 4) {
      a0 = fma(qsr[k0 + k + 0], (double)reducer_w[(k0 + k + 0) * 64 + j], a0);
      a1 = fma(qsr[k0 + k + 1], (double)reducer_w[(k0 + k + 1) * 64 + j], a1);
      a2 = fma(qsr[k0 + k + 2], (double)reducer_w[(k0 + k + 2) * 64 + j], a2);
      a3 = fma(qsr[k0 + k + 3], (double)reducer_w[(k0 + k + 3) * 64 + j], a3);
    }
    ps[h][j] = (a0 + a1) + (a2 + a3);
  }
  __syncthreads();
  if (tid < 64) gi[tid] = (ps[0][tid] + ps[1][tid]) + (ps[2][tid] + ps[3][tid]);
  if (tid >= 64 && tid < 68) {
    const int e = tid - 64;
    double a0 = 0.0, a1 = 0.0, a2 = 0.0, a3 = 0.0;
    for (int k = 0; k < 256; k += 4) {
      a0 = fma(qsr[k + 0], (double)wgate_w[(k + 0) * 4 + e], a0);
      a1 = fma(qsr[k + 1], (double)wgate_w[(k + 1) * 4 + e], a1);
      a2 = fma(qsr[k + 2], (double)wgate_w[(k + 2) * 4 + e], a2);
      a3 = fma(qsr[k + 3], (double)wgate_w[(k + 3) * 4 + e], a3);
    }
    g_lq[(size_t)qq * 4 + e] = (a0 + a1) + (a2 + a3);
  }
  __syncthreads();
  if (tid < 192) {
    double a0 = 0.0, a1 = 0.0, a2 = 0.0, a3 = 0.0;
    for (int k = 0; k < 64; k += 4) {
      a0 = fma(gi[k + 0], (double)gru_w_ih[tid * 64 + k + 0], a0);
      a1 = fma(gi[k + 1], (double)gru_w_ih[tid * 64 + k + 1], a1);
      a2 = fma(gi[k + 2], (double)gru_w_ih[tid * 64 + k + 2], a2);
      a3 = fma(gi[k + 3], (double)gru_w_ih[tid * 64 + k + 3], a3);
    }
    const double s = (a0 + a1) + (a2 + a3);
    // r-folded x values (fp32): one extra rounding ~1e-8, below the
    // reference's own fp32 noise -> argmax decisions unaffected.
    g_xq2[(size_t)qq * 384 + tid]       = (float)(s + g_xgr[tid]);
    g_xq2[(size_t)qq * 384 + 192 + tid] = (float)(s + g_xgr[192 + tid]);
  }
}

// ---------------------------------------------------------------------------
// gru: 64 blocks x 128 threads (2 waves).  wave w owns rows j = w*32+p;
// lane pair (2p, 2p+1) splits row p's dots over k-halves [0,32)/[32,64).
// Per-lane W = 48 float2 = 96 VGPRs -> resident by construction.
// Half-sums combine via __shfl_xor(.,1) (in-pair, no LDS); both pair lanes
// run the fp64 tail redundantly.  h exchanged via double-buffered HF[2][64],
// ONE raw s_barrier per step (lgkmcnt-only drain; g_m stores not drained).
// Per step: prefetch next r-folded x (3 floats) + q/r one step ahead.
// ---------------------------------------------------------------------------
__global__ void __launch_bounds__(128, 1) gru_kernel(
    const int* __restrict__ q, const int* __restrict__ r,
    const float* __restrict__ whh, const float* __restrict__ bhh)
{
  __shared__ __align__(16) float HF[2][64];
  const int tid = threadIdx.x;
  const int b = blockIdx.x;
  const int wv = tid >> 6;           // wave: rows [wv*32, wv*32+32)
  const int l = tid & 63;
  const int p = l >> 1;              // row within wave
  const int half = l & 1;            // k-half
  const int j = wv * 32 + p;         // row
  const int k0 = half * 32;

  // W half-rows for this lane, fp32 float2 pairs, resident (96 VGPRs).
  float2 Wr[16], Wz[16], Wn[16];
#pragma unroll
  for (int i = 0; i < 16; ++i) {
    Wr[i] = *(const float2*)(whh + (size_t)(0 * 64 + j) * 64 + k0 + 2 * i);
    Wz[i] = *(const float2*)(whh + (size_t)(1 * 64 + j) * 64 + k0 + 2 * i);
    Wn[i] = *(const float2*)(whh + (size_t)(2 * 64 + j) * 64 + k0 + 2 * i);
  }
#pragma unroll
  for (int i = 0; i < 16; ++i) {
    asm volatile("" : "+v"(Wr[i]));
    asm volatile("" : "+v"(Wz[i]));
    asm volatile("" : "+v"(Wn[i]));
  }
  const double br = (double)bhh[j];
  const double bz = (double)bhh[64 + j];
  const double bn = (double)bhh[128 + j];

  // step 0 consumes the start token (b_ih already folded in g_xg0f)
  float cx0 = g_xg0f[j], cx1 = g_xg0f[64 + j], cx2 = g_xg0f[128 + j];
  int qA = q[b * 512], rA = r[b * 512];

  if (tid < 64) HF[0][tid] = 0.f;
  double hd = 0.0;
  asm volatile("s_waitcnt lgkmcnt(0)\n\ts_barrier" ::: "memory");

  for (int t = 0; t < 512; ++t) {
    // prefetch x for step t+1 (token t) and q/r for token t+1
    float nx0 = 0.f, nx1 = 0.f, nx2 = 0.f;
    int qB = qA, rB = rA;
    if (t < 511) {
      const size_t base = (size_t)(qA * 2 + rA) * 192 + j;
      nx0 = g_xq2[base];
      nx1 = g_xq2[base + 64];
      nx2 = g_xq2[base + 128];
      const int tk = min(t + 1, 510);
      qB = q[b * 512 + tk];
      rB = r[b * 512 + tk];
    }

    // half-dot: 48 packed fp32 FMAs against resident W
    float2 ar = {0.f, 0.f}, az = {0.f, 0.f}, an = {0.f, 0.f};
    {
      const float4* hp = (const float4*)&HF[t & 1][k0];
#pragma unroll
      for (int g = 0; g < 8; ++g) {
        const float4 t4 = hp[g];
        const float2 hA = make_float2(t4.x, t4.y);
        const float2 hB = make_float2(t4.z, t4.w);
        pkfma(ar, Wr[2 * g], hA); pkfma(ar, Wr[2 * g + 1], hB);
        pkfma(az, Wz[2 * g], hA); pkfma(az, Wz[2 * g + 1], hB);
        pkfma(an, Wn[2 * g], hA); pkfma(an, Wn[2 * g + 1], hB);
      }
    }
    // combine k-halves in-pair (fp64 add is commutative -> pair-uniform)
    const float srh = ar.x + ar.y;
    const float szh = az.x + az.y;
    const float snh = an.x + an.y;
    const float sro = __shfl_xor(srh, 1);
    const float szo = __shfl_xor(szh, 1);
    const float sno = __shfl_xor(snh, 1);
    const double hr = br + ((double)srh + (double)sro);
    const double hz = bz + ((double)szh + (double)szo);
    const double hn = bn + ((double)snh + (double)sno);
    const double pr = (double)cx0 + hr, pz = (double)cx1 + hz;
    const double xn = (double)cx2;
    double rg = fma(0.5, tpoly(0.5 * pr), 0.5);
    double zg = fma(0.5, tpoly(0.5 * pz), 0.5);
    double pre = fma(rg, hn, xn);
    double ng = tpoly(pre);
    const bool bad = (fabs(pr) > 0.5) | (fabs(pz) > 0.5) | (fabs(pre) > 0.25);
    if (bad) {   // rare slow path
      rg = 1.0 / (1.0 + fexp(-pr));
      zg = 1.0 / (1.0 + fexp(-pz));
      pre = fma(rg, hn, xn);
      ng = 1.0 - 2.0 / (fexp(pre + pre) + 1.0);
    }
    const double hnew = fma(zg, hd - ng, ng);   // (1-z)n + z h
    hd = hnew;
    const float hnf = (float)hnew;
    if (half == 0) {
      HF[(t & 1) ^ 1][j] = hnf;
      g_m[((size_t)b * 512 + t) * 64 + j] = hnf;
    }
    asm volatile("s_waitcnt lgkmcnt(0)\n\ts_barrier" ::: "memory");

    cx0 = nx0; cx1 = nx1; cx2 = nx2;
    qA = qB; rA = rB;
  }
}

// ---------------------------------------------------------------------------
// top1: logits = lq[q_t] + m_t @ wgate[256:320] + wgate_b ; first-max argmax.
// ---------------------------------------------------------------------------
__global__ void __launch_bounds__(256) top1_kernel(
    const int* __restrict__ q,
    const float* __restrict__ wgate_w, const float* __restrict__ wgate_b)
{
  __shared__ double w2[256];   // [j][e]
  const int tid = threadIdx.x;
  w2[tid] = (double)wgate_w[1024 + tid];
  __syncthreads();
  const int t = blockIdx.x * 256 + tid;
  const int qv = q[t];
  double l0 = g_lq[(size_t)qv * 4 + 0] + (double)wgate_b[0];
  double l1 = g_lq[(size_t)qv * 4 + 1] + (double)wgate_b[1];
  double l2 = g_lq[(size_t)qv * 4 + 2] + (double)wgate_b[2];
  double l3 = g_lq[(size_t)qv * 4 + 3] + (double)wgate_b[3];
  const f32x4* mr4 = (const f32x4*)(g_m + (size_t)t * 64);
#pragma unroll 4
  for (int jj = 0; jj < 16; ++jj) {
    const f32x4 mv4 = mr4[jj];
#pragma unroll
    for (int c = 0; c < 4; ++c) {
      const double mv = (double)mv4[c];
      const int k = (jj * 4 + c) * 4;
      l0 = fma(mv, w2[k + 0], l0);
      l1 = fma(mv, w2[k + 1], l1);
      l2 = fma(mv, w2[k + 2], l2);
      l3 = fma(mv, w2[k + 3], l3);
    }
  }
  int bi = 0; double bvv = l0;
  if (l1 > bvv) { bvv = l1; bi = 1; }
  if (l2 > bvv) { bvv = l2; bi = 2; }
  if (l3 > bvv) { bvv = l3; bi = 3; }
  g_top1[t] = bi;
}

// ---------------------------------------------------------------------------
// kernelE: grid (313, 4): 32 q-values x one expert per block.
// Stage expert-e emb slice (32x256) as bf16; h1=relu(qr_e@W1+b1);
// out=h1@W2+b2 -> LN -> qf[q][e] bf16.  LDS 50.7 KB -> 3 blocks/CU.
// ---------------------------------------------------------------------------
__global__ void __launch_bounds__(128) kernelE(
    const float* __restrict__ emb,
    const float* __restrict__ b1, const float* __restrict__ b2,
    const float* __restrict__ lng, const float* __restrict__ lnb)
{
  __shared__ __align__(16) unsigned short QR[32 * 264];
  __shared__ __align__(16) unsigned short H1[32 * 264];
  __shared__ __align__(16) unsigned short EO[32 * 264];
  const int tid = threadIdx.x;
  const int t0 = blockIdx.x * 32;
  const int e  = blockIdx.y;
  const int w = tid >> 6;
  const int lane = tid & 63;
  const int l15 = lane & 15;
  const int quad = lane >> 4;

  // stage expert-e slice: 32 rows x 256 cols fp32 -> bf16
  for (int c = 0; c < 16; ++c) {
    const int idx = c * 128 + tid;           // f32x4 chunks: 32 rows x 64
    const int row = idx >> 6, col4 = idx & 63;
    const int qv = min(t0 + row, NQ - 1);
    f32x4 v = *(const f32x4*)(emb + (size_t)qv * 1024 + e * 256 + col4 * 4);
    unsigned a = ((unsigned)f2bf(v[1]) << 16) | f2bf(v[0]);
    unsigned bb = ((unsigned)f2bf(v[3]) << 16) | f2bf(v[2]);
    *(uint2*)&QR[row * 264 + col4 * 4] = make_uint2(a, bb);
  }
  __syncthreads();

  const f32x4 z4 = {0.f, 0.f, 0.f, 0.f};
  const int n0 = w * 128;

  f32x4 acc[2][8];
#pragma unroll
  for (int a = 0; a < 2; ++a)
#pragma unroll
    for (int bq = 0; bq < 8; ++bq) acc[a][bq] = z4;
#pragma unroll
  for (int ks = 0; ks < 8; ++ks) {
    const int koff = ks * 32 + quad * 8;
    bf16x8 a0 = *(const bf16x8*)&QR[l15 * 264 + koff];
    bf16x8 a1 = *(const bf16x8*)&QR[(16 + l15) * 264 + koff];
#pragma unroll
    for (int nt = 0; nt < 8; ++nt) {
      bf16x8 bbv = *(const bf16x8*)(g_w1t + (size_t)e * 65536 +
                                    (size_t)(n0 + nt * 16 + l15) * 256 + koff);
      acc[0][nt] = mfma16(a0, bbv, acc[0][nt]);
      acc[1][nt] = mfma16(a1, bbv, acc[1][nt]);
    }
  }
#pragma unroll
  for (int nt = 0; nt < 8; ++nt) {
    const int n = n0 + nt * 16 + l15;
    const float b1v = b1[e * 256 + n];
#pragma unroll
    for (int mt = 0; mt < 2; ++mt)
#pragma unroll
      for (int rg = 0; rg < 4; ++rg) {
        const int m = mt * 16 + quad * 4 + rg;
        H1[m * 264 + n] = f2bf(fmaxf(acc[mt][nt][rg] + b1v, 0.f));
      }
  }
  __syncthreads();

  f32x4 acc2[2][8];
#pragma unroll
  for (int a = 0; a < 2; ++a)
#pragma unroll
    for (int bq = 0; bq < 8; ++bq) acc2[a][bq] = z4;
#pragma unroll
  for (int ks = 0; ks < 8; ++ks) {
    const int koff = ks * 32 + quad * 8;
    bf16x8 a0 = *(const bf16x8*)&H1[l15 * 264 + koff];
    bf16x8 a1 = *(const bf16x8*)&H1[(16 + l15) * 264 + koff];
#pragma unroll
    for (int nt = 0; nt < 8; ++nt) {
      bf16x8 bbv = *(const bf16x8*)(g_w2t + (size_t)e * 65536 +
                                    (size_t)(n0 + nt * 16 + l15) * 256 + koff);
      acc2[0][nt] = mfma16(a0, bbv, acc2[0][nt]);
      acc2[1][nt] = mfma16(a1, bbv, acc2[1][nt]);
    }
  }
#pragma unroll
  for (int nt = 0; nt < 8; ++nt) {
    const int n = n0 + nt * 16 + l15;
    const float b2v = b2[e * 256 + n];
#pragma unroll
    for (int mt = 0; mt < 2; ++mt)
#pragma unroll
      for (int rg = 0; rg < 4; ++rg) {
        const int m = mt * 16 + quad * 4 + rg;
        EO[m * 264 + n] = f2bf(acc2[mt][nt][rg] + b2v);
      }
  }
  __syncthreads();

  {
    const int m = tid >> 2;
    const int sub = tid & 3;
    float sx = 0.f, sxx = 0.f;
#pragma unroll
    for (int i = 0; i < 8; ++i) {
      bf16x8 v = *(const bf16x8*)&EO[m * 264 + sub * 64 + i * 8];
#pragma unroll
      for (int c = 0; c < 8; ++c) {
        const float f = bf2f((unsigned short)v[c]);
        sx += f; sxx += f * f;
      }
    }
    sx += __shfl_xor(sx, 1); sxx += __shfl_xor(sxx, 1);
    sx += __shfl_xor(sx, 2); sxx += __shfl_xor(sxx, 2);
    const float mu = sx * (1.f / 256.f);
    const float var = sxx * (1.f / 256.f) - mu * mu;
    const float inv = 1.f / sqrtf(var + 1e-5f);
    if (t0 + m < NQ) {
      const size_t base = ((size_t)(t0 + m) * 4 + e) * 256;
#pragma unroll
      for (int i = 0; i < 8; ++i) {
        const int dbase = sub * 64 + i * 8;
        bf16x8 v = *(const bf16x8*)&EO[m * 264 + dbase];
        bf16x8 ov;
#pragma unroll
        for (int c = 0; c < 8; ++c) {
          const int d = dbase + c;
          const float f = bf2f((unsigned short)v[c]);
          ov[c] = (short)f2bf(lng[d] * (f - mu) * inv + lnb[d]);
        }
        *(bf16x8*)(g_qf + base + dbase) = ov;
      }
    }
  }
}

// ---------------------------------------------------------------------------
// kernelF: per 32 tokens: gather qf[q_t][top1_t] -> q_fused out (fp32) and
// LDS; proj (cor|inc) bf16 MFMA; qa_fused by r.
// ---------------------------------------------------------------------------
__global__ void __launch_bounds__(128) kernelF(
    const int* __restrict__ q, const int* __restrict__ r,
    const float* __restrict__ pcb, const float* __restrict__ pib,
    float* __restrict__ out)
{
  __shared__ __align__(16) unsigned short QF[32 * 264];
  __shared__ int rv_l[32];
  const int tid = threadIdx.x;
  const int t0 = blockIdx.x * 32;
  const int w = tid >> 6;
  const int lane = tid & 63;
  const int l15 = lane & 15;
  const int quad = lane >> 4;
  if (tid < 32) rv_l[tid] = r[t0 + tid];
  __syncthreads();

  {
    const int m = tid >> 2;
    const size_t row = ((size_t)q[t0 + m] * 4 + g_top1[t0 + m]) * 256;
#pragma unroll
    for (int i = 0; i < 8; ++i) {
      const int dbase = (tid & 3) * 64 + i * 8;
      bf16x8 v = *(const bf16x8*)(g_qf + row + dbase);
      *(bf16x8*)&QF[m * 264 + dbase] = v;
      f32x4 f0, f1;
#pragma unroll
      for (int c = 0; c < 4; ++c) f0[c] = bf2f((unsigned short)v[c]);
#pragma unroll
      for (int c = 0; c < 4; ++c) f1[c] = bf2f((unsigned short)v[4 + c]);
      *(f32x4*)(out + (size_t)(t0 + m) * 256 + dbase) = f0;
      *(f32x4*)(out + (size_t)(t0 + m) * 256 + dbase + 4) = f1;
    }
  }
  __syncthreads();

  const f32x4 z4 = {0.f, 0.f, 0.f, 0.f};
  const int n0 = w * 128;
  for (int ph = 0; ph < 2; ++ph) {
    f32x4 acc[2][8];
#pragma unroll
    for (int a = 0; a < 2; ++a)
#pragma unroll
      for (int bq = 0; bq < 8; ++bq) acc[a][bq] = z4;
#pragma unroll
    for (int ks = 0; ks < 8; ++ks) {
      const int koff = ks * 32 + quad * 8;
      bf16x8 a0 = *(const bf16x8*)&QF[l15 * 264 + koff];
      bf16x8 a1 = *(const bf16x8*)&QF[(16 + l15) * 264 + koff];
#pragma unroll
      for (int nt = 0; nt < 8; ++nt) {
        bf16x8 bbv = *(const bf16x8*)(g_projt +
            (size_t)(ph * 256 + n0 + nt * 16 + l15) * 256 + koff);
        acc[0][nt] = mfma16(a0, bbv, acc[0][nt]);
        acc[1][nt] = mfma16(a1, bbv, acc[1][nt]);
      }
    }
    const float* pbb = ph ? pib : pcb;
    const int want = ph ? 0 : 1;
#pragma unroll
    for (int nt = 0; nt < 8; ++nt) {
      const int n = n0 + nt * 16 + l15;
      const float pbv = pbb[n];
#pragma unroll
      for (int mt = 0; mt < 2; ++mt)
#pragma unroll
        for (int rg = 0; rg < 4; ++rg) {
          const int m = mt * 16 + quad * 4 + rg;
          if (rv_l[m] == want)
            out[(size_t)TT * 256 + (size_t)(t0 + m) * 256 + n] =
                acc[mt][nt][rg] + pbv;
        }
    }
  }
}

// ---------------------------------------------------------------------------
extern "C" void kernel_launch(void* const* d_in, const int* in_sizes, int n_in,
                              void* d_out, int out_size, void* d_ws, size_t ws_size,
                              hipStream_t stream)
{
  const int*   q   = (const int*)d_in[0];
  const int*   r   = (const int*)d_in[1];
  const float* emb = (const float*)d_in[2];
  const float* ew1 = (const float*)d_in[3];
  const float* eb1 = (const float*)d_in[4];
  const float* ew2 = (const float*)d_in[5];
  const float* eb2 = (const float*)d_in[6];
  const float* aw  = (const float*)d_in[7];
  const float* ab  = (const float*)d_in[8];
  const float* rw  = (const float*)d_in[9];
  const float* rb  = (const float*)d_in[10];
  const float* st  = (const float*)d_in[11];
  const float* wih = (const float*)d_in[12];
  const float* whh = (const float*)d_in[13];
  const float* bih = (const float*)d_in[14];
  const float* bhh = (const float*)d_in[15];
  const float* wgw = (const float*)d_in[16];
  const float* wgb = (const float*)d_in[17];
  const float* lng = (const float*)d_in[18];
  const float* lnb = (const float*)d_in[19];
  const float* resp= (const float*)d_in[20];
  const float* pcw = (const float*)d_in[21];
  const float* pcb = (const float*)d_in[22];
  const float* piw = (const float*)d_in[23];
  const float* pib = (const float*)d_in[24];
  float* out = (float*)d_out;
  (void)bih; (void)in_sizes; (void)n_in; (void)d_ws; (void)ws_size; (void)out_size;

  prep_kernel<<<64, 256, 0, stream>>>(ew1, ew2, pcw, piw, resp, rw, rb, st, wih, bih);
  qsk_kernel<<<dim3(157, 4), 256, 0, stream>>>(emb, aw, ab);
  smallk_kernel<<<NQ, 256, 0, stream>>>(rw, wih, wgw);
  gru_kernel<<<64, 128, 0, stream>>>(q, r, whh, bhh);
  top1_kernel<<<128, 256, 0, stream>>>(q, wgw, wgb);
  kernelE<<<dim3(313, 4), 128, 0, stream>>>(emb, eb1, eb2, lng, lnb);
  kernelF<<<1024, 128, 0, stream>>>(q, r, pcb, pib, out);
}

// Round 6
// 856.067 us; speedup vs baseline: 1.4143x; 1.0172x over previous
//
#include <hip/hip_runtime.h>
#include <cstddef>

// ---------------------------------------------------------------------------
// PolyaAKT interaction embedder, MI355X/gfx950.  Inputs fp32, output fp32.
// Control path (logits/GRU) high-precision for argmax fidelity; value path
// (experts/LN/proj) in bf16 MFMA.  Per-q dedup throughout.
// R11: the actual residency knob.  R5-R10 all lost W residency because
// __launch_bounds__(N,1) only CAPS VGPRs (min waves/EU); the allocator's
// occupancy TARGET stayed at several waves/EU (~64-72 regs) so it spilled
// W every time (VGPR_Count 72-148 across 5 attempts).
//  - gru: __attribute__((amdgpu_waves_per_eu(1,1))) pins the target to
//    1 wave/EU -> full register budget -> 96-reg W set stays resident.
//    (Occupancy is irrelevant: 64 blocks on 64 CUs, serial-latency kernel.)
//  - HF padded [2][68] (odd half at word 36): kills the measured 2-way
//    bank conflict (SQ_LDS_BANK_CONFLICT was exactly 64/step).
// kernelE keeps R10's (313,4) expert-split grid.
// ---------------------------------------------------------------------------

#define NQ 10000
#define TT 32768   // B*S

typedef __attribute__((ext_vector_type(8))) short bf16x8;
typedef __attribute__((ext_vector_type(4))) float f32x4;

__device__ double g_qs  [NQ * 256];      // q_summary (relu'd), fp64
__device__ double g_xgr [2 * 192];       // r-part of xg (+b_ih), fp64
__device__ float  g_xg0f[192];           // start_token @ W_ih^T + b_ih (fp32)
__device__ float  g_xq2 [NQ * 384];      // r-folded xg: [q][r][192] fp32
__device__ double g_lq  [NQ * 4];        // qs @ wgate[0:256]
__device__ float  g_m   [TT * 64];       // GRU hidden per token (fp32)
__device__ int    g_top1[TT];
__device__ unsigned short g_w1t  [4 * 256 * 256];  // bf16 [e][n][k]
__device__ unsigned short g_w2t  [4 * 256 * 256];
__device__ unsigned short g_projt[512 * 256];      // bf16 [n(cor|inc)][k]
__device__ unsigned short g_qf   [NQ * 4 * 256];   // LN'd expert out, bf16

__device__ __forceinline__ float bf2f(unsigned short x) {
  return __uint_as_float(((unsigned)x) << 16);
}
__device__ __forceinline__ unsigned short f2bf(float f) {
  unsigned u = __float_as_uint(f);
  u += 0x7FFFu + ((u >> 16) & 1u);   // RNE
  return (unsigned short)(u >> 16);
}
__device__ __forceinline__ f32x4 mfma16(bf16x8 a, bf16x8 b, f32x4 c) {
  return __builtin_amdgcn_mfma_f32_16x16x32_bf16(a, b, c, 0, 0, 0);
}
// packed fp32 fma: c = a*b + c on both lanes of the pair (bit-identical to
// two scalar v_fma_f32, just one instruction).
__device__ __forceinline__ void pkfma(float2& c, float2 a, float2 b) {
  asm("v_pk_fma_f32 %0, %1, %2, %0" : "+v"(c) : "v"(a), "v"(b));
}

// fast fp64 exp (slow path only): range-reduced degree-10 poly, rel err ~2e-13.
__device__ __forceinline__ double fexp(double x) {
  const double L2E  = 1.4426950408889634074;
  const double LN2H = 6.93147180369123816490e-01;
  const double LN2L = 1.90821492927058770002e-10;
  double n = rint(x * L2E);
  int ni = (int)n;
  double r = fma(-n, LN2H, x);
  r = fma(-n, LN2L, r);
  double p = 2.7557319223985888e-07;
  p = fma(p, r, 2.7557319223985893e-06);
  p = fma(p, r, 2.4801587301587302e-05);
  p = fma(p, r, 1.9841269841269841e-04);
  p = fma(p, r, 1.3888888888888889e-03);
  p = fma(p, r, 8.3333333333333332e-03);
  p = fma(p, r, 4.1666666666666664e-02);
  p = fma(p, r, 1.6666666666666666e-01);
  p = fma(p, r, 0.5);
  p = fma(p, r, 1.0);
  p = fma(p, r, 1.0);
  return ldexp(p, ni);
}

// tanh via odd Taylor, |p| <= 0.25: abs err ~5e-11.
__device__ __forceinline__ double tpoly(double p) {
  const double p2 = p * p;
  double t = -1382.0 / 155925.0;          // p^11
  t = fma(t, p2, 62.0 / 2835.0);          // p^9
  t = fma(t, p2, -17.0 / 315.0);          // p^7
  t = fma(t, p2, 2.0 / 15.0);             // p^5
  t = fma(t, p2, -1.0 / 3.0);             // p^3
  t = fma(t, p2, 1.0);
  return p * t;
}

// ---------------------------------------------------------------------------
// prep: bf16 transposed weight tables + fp64 folds (xg_r, xg0).
// ---------------------------------------------------------------------------
__global__ void __launch_bounds__(256) prep_kernel(
    const float* __restrict__ expert_w1, const float* __restrict__ expert_w2,
    const float* __restrict__ proj_cor_w, const float* __restrict__ proj_inc_w,
    const float* __restrict__ resp_table, const float* __restrict__ reducer_w,
    const float* __restrict__ reducer_b,  const float* __restrict__ start_token,
    const float* __restrict__ gru_w_ih,   const float* __restrict__ gru_b_ih)
{
  __shared__ double red2f[128];   // [rr][j]
  const int tid = threadIdx.x;
  if (blockIdx.x == 0) {
    if (tid < 128) {
      const int rr = tid >> 6, j = tid & 63;
      double acc = (double)reducer_b[j];
      for (int k = 0; k < 256; ++k)
        acc += (double)resp_table[rr * 256 + k] *
               (double)reducer_w[(256 + k) * 64 + j];
      red2f[tid] = acc;
    }
    __syncthreads();
    if (tid < 192) {
      const double bih = (double)gru_b_ih[tid];
      double a0 = bih, a1 = bih, a2 = bih;
      for (int j = 0; j < 64; ++j) {
        const double w = (double)gru_w_ih[tid * 64 + j];
        a0 += red2f[j] * w;
        a1 += red2f[64 + j] * w;
        a2 += (double)start_token[j] * w;
      }
      g_xgr[tid] = a0; g_xgr[192 + tid] = a1; g_xg0f[tid] = (float)a2;
    }
  }
  const int idx0 = blockIdx.x * 256 + tid;
  const int stride = gridDim.x * 256;
  for (int i = idx0; i < 4 * 256 * 256; i += stride) {
    const int e = i >> 16, rem = i & 65535, n = rem >> 8, k = rem & 255;
    g_w1t[i] = f2bf(expert_w1[e * 65536 + k * 256 + n]);
    g_w2t[i] = f2bf(expert_w2[e * 65536 + k * 256 + n]);
  }
  for (int i = idx0; i < 512 * 256; i += stride) {
    const int n = i >> 8, k = i & 255;
    g_projt[i] = f2bf((n < 256) ? proj_cor_w[k * 256 + n]
                                : proj_inc_w[k * 256 + (n - 256)]);
  }
}

// ---------------------------------------------------------------------------
// qsk: fp64 GEMM  qs[q][n] = relu( emb_row_q(1024) . adapter_w[:,n] + b[n] )
// ---------------------------------------------------------------------------
__global__ void __launch_bounds__(256) qsk_kernel(
    const float* __restrict__ emb, const float* __restrict__ adapter_w,
    const float* __restrict__ adapter_b)
{
  __shared__ __align__(16) float As[64][33];
  __shared__ __align__(16) float Bs[32][65];
  const int tid = threadIdx.x;
  const int q0 = blockIdx.x * 64;
  const int n0 = blockIdx.y * 64;
  const int ty = tid >> 4, tx = tid & 15;

  double acc[4][4];
#pragma unroll
  for (int i = 0; i < 4; ++i)
#pragma unroll
    for (int j = 0; j < 4; ++j) acc[i][j] = 0.0;

  const int arow = tid >> 2, aks = (tid & 3) * 8;
  const int qa = min(q0 + arow, NQ - 1);
  const int bkk = tid >> 3, bns = (tid & 7) * 8;

  for (int kc = 0; kc < 1024; kc += 32) {
    f32x4 av0 = *(const f32x4*)(emb + (size_t)qa * 1024 + kc + aks);
    f32x4 av1 = *(const f32x4*)(emb + (size_t)qa * 1024 + kc + aks + 4);
    f32x4 bv0 = *(const f32x4*)(adapter_w + (size_t)(kc + bkk) * 256 + n0 + bns);
    f32x4 bv1 = *(const f32x4*)(adapter_w + (size_t)(kc + bkk) * 256 + n0 + bns + 4);
    __syncthreads();
#pragma unroll
    for (int i = 0; i < 4; ++i) { As[arow][aks + i] = av0[i]; As[arow][aks + 4 + i] = av1[i]; }
#pragma unroll
    for (int i = 0; i < 4; ++i) { Bs[bkk][bns + i] = bv0[i]; Bs[bkk][bns + 4 + i] = bv1[i]; }
    __syncthreads();
#pragma unroll 4
    for (int kk = 0; kk < 32; ++kk) {
      double a[4], b[4];
#pragma unroll
      for (int i = 0; i < 4; ++i) a[i] = (double)As[ty * 4 + i][kk];
#pragma unroll
      for (int j = 0; j < 4; ++j) b[j] = (double)Bs[kk][tx * 4 + j];
#pragma unroll
      for (int i = 0; i < 4; ++i)
#pragma unroll
        for (int j = 0; j < 4; ++j) acc[i][j] = fma(a[i], b[j], acc[i][j]);
    }
  }
#pragma unroll
  for (int i = 0; i < 4; ++i) {
    const int qrow = q0 + ty * 4 + i;
    if (qrow < NQ) {
#pragma unroll
      for (int j = 0; j < 4; ++j) {
        const int n = n0 + tx * 4 + j;
        double v = acc[i][j] + (double)adapter_b[n];
        g_qs[(size_t)qrow * 256 + n] = v > 0.0 ? v : 0.0;
      }
    }
  }
}

// ---------------------------------------------------------------------------
// smallk: per q -> gru_in_q(64), r-folded xg table (fp32), lq(4).
// One block per q.
// ---------------------------------------------------------------------------
__global__ void __launch_bounds__(256) smallk_kernel(
    const float* __restrict__ reducer_w, const float* __restrict__ gru_w_ih,
    const float* __restrict__ wgate_w)
{
  __shared__ double qsr[256];
  __shared__ double ps[4][64];
  __shared__ double gi[64];
  const int tid = threadIdx.x;
  const int qq = blockIdx.x;
  qsr[tid] = g_qs[(size_t)qq * 256 + tid];
  __syncthreads();
  {
    const int j = tid & 63, h = tid >> 6;
    const int k0 = h * 64;
    double a0 = 0.0, a1 = 0.0, a2 = 0.0, a3 = 0.0;
    for (int k = 0; k < 64; k += 4) {
      a0 = fma(qsr[k0 + k + 0], (double)reducer_w[(k0 + k + 0) * 64 + j], a0);
      a1 = fma(qsr[k0 + k + 1], (double)reducer_w[(k0 + k + 1) * 64 + j], a1);
      a2 = fma(qsr[k0 + k + 2], (double)reducer_w[(k0 + k + 2) * 64 + j], a2);
      a3 = fma(qsr[k0 + k + 3], (double)reducer_w[(k0 + k + 3) * 64 + j], a3);
    }
    ps[h][j] = (a0 + a1) + (a2 + a3);
  }
  __syncthreads();
  if (tid < 64) gi[tid] = (ps[0][tid] + ps[1][tid]) + (ps[2][tid] + ps[3][tid]);
  if (tid >= 64 && tid < 68) {
    const int e = tid - 64;
    double a0 = 0.0, a1 = 0.0, a2 = 0.0, a3 = 0.0;
    for (int k = 0; k < 256; k += 4) {
      a0 = fma(qsr[k + 0], (double)wgate_w[(k + 0) * 4 + e], a0);
      a1 = fma(qsr[k + 1], (double)wgate_w[(k + 1) * 4 + e], a1);
      a2 = fma(qsr[k + 2], (double)wgate_w[(k + 2) * 4 + e], a2);
      a3 = fma(qsr[k + 3], (double)wgate_w[(k + 3) * 4 + e], a3);
    }
    g_lq[(size_t)qq * 4 + e] = (a0 + a1) + (a2 + a3);
  }
  __syncthreads();
  if (tid < 192) {
    double a0 = 0.0, a1 = 0.0, a2 = 0.0, a3 = 0.0;
    for (int k = 0; k < 64; k += 4) {
      a0 = fma(gi[k + 0], (double)gru_w_ih[tid * 64 + k + 0], a0);
      a1 = fma(gi[k + 1], (double)gru_w_ih[tid * 64 + k + 1], a1);
      a2 = fma(gi[k + 2], (double)gru_w_ih[tid * 64 + k + 2], a2);
      a3 = fma(gi[k + 3], (double)gru_w_ih[tid * 64 + k + 3], a3);
    }
    const double s = (a0 + a1) + (a2 + a3);
    // r-folded x values (fp32): one extra rounding ~1e-8, below the
    // reference's own fp32 noise -> argmax decisions unaffected.
    g_xq2[(size_t)qq * 384 + tid]       = (float)(s + g_xgr[tid]);
    g_xq2[(size_t)qq * 384 + 192 + tid] = (float)(s + g_xgr[192 + tid]);
  }
}

// ---------------------------------------------------------------------------
// gru: 64 blocks x 128 threads (2 waves).  wave w owns rows j = w*32+p;
// lane pair (2p, 2p+1) splits row p's dots over k-halves [0,32)/[32,64).
// Per-lane W = 48 float2 = 96 VGPRs.  amdgpu_waves_per_eu(1,1) pins the
// allocator's occupancy target to 1 wave/EU -> full register budget -> W
// stays resident (launch_bounds(_,1) alone only caps, doesn't retarget).
// Half-sums combine via __shfl_xor(.,1); both pair lanes run the fp64 tail
// redundantly.  h exchanged via double-buffered padded HF[2][68] (odd half
// at word 36 -> even/odd lanes hit disjoint banks; R10 measured exactly
// 64 conflict-cycles/step on the unpadded layout).  ONE raw s_barrier per
// step (lgkmcnt-only drain; g_m stores not drained).
// ---------------------------------------------------------------------------
__global__ void __attribute__((amdgpu_waves_per_eu(1, 1)))
__launch_bounds__(128, 1) gru_kernel(
    const int* __restrict__ q, const int* __restrict__ r,
    const float* __restrict__ whh, const float* __restrict__ bhh)
{
  __shared__ __align__(16) float HF[2][68];   // h[0..31] at [0..31], h[32..63] at [36..67]
  const int tid = threadIdx.x;
  const int b = blockIdx.x;
  const int wv = tid >> 6;           // wave: rows [wv*32, wv*32+32)
  const int l = tid & 63;
  const int p = l >> 1;              // row within wave
  const int half = l & 1;            // k-half
  const int j = wv * 32 + p;         // row
  const int k0 = half * 32;

  // W half-rows for this lane, fp32 float2 pairs, resident (96 VGPRs).
  float2 Wr[16], Wz[16], Wn[16];
#pragma unroll
  for (int i = 0; i < 16; ++i) {
    Wr[i] = *(const float2*)(whh + (size_t)(0 * 64 + j) * 64 + k0 + 2 * i);
    Wz[i] = *(const float2*)(whh + (size_t)(1 * 64 + j) * 64 + k0 + 2 * i);
    Wn[i] = *(const float2*)(whh + (size_t)(2 * 64 + j) * 64 + k0 + 2 * i);
  }
#pragma unroll
  for (int i = 0; i < 16; ++i) {
    asm volatile("" : "+v"(Wr[i]));
    asm volatile("" : "+v"(Wz[i]));
    asm volatile("" : "+v"(Wn[i]));
  }
  const double br = (double)bhh[j];
  const double bz = (double)bhh[64 + j];
  const double bn = (double)bhh[128 + j];

  // step 0 consumes the start token (b_ih already folded in g_xg0f)
  float cx0 = g_xg0f[j], cx1 = g_xg0f[64 + j], cx2 = g_xg0f[128 + j];
  int qA = q[b * 512], rA = r[b * 512];

  const int jpad = j + ((j >> 5) << 2);     // +4 words for rows 32..63
  if (tid < 64) {
    const int tp = tid + ((tid >> 5) << 2);
    HF[0][tp] = 0.f;
  }
  double hd = 0.0;
  asm volatile("s_waitcnt lgkmcnt(0)\n\ts_barrier" ::: "memory");

  for (int t = 0; t < 512; ++t) {
    // prefetch x for step t+1 (token t) and q/r for token t+1
    float nx0 = 0.f, nx1 = 0.f, nx2 = 0.f;
    int qB = qA, rB = rA;
    if (t < 511) {
      const size_t base = (size_t)(qA * 2 + rA) * 192 + j;
      nx0 = g_xq2[base];
      nx1 = g_xq2[base + 64];
      nx2 = g_xq2[base + 128];
      const int tk = min(t + 1, 510);
      qB = q[b * 512 + tk];
      rB = r[b * 512 + tk];
    }

    // half-dot: 48 packed fp32 FMAs against resident W
    float2 ar = {0.f, 0.f}, az = {0.f, 0.f}, an = {0.f, 0.f};
    {
      const float4* hp = (const float4*)&HF[t & 1][half * 36];
#pragma unroll
      for (int g = 0; g < 8; ++g) {
        const float4 t4 = hp[g];
        const float2 hA = make_float2(t4.x, t4.y);
        const float2 hB = make_float2(t4.z, t4.w);
        pkfma(ar, Wr[2 * g], hA); pkfma(ar, Wr[2 * g + 1], hB);
        pkfma(az, Wz[2 * g], hA); pkfma(az, Wz[2 * g + 1], hB);
        pkfma(an, Wn[2 * g], hA); pkfma(an, Wn[2 * g + 1], hB);
      }
    }
    // combine k-halves in-pair (fp64 add is commutative -> pair-uniform)
    const float srh = ar.x + ar.y;
    const float szh = az.x + az.y;
    const float snh = an.x + an.y;
    const float sro = __shfl_xor(srh, 1);
    const float szo = __shfl_xor(szh, 1);
    const float sno = __shfl_xor(snh, 1);
    const double hr = br + ((double)srh + (double)sro);
    const double hz = bz + ((double)szh + (double)szo);
    const double hn = bn + ((double)snh + (double)sno);
    const double pr = (double)cx0 + hr, pz = (double)cx1 + hz;
    const double xn = (double)cx2;
    double rg = fma(0.5, tpoly(0.5 * pr), 0.5);
    double zg = fma(0.5, tpoly(0.5 * pz), 0.5);
    double pre = fma(rg, hn, xn);
    double ng = tpoly(pre);
    const bool bad = (fabs(pr) > 0.5) | (fabs(pz) > 0.5) | (fabs(pre) > 0.25);
    if (bad) {   // rare slow path
      rg = 1.0 / (1.0 + fexp(-pr));
      zg = 1.0 / (1.0 + fexp(-pz));
      pre = fma(rg, hn, xn);
      ng = 1.0 - 2.0 / (fexp(pre + pre) + 1.0);
    }
    const double hnew = fma(zg, hd - ng, ng);   // (1-z)n + z h
    hd = hnew;
    const float hnf = (float)hnew;
    if (half == 0) {
      HF[(t & 1) ^ 1][jpad] = hnf;
      g_m[((size_t)b * 512 + t) * 64 + j] = hnf;
    }
    asm volatile("s_waitcnt lgkmcnt(0)\n\ts_barrier" ::: "memory");

    cx0 = nx0; cx1 = nx1; cx2 = nx2;
    qA = qB; rA = rB;
  }
}

// ---------------------------------------------------------------------------
// top1: logits = lq[q_t] + m_t @ wgate[256:320] + wgate_b ; first-max argmax.
// ---------------------------------------------------------------------------
__global__ void __launch_bounds__(256) top1_kernel(
    const int* __restrict__ q,
    const float* __restrict__ wgate_w, const float* __restrict__ wgate_b)
{
  __shared__ double w2[256];   // [j][e]
  const int tid = threadIdx.x;
  w2[tid] = (double)wgate_w[1024 + tid];
  __syncthreads();
  const int t = blockIdx.x * 256 + tid;
  const int qv = q[t];
  double l0 = g_lq[(size_t)qv * 4 + 0] + (double)wgate_b[0];
  double l1 = g_lq[(size_t)qv * 4 + 1] + (double)wgate_b[1];
  double l2 = g_lq[(size_t)qv * 4 + 2] + (double)wgate_b[2];
  double l3 = g_lq[(size_t)qv * 4 + 3] + (double)wgate_b[3];
  const f32x4* mr4 = (const f32x4*)(g_m + (size_t)t * 64);
#pragma unroll 4
  for (int jj = 0; jj < 16; ++jj) {
    const f32x4 mv4 = mr4[jj];
#pragma unroll
    for (int c = 0; c < 4; ++c) {
      const double mv = (double)mv4[c];
      const int k = (jj * 4 + c) * 4;
      l0 = fma(mv, w2[k + 0], l0);
      l1 = fma(mv, w2[k + 1], l1);
      l2 = fma(mv, w2[k + 2], l2);
      l3 = fma(mv, w2[k + 3], l3);
    }
  }
  int bi = 0; double bvv = l0;
  if (l1 > bvv) { bvv = l1; bi = 1; }
  if (l2 > bvv) { bvv = l2; bi = 2; }
  if (l3 > bvv) { bvv = l3; bi = 3; }
  g_top1[t] = bi;
}

// ---------------------------------------------------------------------------
// kernelE: grid (313, 4): 32 q-values x one expert per block.
// Stage expert-e emb slice (32x256) as bf16; h1=relu(qr_e@W1+b1);
// out=h1@W2+b2 -> LN -> qf[q][e] bf16.  LDS 50.7 KB -> 3 blocks/CU.
// ---------------------------------------------------------------------------
__global__ void __launch_bounds__(128) kernelE(
    const float* __restrict__ emb,
    const float* __restrict__ b1, const float* __restrict__ b2,
    const float* __restrict__ lng, const float* __restrict__ lnb)
{
  __shared__ __align__(16) unsigned short QR[32 * 264];
  __shared__ __align__(16) unsigned short H1[32 * 264];
  __shared__ __align__(16) unsigned short EO[32 * 264];
  const int tid = threadIdx.x;
  const int t0 = blockIdx.x * 32;
  const int e  = blockIdx.y;
  const int w = tid >> 6;
  const int lane = tid & 63;
  const int l15 = lane & 15;
  const int quad = lane >> 4;

  // stage expert-e slice: 32 rows x 256 cols fp32 -> bf16
  for (int c = 0; c < 16; ++c) {
    const int idx = c * 128 + tid;           // f32x4 chunks: 32 rows x 64
    const int row = idx >> 6, col4 = idx & 63;
    const int qv = min(t0 + row, NQ - 1);
    f32x4 v = *(const f32x4*)(emb + (size_t)qv * 1024 + e * 256 + col4 * 4);
    unsigned a = ((unsigned)f2bf(v[1]) << 16) | f2bf(v[0]);
    unsigned bb = ((unsigned)f2bf(v[3]) << 16) | f2bf(v[2]);
    *(uint2*)&QR[row * 264 + col4 * 4] = make_uint2(a, bb);
  }
  __syncthreads();

  const f32x4 z4 = {0.f, 0.f, 0.f, 0.f};
  const int n0 = w * 128;

  f32x4 acc[2][8];
#pragma unroll
  for (int a = 0; a < 2; ++a)
#pragma unroll
    for (int bq = 0; bq < 8; ++bq) acc[a][bq] = z4;
#pragma unroll
  for (int ks = 0; ks < 8; ++ks) {
    const int koff = ks * 32 + quad * 8;
    bf16x8 a0 = *(const bf16x8*)&QR[l15 * 264 + koff];
    bf16x8 a1 = *(const bf16x8*)&QR[(16 + l15) * 264 + koff];
#pragma unroll
    for (int nt = 0; nt < 8; ++nt) {
      bf16x8 bbv = *(const bf16x8*)(g_w1t + (size_t)e * 65536 +
                                    (size_t)(n0 + nt * 16 + l15) * 256 + koff);
      acc[0][nt] = mfma16(a0, bbv, acc[0][nt]);
      acc[1][nt] = mfma16(a1, bbv, acc[1][nt]);
    }
  }
#pragma unroll
  for (int nt = 0; nt < 8; ++nt) {
    const int n = n0 + nt * 16 + l15;
    const float b1v = b1[e * 256 + n];
#pragma unroll
    for (int mt = 0; mt < 2; ++mt)
#pragma unroll
      for (int rg = 0; rg < 4; ++rg) {
        const int m = mt * 16 + quad * 4 + rg;
        H1[m * 264 + n] = f2bf(fmaxf(acc[mt][nt][rg] + b1v, 0.f));
      }
  }
  __syncthreads();

  f32x4 acc2[2][8];
#pragma unroll
  for (int a = 0; a < 2; ++a)
#pragma unroll
    for (int bq = 0; bq < 8; ++bq) acc2[a][bq] = z4;
#pragma unroll
  for (int ks = 0; ks < 8; ++ks) {
    const int koff = ks * 32 + quad * 8;
    bf16x8 a0 = *(const bf16x8*)&H1[l15 * 264 + koff];
    bf16x8 a1 = *(const bf16x8*)&H1[(16 + l15) * 264 + koff];
#pragma unroll
    for (int nt = 0; nt < 8; ++nt) {
      bf16x8 bbv = *(const bf16x8*)(g_w2t + (size_t)e * 65536 +
                                    (size_t)(n0 + nt * 16 + l15) * 256 + koff);
      acc2[0][nt] = mfma16(a0, bbv, acc2[0][nt]);
      acc2[1][nt] = mfma16(a1, bbv, acc2[1][nt]);
    }
  }
#pragma unroll
  for (int nt = 0; nt < 8; ++nt) {
    const int n = n0 + nt * 16 + l15;
    const float b2v = b2[e * 256 + n];
#pragma unroll
    for (int mt = 0; mt < 2; ++mt)
#pragma unroll
      for (int rg = 0; rg < 4; ++rg) {
        const int m = mt * 16 + quad * 4 + rg;
        EO[m * 264 + n] = f2bf(acc2[mt][nt][rg] + b2v);
      }
  }
  __syncthreads();

  {
    const int m = tid >> 2;
    const int sub = tid & 3;
    float sx = 0.f, sxx = 0.f;
#pragma unroll
    for (int i = 0; i < 8; ++i) {
      bf16x8 v = *(const bf16x8*)&EO[m * 264 + sub * 64 + i * 8];
#pragma unroll
      for (int c = 0; c < 8; ++c) {
        const float f = bf2f((unsigned short)v[c]);
        sx += f; sxx += f * f;
      }
    }
    sx += __shfl_xor(sx, 1); sxx += __shfl_xor(sxx, 1);
    sx += __shfl_xor(sx, 2); sxx += __shfl_xor(sxx, 2);
    const float mu = sx * (1.f / 256.f);
    const float var = sxx * (1.f / 256.f) - mu * mu;
    const float inv = 1.f / sqrtf(var + 1e-5f);
    if (t0 + m < NQ) {
      const size_t base = ((size_t)(t0 + m) * 4 + e) * 256;
#pragma unroll
      for (int i = 0; i < 8; ++i) {
        const int dbase = sub * 64 + i * 8;
        bf16x8 v = *(const bf16x8*)&EO[m * 264 + dbase];
        bf16x8 ov;
#pragma unroll
        for (int c = 0; c < 8; ++c) {
          const int d = dbase + c;
          const float f = bf2f((unsigned short)v[c]);
          ov[c] = (short)f2bf(lng[d] * (f - mu) * inv + lnb[d]);
        }
        *(bf16x8*)(g_qf + base + dbase) = ov;
      }
    }
  }
}

// ---------------------------------------------------------------------------
// kernelF: per 32 tokens: gather qf[q_t][top1_t] -> q_fused out (fp32) and
// LDS; proj (cor|inc) bf16 MFMA; qa_fused by r.
// ---------------------------------------------------------------------------
__global__ void __launch_bounds__(128) kernelF(
    const int* __restrict__ q, const int* __restrict__ r,
    const float* __restrict__ pcb, const float* __restrict__ pib,
    float* __restrict__ out)
{
  __shared__ __align__(16) unsigned short QF[32 * 264];
  __shared__ int rv_l[32];
  const int tid = threadIdx.x;
  const int t0 = blockIdx.x * 32;
  const int w = tid >> 6;
  const int lane = tid & 63;
  const int l15 = lane & 15;
  const int quad = lane >> 4;
  if (tid < 32) rv_l[tid] = r[t0 + tid];
  __syncthreads();

  {
    const int m = tid >> 2;
    const size_t row = ((size_t)q[t0 + m] * 4 + g_top1[t0 + m]) * 256;
#pragma unroll
    for (int i = 0; i < 8; ++i) {
      const int dbase = (tid & 3) * 64 + i * 8;
      bf16x8 v = *(const bf16x8*)(g_qf + row + dbase);
      *(bf16x8*)&QF[m * 264 + dbase] = v;
      f32x4 f0, f1;
#pragma unroll
      for (int c = 0; c < 4; ++c) f0[c] = bf2f((unsigned short)v[c]);
#pragma unroll
      for (int c = 0; c < 4; ++c) f1[c] = bf2f((unsigned short)v[4 + c]);
      *(f32x4*)(out + (size_t)(t0 + m) * 256 + dbase) = f0;
      *(f32x4*)(out + (size_t)(t0 + m) * 256 + dbase + 4) = f1;
    }
  }
  __syncthreads();

  const f32x4 z4 = {0.f, 0.f, 0.f, 0.f};
  const int n0 = w * 128;
  for (int ph = 0; ph < 2; ++ph) {
    f32x4 acc[2][8];
#pragma unroll
    for (int a = 0; a < 2; ++a)
#pragma unroll
      for (int bq = 0; bq < 8; ++bq) acc[a][bq] = z4;
#pragma unroll
    for (int ks = 0; ks < 8; ++ks) {
      const int koff = ks * 32 + quad * 8;
      bf16x8 a0 = *(const bf16x8*)&QF[l15 * 264 + koff];
      bf16x8 a1 = *(const bf16x8*)&QF[(16 + l15) * 264 + koff];
#pragma unroll
      for (int nt = 0; nt < 8; ++nt) {
        bf16x8 bbv = *(const bf16x8*)(g_projt +
            (size_t)(ph * 256 + n0 + nt * 16 + l15) * 256 + koff);
        acc[0][nt] = mfma16(a0, bbv, acc[0][nt]);
        acc[1][nt] = mfma16(a1, bbv, acc[1][nt]);
      }
    }
    const float* pbb = ph ? pib : pcb;
    const int want = ph ? 0 : 1;
#pragma unroll
    for (int nt = 0; nt < 8; ++nt) {
      const int n = n0 + nt * 16 + l15;
      const float pbv = pbb[n];
#pragma unroll
      for (int mt = 0; mt < 2; ++mt)
#pragma unroll
        for (int rg = 0; rg < 4; ++rg) {
          const int m = mt * 16 + quad * 4 + rg;
          if (rv_l[m] == want)
            out[(size_t)TT * 256 + (size_t)(t0 + m) * 256 + n] =
                acc[mt][nt][rg] + pbv;
        }
    }
  }
}

// ---------------------------------------------------------------------------
extern "C" void kernel_launch(void* const* d_in, const int* in_sizes, int n_in,
                              void* d_out, int out_size, void* d_ws, size_t ws_size,
                              hipStream_t stream)
{
  const int*   q   = (const int*)d_in[0];
  const int*   r   = (const int*)d_in[1];
  const float* emb = (const float*)d_in[2];
  const float* ew1 = (const float*)d_in[3];
  const float* eb1 = (const float*)d_in[4];
  const float* ew2 = (const float*)d_in[5];
  const float* eb2 = (const float*)d_in[6];
  const float* aw  = (const float*)d_in[7];
  const float* ab  = (const float*)d_in[8];
  const float* rw  = (const float*)d_in[9];
  const float* rb  = (const float*)d_in[10];
  const float* st  = (const float*)d_in[11];
  const float* wih = (const float*)d_in[12];
  const float* whh = (const float*)d_in[13];
  const float* bih = (const float*)d_in[14];
  const float* bhh = (const float*)d_in[15];
  const float* wgw = (const float*)d_in[16];
  const float* wgb = (const float*)d_in[17];
  const float* lng = (const float*)d_in[18];
  const float* lnb = (const float*)d_in[19];
  const float* resp= (const float*)d_in[20];
  const float* pcw = (const float*)d_in[21];
  const float* pcb = (const float*)d_in[22];
  const float* piw = (const float*)d_in[23];
  const float* pib = (const float*)d_in[24];
  float* out = (float*)d_out;
  (void)bih; (void)in_sizes; (void)n_in; (void)d_ws; (void)ws_size; (void)out_size;

  prep_kernel<<<64, 256, 0, stream>>>(ew1, ew2, pcw, piw, resp, rw, rb, st, wih, bih);
  qsk_kernel<<<dim3(157, 4), 256, 0, stream>>>(emb, aw, ab);
  smallk_kernel<<<NQ, 256, 0, stream>>>(rw, wih, wgw);
  gru_kernel<<<64, 128, 0, stream>>>(q, r, whh, bhh);
  top1_kernel<<<128, 256, 0, stream>>>(q, wgw, wgb);
  kernelE<<<dim3(313, 4), 128, 0, stream>>>(emb, eb1, eb2, lng, lnb);
  kernelF<<<1024, 128, 0, stream>>>(q, r, pcb, pib, out);
}

// Round 7
// 778.806 us; speedup vs baseline: 1.5546x; 1.0992x over previous
//
#include <hip/hip_runtime.h>
#include <cstddef>

// ---------------------------------------------------------------------------
// PolyaAKT interaction embedder, MI355X/gfx950.  Inputs fp32, output fp32.
// Control path (logits/GRU) high-precision for argmax fidelity; value path
// (experts/LN/proj) in bf16 MFMA.  Per-q dedup throughout.
// R12: hide independent work under the serial GRU (R11 evidence: W resident
// (VGPR 132), bank conflicts 0, 266us is the irreducible fp64-tail chain;
// gru uses 64/256 CUs -> 192 CUs idle for 266us):
//  - gruE: ONE dispatch, blocks 0..63 = gru body, blocks 64..1315 = kernelE
//    body (kernelE depends only on prep+emb, NOT on qsk/smallk/gru).
//    kernelE inherits waves_per_eu(1,1) (2 blk/CU vs 3) but is fully
//    shadowed by gru's long pole.  Bit-exact: same code per element.
//  - prepqsk: prep (64 blocks) fused with qsk (628 blocks), independent.
//    prep's grid-stride fixed at 64*256 (was gridDim-based).
// ---------------------------------------------------------------------------

#define NQ 10000
#define TT 32768   // B*S

typedef __attribute__((ext_vector_type(8))) short bf16x8;
typedef __attribute__((ext_vector_type(4))) float f32x4;

__device__ double g_qs  [NQ * 256];      // q_summary (relu'd), fp64
__device__ double g_xgr [2 * 192];       // r-part of xg (+b_ih), fp64
__device__ float  g_xg0f[192];           // start_token @ W_ih^T + b_ih (fp32)
__device__ float  g_xq2 [NQ * 384];      // r-folded xg: [q][r][192] fp32
__device__ double g_lq  [NQ * 4];        // qs @ wgate[0:256]
__device__ float  g_m   [TT * 64];       // GRU hidden per token (fp32)
__device__ int    g_top1[TT];
__device__ unsigned short g_w1t  [4 * 256 * 256];  // bf16 [e][n][k]
__device__ unsigned short g_w2t  [4 * 256 * 256];
__device__ unsigned short g_projt[512 * 256];      // bf16 [n(cor|inc)][k]
__device__ unsigned short g_qf   [NQ * 4 * 256];   // LN'd expert out, bf16

__device__ __forceinline__ float bf2f(unsigned short x) {
  return __uint_as_float(((unsigned)x) << 16);
}
__device__ __forceinline__ unsigned short f2bf(float f) {
  unsigned u = __float_as_uint(f);
  u += 0x7FFFu + ((u >> 16) & 1u);   // RNE
  return (unsigned short)(u >> 16);
}
__device__ __forceinline__ f32x4 mfma16(bf16x8 a, bf16x8 b, f32x4 c) {
  return __builtin_amdgcn_mfma_f32_16x16x32_bf16(a, b, c, 0, 0, 0);
}
// packed fp32 fma: c = a*b + c on both lanes of the pair (bit-identical to
// two scalar v_fma_f32, just one instruction).
__device__ __forceinline__ void pkfma(float2& c, float2 a, float2 b) {
  asm("v_pk_fma_f32 %0, %1, %2, %0" : "+v"(c) : "v"(a), "v"(b));
}

// fast fp64 exp (slow path only): range-reduced degree-10 poly, rel err ~2e-13.
__device__ __forceinline__ double fexp(double x) {
  const double L2E  = 1.4426950408889634074;
  const double LN2H = 6.93147180369123816490e-01;
  const double LN2L = 1.90821492927058770002e-10;
  double n = rint(x * L2E);
  int ni = (int)n;
  double r = fma(-n, LN2H, x);
  r = fma(-n, LN2L, r);
  double p = 2.7557319223985888e-07;
  p = fma(p, r, 2.7557319223985893e-06);
  p = fma(p, r, 2.4801587301587302e-05);
  p = fma(p, r, 1.9841269841269841e-04);
  p = fma(p, r, 1.3888888888888889e-03);
  p = fma(p, r, 8.3333333333333332e-03);
  p = fma(p, r, 4.1666666666666664e-02);
  p = fma(p, r, 1.6666666666666666e-01);
  p = fma(p, r, 0.5);
  p = fma(p, r, 1.0);
  p = fma(p, r, 1.0);
  return ldexp(p, ni);
}

// tanh via odd Taylor, |p| <= 0.25: abs err ~5e-11.
__device__ __forceinline__ double tpoly(double p) {
  const double p2 = p * p;
  double t = -1382.0 / 155925.0;          // p^11
  t = fma(t, p2, 62.0 / 2835.0);          // p^9
  t = fma(t, p2, -17.0 / 315.0);          // p^7
  t = fma(t, p2, 2.0 / 15.0);             // p^5
  t = fma(t, p2, -1.0 / 3.0);             // p^3
  t = fma(t, p2, 1.0);
  return p * t;
}

// ---------------------------------------------------------------------------
// prepqsk: blocks 0..63 = prep (bf16 weight tables + fp64 folds);
// blocks 64..691 = qsk fp64 GEMM (independent of prep).
// ---------------------------------------------------------------------------
__global__ void __launch_bounds__(256) prepqsk_kernel(
    const float* __restrict__ expert_w1, const float* __restrict__ expert_w2,
    const float* __restrict__ proj_cor_w, const float* __restrict__ proj_inc_w,
    const float* __restrict__ resp_table, const float* __restrict__ reducer_w,
    const float* __restrict__ reducer_b,  const float* __restrict__ start_token,
    const float* __restrict__ gru_w_ih,   const float* __restrict__ gru_b_ih,
    const float* __restrict__ emb, const float* __restrict__ adapter_w,
    const float* __restrict__ adapter_b)
{
  __shared__ double red2f[128];   // prep: [rr][j]
  __shared__ __align__(16) float As[64][33];
  __shared__ __align__(16) float Bs[32][65];
  const int tid = threadIdx.x;

  if (blockIdx.x < 64) {
    // ---- prep ----
    if (blockIdx.x == 0) {
      if (tid < 128) {
        const int rr = tid >> 6, j = tid & 63;
        double acc = (double)reducer_b[j];
        for (int k = 0; k < 256; ++k)
          acc += (double)resp_table[rr * 256 + k] *
                 (double)reducer_w[(256 + k) * 64 + j];
        red2f[tid] = acc;
      }
      __syncthreads();
      if (tid < 192) {
        const double bih = (double)gru_b_ih[tid];
        double a0 = bih, a1 = bih, a2 = bih;
        for (int j = 0; j < 64; ++j) {
          const double w = (double)gru_w_ih[tid * 64 + j];
          a0 += red2f[j] * w;
          a1 += red2f[64 + j] * w;
          a2 += (double)start_token[j] * w;
        }
        g_xgr[tid] = a0; g_xgr[192 + tid] = a1; g_xg0f[tid] = (float)a2;
      }
    }
    const int idx0 = blockIdx.x * 256 + tid;
    const int stride = 64 * 256;
    for (int i = idx0; i < 4 * 256 * 256; i += stride) {
      const int e = i >> 16, rem = i & 65535, n = rem >> 8, k = rem & 255;
      g_w1t[i] = f2bf(expert_w1[e * 65536 + k * 256 + n]);
      g_w2t[i] = f2bf(expert_w2[e * 65536 + k * 256 + n]);
    }
    for (int i = idx0; i < 512 * 256; i += stride) {
      const int n = i >> 8, k = i & 255;
      g_projt[i] = f2bf((n < 256) ? proj_cor_w[k * 256 + n]
                                  : proj_inc_w[k * 256 + (n - 256)]);
    }
    return;
  }

  // ---- qsk ----
  const int bq = blockIdx.x - 64;
  const int q0 = (bq >> 2) * 64;
  const int n0 = (bq & 3) * 64;
  const int ty = tid >> 4, tx = tid & 15;

  double acc[4][4];
#pragma unroll
  for (int i = 0; i < 4; ++i)
#pragma unroll
    for (int j = 0; j < 4; ++j) acc[i][j] = 0.0;

  const int arow = tid >> 2, aks = (tid & 3) * 8;
  const int qa = min(q0 + arow, NQ - 1);
  const int bkk = tid >> 3, bns = (tid & 7) * 8;

  for (int kc = 0; kc < 1024; kc += 32) {
    f32x4 av0 = *(const f32x4*)(emb + (size_t)qa * 1024 + kc + aks);
    f32x4 av1 = *(const f32x4*)(emb + (size_t)qa * 1024 + kc + aks + 4);
    f32x4 bv0 = *(const f32x4*)(adapter_w + (size_t)(kc + bkk) * 256 + n0 + bns);
    f32x4 bv1 = *(const f32x4*)(adapter_w + (size_t)(kc + bkk) * 256 + n0 + bns + 4);
    __syncthreads();
#pragma unroll
    for (int i = 0; i < 4; ++i) { As[arow][aks + i] = av0[i]; As[arow][aks + 4 + i] = av1[i]; }
#pragma unroll
    for (int i = 0; i < 4; ++i) { Bs[bkk][bns + i] = bv0[i]; Bs[bkk][bns + 4 + i] = bv1[i]; }
    __syncthreads();
#pragma unroll 4
    for (int kk = 0; kk < 32; ++kk) {
      double a[4], b[4];
#pragma unroll
      for (int i = 0; i < 4; ++i) a[i] = (double)As[ty * 4 + i][kk];
#pragma unroll
      for (int j = 0; j < 4; ++j) b[j] = (double)Bs[kk][tx * 4 + j];
#pragma unroll
      for (int i = 0; i < 4; ++i)
#pragma unroll
        for (int j = 0; j < 4; ++j) acc[i][j] = fma(a[i], b[j], acc[i][j]);
    }
  }
#pragma unroll
  for (int i = 0; i < 4; ++i) {
    const int qrow = q0 + ty * 4 + i;
    if (qrow < NQ) {
#pragma unroll
      for (int j = 0; j < 4; ++j) {
        const int n = n0 + tx * 4 + j;
        double v = acc[i][j] + (double)adapter_b[n];
        g_qs[(size_t)qrow * 256 + n] = v > 0.0 ? v : 0.0;
      }
    }
  }
}

// ---------------------------------------------------------------------------
// smallk: per q -> gru_in_q(64), r-folded xg table (fp32), lq(4).
// One block per q.
// ---------------------------------------------------------------------------
__global__ void __launch_bounds__(256) smallk_kernel(
    const float* __restrict__ reducer_w, const float* __restrict__ gru_w_ih,
    const float* __restrict__ wgate_w)
{
  __shared__ double qsr[256];
  __shared__ double ps[4][64];
  __shared__ double gi[64];
  const int tid = threadIdx.x;
  const int qq = blockIdx.x;
  qsr[tid] = g_qs[(size_t)qq * 256 + tid];
  __syncthreads();
  {
    const int j = tid & 63, h = tid >> 6;
    const int k0 = h * 64;
    double a0 = 0.0, a1 = 0.0, a2 = 0.0, a3 = 0.0;
    for (int k = 0; k < 64; k += 4) {
      a0 = fma(qsr[k0 + k + 0], (double)reducer_w[(k0 + k + 0) * 64 + j], a0);
      a1 = fma(qsr[k0 + k + 1], (double)reducer_w[(k0 + k + 1) * 64 + j], a1);
      a2 = fma(qsr[k0 + k + 2], (double)reducer_w[(k0 + k + 2) * 64 + j], a2);
      a3 = fma(qsr[k0 + k + 3], (double)reducer_w[(k0 + k + 3) * 64 + j], a3);
    }
    ps[h][j] = (a0 + a1) + (a2 + a3);
  }
  __syncthreads();
  if (tid < 64) gi[tid] = (ps[0][tid] + ps[1][tid]) + (ps[2][tid] + ps[3][tid]);
  if (tid >= 64 && tid < 68) {
    const int e = tid - 64;
    double a0 = 0.0, a1 = 0.0, a2 = 0.0, a3 = 0.0;
    for (int k = 0; k < 256; k += 4) {
      a0 = fma(qsr[k + 0], (double)wgate_w[(k + 0) * 4 + e], a0);
      a1 = fma(qsr[k + 1], (double)wgate_w[(k + 1) * 4 + e], a1);
      a2 = fma(qsr[k + 2], (double)wgate_w[(k + 2) * 4 + e], a2);
      a3 = fma(qsr[k + 3], (double)wgate_w[(k + 3) * 4 + e], a3);
    }
    g_lq[(size_t)qq * 4 + e] = (a0 + a1) + (a2 + a3);
  }
  __syncthreads();
  if (tid < 192) {
    double a0 = 0.0, a1 = 0.0, a2 = 0.0, a3 = 0.0;
    for (int k = 0; k < 64; k += 4) {
      a0 = fma(gi[k + 0], (double)gru_w_ih[tid * 64 + k + 0], a0);
      a1 = fma(gi[k + 1], (double)gru_w_ih[tid * 64 + k + 1], a1);
      a2 = fma(gi[k + 2], (double)gru_w_ih[tid * 64 + k + 2], a2);
      a3 = fma(gi[k + 3], (double)gru_w_ih[tid * 64 + k + 3], a3);
    }
    const double s = (a0 + a1) + (a2 + a3);
    // r-folded x values (fp32): one extra rounding ~1e-8, below the
    // reference's own fp32 noise -> argmax decisions unaffected.
    g_xq2[(size_t)qq * 384 + tid]       = (float)(s + g_xgr[tid]);
    g_xq2[(size_t)qq * 384 + 192 + tid] = (float)(s + g_xgr[192 + tid]);
  }
}

// ---------------------------------------------------------------------------
// gruE: blocks 0..63 = gru (2-wave k-split, resident W, padded HF);
// blocks 64..1315 = kernelE (expert-split, flattened (313,4)).
// kernelE depends only on prep+emb -> fully shadowed under gru's 266us on
// the 192 otherwise-idle CUs.  waves_per_eu(1,1) pins the register budget
// (R11: VGPR 132, W resident; kernelE tolerates 2 blk/CU since shadowed).
// ---------------------------------------------------------------------------
__global__ void __attribute__((amdgpu_waves_per_eu(1, 1)))
__launch_bounds__(128, 1) gruE_kernel(
    const int* __restrict__ q, const int* __restrict__ r,
    const float* __restrict__ whh, const float* __restrict__ bhh,
    const float* __restrict__ emb,
    const float* __restrict__ b1, const float* __restrict__ b2,
    const float* __restrict__ lng, const float* __restrict__ lnb)
{
  __shared__ __align__(16) float HF[2][68];   // gru: h mirror, padded
  __shared__ __align__(16) unsigned short QR[32 * 264];
  __shared__ __align__(16) unsigned short H1[32 * 264];
  __shared__ __align__(16) unsigned short EO[32 * 264];
  const int tid = threadIdx.x;

  if (blockIdx.x < 64) {
    // ---- gru ----
    const int b = blockIdx.x;
    const int wv = tid >> 6;           // wave: rows [wv*32, wv*32+32)
    const int l = tid & 63;
    const int p = l >> 1;              // row within wave
    const int half = l & 1;            // k-half
    const int j = wv * 32 + p;         // row
    const int k0 = half * 32;

    // W half-rows for this lane, fp32 float2 pairs, resident (96 VGPRs).
    float2 Wr[16], Wz[16], Wn[16];
#pragma unroll
    for (int i = 0; i < 16; ++i) {
      Wr[i] = *(const float2*)(whh + (size_t)(0 * 64 + j) * 64 + k0 + 2 * i);
      Wz[i] = *(const float2*)(whh + (size_t)(1 * 64 + j) * 64 + k0 + 2 * i);
      Wn[i] = *(const float2*)(whh + (size_t)(2 * 64 + j) * 64 + k0 + 2 * i);
    }
#pragma unroll
    for (int i = 0; i < 16; ++i) {
      asm volatile("" : "+v"(Wr[i]));
      asm volatile("" : "+v"(Wz[i]));
      asm volatile("" : "+v"(Wn[i]));
    }
    const double br = (double)bhh[j];
    const double bz = (double)bhh[64 + j];
    const double bn = (double)bhh[128 + j];

    // step 0 consumes the start token (b_ih already folded in g_xg0f)
    float cx0 = g_xg0f[j], cx1 = g_xg0f[64 + j], cx2 = g_xg0f[128 + j];
    int qA = q[b * 512], rA = r[b * 512];

    const int jpad = j + ((j >> 5) << 2);     // +4 words for rows 32..63
    if (tid < 64) {
      const int tp = tid + ((tid >> 5) << 2);
      HF[0][tp] = 0.f;
    }
    double hd = 0.0;
    asm volatile("s_waitcnt lgkmcnt(0)\n\ts_barrier" ::: "memory");

    for (int t = 0; t < 512; ++t) {
      // prefetch x for step t+1 (token t) and q/r for token t+1
      float nx0 = 0.f, nx1 = 0.f, nx2 = 0.f;
      int qB = qA, rB = rA;
      if (t < 511) {
        const size_t base = (size_t)(qA * 2 + rA) * 192 + j;
        nx0 = g_xq2[base];
        nx1 = g_xq2[base + 64];
        nx2 = g_xq2[base + 128];
        const int tk = min(t + 1, 510);
        qB = q[b * 512 + tk];
        rB = r[b * 512 + tk];
      }

      // half-dot: 48 packed fp32 FMAs against resident W
      float2 ar = {0.f, 0.f}, az = {0.f, 0.f}, an = {0.f, 0.f};
      {
        const float4* hp = (const float4*)&HF[t & 1][half * 36];
#pragma unroll
        for (int g = 0; g < 8; ++g) {
          const float4 t4 = hp[g];
          const float2 hA = make_float2(t4.x, t4.y);
          const float2 hB = make_float2(t4.z, t4.w);
          pkfma(ar, Wr[2 * g], hA); pkfma(ar, Wr[2 * g + 1], hB);
          pkfma(az, Wz[2 * g], hA); pkfma(az, Wz[2 * g + 1], hB);
          pkfma(an, Wn[2 * g], hA); pkfma(an, Wn[2 * g + 1], hB);
        }
      }
      // combine k-halves in-pair (fp64 add is commutative -> pair-uniform)
      const float srh = ar.x + ar.y;
      const float szh = az.x + az.y;
      const float snh = an.x + an.y;
      const float sro = __shfl_xor(srh, 1);
      const float szo = __shfl_xor(szh, 1);
      const float sno = __shfl_xor(snh, 1);
      const double hr = br + ((double)srh + (double)sro);
      const double hz = bz + ((double)szh + (double)szo);
      const double hn = bn + ((double)snh + (double)sno);
      const double pr = (double)cx0 + hr, pz = (double)cx1 + hz;
      const double xn = (double)cx2;
      double rg = fma(0.5, tpoly(0.5 * pr), 0.5);
      double zg = fma(0.5, tpoly(0.5 * pz), 0.5);
      double pre = fma(rg, hn, xn);
      double ng = tpoly(pre);
      const bool bad = (fabs(pr) > 0.5) | (fabs(pz) > 0.5) | (fabs(pre) > 0.25);
      if (bad) {   // rare slow path
        rg = 1.0 / (1.0 + fexp(-pr));
        zg = 1.0 / (1.0 + fexp(-pz));
        pre = fma(rg, hn, xn);
        ng = 1.0 - 2.0 / (fexp(pre + pre) + 1.0);
      }
      const double hnew = fma(zg, hd - ng, ng);   // (1-z)n + z h
      hd = hnew;
      const float hnf = (float)hnew;
      if (half == 0) {
        HF[(t & 1) ^ 1][jpad] = hnf;
        g_m[((size_t)b * 512 + t) * 64 + j] = hnf;
      }
      asm volatile("s_waitcnt lgkmcnt(0)\n\ts_barrier" ::: "memory");

      cx0 = nx0; cx1 = nx1; cx2 = nx2;
      qA = qB; rA = rB;
    }
    return;
  }

  // ---- kernelE ----
  const int bx = blockIdx.x - 64;
  const int e  = bx & 3;
  const int t0 = (bx >> 2) * 32;
  const int w = tid >> 6;
  const int lane = tid & 63;
  const int l15 = lane & 15;
  const int quad = lane >> 4;

  // stage expert-e slice: 32 rows x 256 cols fp32 -> bf16
  for (int c = 0; c < 16; ++c) {
    const int idx = c * 128 + tid;           // f32x4 chunks: 32 rows x 64
    const int row = idx >> 6, col4 = idx & 63;
    const int qv = min(t0 + row, NQ - 1);
    f32x4 v = *(const f32x4*)(emb + (size_t)qv * 1024 + e * 256 + col4 * 4);
    unsigned a = ((unsigned)f2bf(v[1]) << 16) | f2bf(v[0]);
    unsigned bb = ((unsigned)f2bf(v[3]) << 16) | f2bf(v[2]);
    *(uint2*)&QR[row * 264 + col4 * 4] = make_uint2(a, bb);
  }
  __syncthreads();

  const f32x4 z4 = {0.f, 0.f, 0.f, 0.f};
  const int n0 = w * 128;

  f32x4 acc[2][8];
#pragma unroll
  for (int a = 0; a < 2; ++a)
#pragma unroll
    for (int bq = 0; bq < 8; ++bq) acc[a][bq] = z4;
#pragma unroll
  for (int ks = 0; ks < 8; ++ks) {
    const int koff = ks * 32 + quad * 8;
    bf16x8 a0 = *(const bf16x8*)&QR[l15 * 264 + koff];
    bf16x8 a1 = *(const bf16x8*)&QR[(16 + l15) * 264 + koff];
#pragma unroll
    for (int nt = 0; nt < 8; ++nt) {
      bf16x8 bbv = *(const bf16x8*)(g_w1t + (size_t)e * 65536 +
                                    (size_t)(n0 + nt * 16 + l15) * 256 + koff);
      acc[0][nt] = mfma16(a0, bbv, acc[0][nt]);
      acc[1][nt] = mfma16(a1, bbv, acc[1][nt]);
    }
  }
#pragma unroll
  for (int nt = 0; nt < 8; ++nt) {
    const int n = n0 + nt * 16 + l15;
    const float b1v = b1[e * 256 + n];
#pragma unroll
    for (int mt = 0; mt < 2; ++mt)
#pragma unroll
      for (int rg = 0; rg < 4; ++rg) {
        const int m = mt * 16 + quad * 4 + rg;
        H1[m * 264 + n] = f2bf(fmaxf(acc[mt][nt][rg] + b1v, 0.f));
      }
  }
  __syncthreads();

  f32x4 acc2[2][8];
#pragma unroll
  for (int a = 0; a < 2; ++a)
#pragma unroll
    for (int bq = 0; bq < 8; ++bq) acc2[a][bq] = z4;
#pragma unroll
  for (int ks = 0; ks < 8; ++ks) {
    const int koff = ks * 32 + quad * 8;
    bf16x8 a0 = *(const bf16x8*)&H1[l15 * 264 + koff];
    bf16x8 a1 = *(const bf16x8*)&H1[(16 + l15) * 264 + koff];
#pragma unroll
    for (int nt = 0; nt < 8; ++nt) {
      bf16x8 bbv = *(const bf16x8*)(g_w2t + (size_t)e * 65536 +
                                    (size_t)(n0 + nt * 16 + l15) * 256 + koff);
      acc2[0][nt] = mfma16(a0, bbv, acc2[0][nt]);
      acc2[1][nt] = mfma16(a1, bbv, acc2[1][nt]);
    }
  }
#pragma unroll
  for (int nt = 0; nt < 8; ++nt) {
    const int n = n0 + nt * 16 + l15;
    const float b2v = b2[e * 256 + n];
#pragma unroll
    for (int mt = 0; mt < 2; ++mt)
#pragma unroll
      for (int rg = 0; rg < 4; ++rg) {
        const int m = mt * 16 + quad * 4 + rg;
        EO[m * 264 + n] = f2bf(acc2[mt][nt][rg] + b2v);
      }
  }
  __syncthreads();

  {
    const int m = tid >> 2;
    const int sub = tid & 3;
    float sx = 0.f, sxx = 0.f;
#pragma unroll
    for (int i = 0; i < 8; ++i) {
      bf16x8 v = *(const bf16x8*)&EO[m * 264 + sub * 64 + i * 8];
#pragma unroll
      for (int c = 0; c < 8; ++c) {
        const float f = bf2f((unsigned short)v[c]);
        sx += f; sxx += f * f;
      }
    }
    sx += __shfl_xor(sx, 1); sxx += __shfl_xor(sxx, 1);
    sx += __shfl_xor(sx, 2); sxx += __shfl_xor(sxx, 2);
    const float mu = sx * (1.f / 256.f);
    const float var = sxx * (1.f / 256.f) - mu * mu;
    const float inv = 1.f / sqrtf(var + 1e-5f);
    if (t0 + m < NQ) {
      const size_t base = ((size_t)(t0 + m) * 4 + e) * 256;
#pragma unroll
      for (int i = 0; i < 8; ++i) {
        const int dbase = sub * 64 + i * 8;
        bf16x8 v = *(const bf16x8*)&EO[m * 264 + dbase];
        bf16x8 ov;
#pragma unroll
        for (int c = 0; c < 8; ++c) {
          const int d = dbase + c;
          const float f = bf2f((unsigned short)v[c]);
          ov[c] = (short)f2bf(lng[d] * (f - mu) * inv + lnb[d]);
        }
        *(bf16x8*)(g_qf + base + dbase) = ov;
      }
    }
  }
}

// ---------------------------------------------------------------------------
// top1: logits = lq[q_t] + m_t @ wgate[256:320] + wgate_b ; first-max argmax.
// ---------------------------------------------------------------------------
__global__ void __launch_bounds__(256) top1_kernel(
    const int* __restrict__ q,
    const float* __restrict__ wgate_w, const float* __restrict__ wgate_b)
{
  __shared__ double w2[256];   // [j][e]
  const int tid = threadIdx.x;
  w2[tid] = (double)wgate_w[1024 + tid];
  __syncthreads();
  const int t = blockIdx.x * 256 + tid;
  const int qv = q[t];
  double l0 = g_lq[(size_t)qv * 4 + 0] + (double)wgate_b[0];
  double l1 = g_lq[(size_t)qv * 4 + 1] + (double)wgate_b[1];
  double l2 = g_lq[(size_t)qv * 4 + 2] + (double)wgate_b[2];
  double l3 = g_lq[(size_t)qv * 4 + 3] + (double)wgate_b[3];
  const f32x4* mr4 = (const f32x4*)(g_m + (size_t)t * 64);
#pragma unroll 4
  for (int jj = 0; jj < 16; ++jj) {
    const f32x4 mv4 = mr4[jj];
#pragma unroll
    for (int c = 0; c < 4; ++c) {
      const double mv = (double)mv4[c];
      const int k = (jj * 4 + c) * 4;
      l0 = fma(mv, w2[k + 0], l0);
      l1 = fma(mv, w2[k + 1], l1);
      l2 = fma(mv, w2[k + 2], l2);
      l3 = fma(mv, w2[k + 3], l3);
    }
  }
  int bi = 0; double bvv = l0;
  if (l1 > bvv) { bvv = l1; bi = 1; }
  if (l2 > bvv) { bvv = l2; bi = 2; }
  if (l3 > bvv) { bvv = l3; bi = 3; }
  g_top1[t] = bi;
}

// ---------------------------------------------------------------------------
// kernelF: per 32 tokens: gather qf[q_t][top1_t] -> q_fused out (fp32) and
// LDS; proj (cor|inc) bf16 MFMA; qa_fused by r.
// ---------------------------------------------------------------------------
__global__ void __launch_bounds__(128) kernelF(
    const int* __restrict__ q, const int* __restrict__ r,
    const float* __restrict__ pcb, const float* __restrict__ pib,
    float* __restrict__ out)
{
  __shared__ __align__(16) unsigned short QF[32 * 264];
  __shared__ int rv_l[32];
  const int tid = threadIdx.x;
  const int t0 = blockIdx.x * 32;
  const int w = tid >> 6;
  const int lane = tid & 63;
  const int l15 = lane & 15;
  const int quad = lane >> 4;
  if (tid < 32) rv_l[tid] = r[t0 + tid];
  __syncthreads();

  {
    const int m = tid >> 2;
    const size_t row = ((size_t)q[t0 + m] * 4 + g_top1[t0 + m]) * 256;
#pragma unroll
    for (int i = 0; i < 8; ++i) {
      const int dbase = (tid & 3) * 64 + i * 8;
      bf16x8 v = *(const bf16x8*)(g_qf + row + dbase);
      *(bf16x8*)&QF[m * 264 + dbase] = v;
      f32x4 f0, f1;
#pragma unroll
      for (int c = 0; c < 4; ++c) f0[c] = bf2f((unsigned short)v[c]);
#pragma unroll
      for (int c = 0; c < 4; ++c) f1[c] = bf2f((unsigned short)v[4 + c]);
      *(f32x4*)(out + (size_t)(t0 + m) * 256 + dbase) = f0;
      *(f32x4*)(out + (size_t)(t0 + m) * 256 + dbase + 4) = f1;
    }
  }
  __syncthreads();

  const f32x4 z4 = {0.f, 0.f, 0.f, 0.f};
  const int n0 = w * 128;
  for (int ph = 0; ph < 2; ++ph) {
    f32x4 acc[2][8];
#pragma unroll
    for (int a = 0; a < 2; ++a)
#pragma unroll
      for (int bq = 0; bq < 8; ++bq) acc[a][bq] = z4;
#pragma unroll
    for (int ks = 0; ks < 8; ++ks) {
      const int koff = ks * 32 + quad * 8;
      bf16x8 a0 = *(const bf16x8*)&QF[l15 * 264 + koff];
      bf16x8 a1 = *(const bf16x8*)&QF[(16 + l15) * 264 + koff];
#pragma unroll
      for (int nt = 0; nt < 8; ++nt) {
        bf16x8 bbv = *(const bf16x8*)(g_projt +
            (size_t)(ph * 256 + n0 + nt * 16 + l15) * 256 + koff);
        acc[0][nt] = mfma16(a0, bbv, acc[0][nt]);
        acc[1][nt] = mfma16(a1, bbv, acc[1][nt]);
      }
    }
    const float* pbb = ph ? pib : pcb;
    const int want = ph ? 0 : 1;
#pragma unroll
    for (int nt = 0; nt < 8; ++nt) {
      const int n = n0 + nt * 16 + l15;
      const float pbv = pbb[n];
#pragma unroll
      for (int mt = 0; mt < 2; ++mt)
#pragma unroll
        for (int rg = 0; rg < 4; ++rg) {
          const int m = mt * 16 + quad * 4 + rg;
          if (rv_l[m] == want)
            out[(size_t)TT * 256 + (size_t)(t0 + m) * 256 + n] =
                acc[mt][nt][rg] + pbv;
        }
    }
  }
}

// ---------------------------------------------------------------------------
extern "C" void kernel_launch(void* const* d_in, const int* in_sizes, int n_in,
                              void* d_out, int out_size, void* d_ws, size_t ws_size,
                              hipStream_t stream)
{
  const int*   q   = (const int*)d_in[0];
  const int*   r   = (const int*)d_in[1];
  const float* emb = (const float*)d_in[2];
  const float* ew1 = (const float*)d_in[3];
  const float* eb1 = (const float*)d_in[4];
  const float* ew2 = (const float*)d_in[5];
  const float* eb2 = (const float*)d_in[6];
  const float* aw  = (const float*)d_in[7];
  const float* ab  = (const float*)d_in[8];
  const float* rw  = (const float*)d_in[9];
  const float* rb  = (const float*)d_in[10];
  const float* st  = (const float*)d_in[11];
  const float* wih = (const float*)d_in[12];
  const float* whh = (const float*)d_in[13];
  const float* bih = (const float*)d_in[14];
  const float* bhh = (const float*)d_in[15];
  const float* wgw = (const float*)d_in[16];
  const float* wgb = (const float*)d_in[17];
  const float* lng = (const float*)d_in[18];
  const float* lnb = (const float*)d_in[19];
  const float* resp= (const float*)d_in[20];
  const float* pcw = (const float*)d_in[21];
  const float* pcb = (const float*)d_in[22];
  const float* piw = (const float*)d_in[23];
  const float* pib = (const float*)d_in[24];
  float* out = (float*)d_out;
  (void)bih; (void)in_sizes; (void)n_in; (void)d_ws; (void)ws_size; (void)out_size;

  prepqsk_kernel<<<692, 256, 0, stream>>>(ew1, ew2, pcw, piw, resp, rw, rb, st,
                                          wih, bih, emb, aw, ab);
  smallk_kernel<<<NQ, 256, 0, stream>>>(rw, wih, wgw);
  gruE_kernel<<<64 + 313 * 4, 128, 0, stream>>>(q, r, whh, bhh,
                                                emb, eb1, eb2, lng, lnb);
  top1_kernel<<<128, 256, 0, stream>>>(q, wgw, wgb);
  kernelF<<<1024, 128, 0, stream>>>(q, r, pcb, pib, out);
}